// Round 1
// baseline (1047.906 us; speedup 1.0000x reference)
//
#include <hip/hip_runtime.h>

namespace {
constexpr int B_ = 16, C_ = 128, N_ = 8192, K_ = 256, P_ = 128, NB_ = 6;
}

// ---------------------------------------------------------------------------
// 1) per-(b,c) instance-norm stats over N
// ---------------------------------------------------------------------------
__global__ __launch_bounds__(256) void k_instat(const float* __restrict__ x,
                                                float* __restrict__ m_o,
                                                float* __restrict__ v_o,
                                                float* __restrict__ r_o) {
  const int row = blockIdx.x;  // b*C + c
  const float4* xr = reinterpret_cast<const float4*>(x + (size_t)row * N_);
  float s = 0.f, ss = 0.f;
  for (int i = threadIdx.x; i < N_ / 4; i += 256) {
    float4 v = xr[i];
    s += v.x + v.y + v.z + v.w;
    ss += v.x * v.x + v.y * v.y + v.z * v.z + v.w * v.w;
  }
  __shared__ float rs[256], rq[256];
  rs[threadIdx.x] = s; rq[threadIdx.x] = ss;
  __syncthreads();
  for (int st = 128; st > 0; st >>= 1) {
    if (threadIdx.x < st) { rs[threadIdx.x] += rs[threadIdx.x + st]; rq[threadIdx.x] += rq[threadIdx.x + st]; }
    __syncthreads();
  }
  if (threadIdx.x == 0) {
    float m = rs[0] / N_;
    float v = rq[0] / N_ - m * m;
    m_o[row] = m; v_o[row] = v; r_o[row] = rsqrtf(v + 1e-3f);
  }
}

// ---------------------------------------------------------------------------
// 2) fold IN+BN into per-(b,c) affine for dp and du paths
//    BN mean over (B,N) of IN(x) is analytically 0; var_c = mean_b v/(v+eps)
// ---------------------------------------------------------------------------
__global__ void k_affine(const float* __restrict__ m_in, const float* __restrict__ v_in,
                         const float* __restrict__ r_in,
                         const float* __restrict__ dpg, const float* __restrict__ dpb,
                         const float* __restrict__ dug, const float* __restrict__ dub,
                         float* __restrict__ a_dp, float* __restrict__ d_dp,
                         float* __restrict__ a_du, float* __restrict__ d_du) {
  int c = threadIdx.x;  // 128 threads
  float V = 0.f;
  for (int b = 0; b < B_; b++) { float v = v_in[b * C_ + c]; V += v / (v + 1e-3f); }
  V *= (1.f / B_);
  float R = rsqrtf(V + 1e-5f);
  float gdp = dpg[c], bdp = dpb[c], gdu = dug[c], bdu = dub[c];
  for (int b = 0; b < B_; b++) {
    int i = b * C_ + c;
    float r = r_in[i], m = m_in[i];
    float sdp = r * R * gdp;
    a_dp[i] = sdp; d_dp[i] = -m * sdp + bdp;
    float sdu = r * R * gdu;
    a_du[i] = sdu; d_du[i] = -m * sdu + bdu;
  }
}

// ---------------------------------------------------------------------------
// 3) embed[b,k,n] = sum_c w[k,c]*relu(a[b,c]*x[b,c,n]+d[b,c]) + bias[k]
//    tile 128k x 128n, contraction c in chunks of 64, micro 8x8
// ---------------------------------------------------------------------------
__global__ __launch_bounds__(256) void k_embed(const float* __restrict__ x,
                                               const float* __restrict__ w,
                                               const float* __restrict__ bias,
                                               const float* __restrict__ aff_a,
                                               const float* __restrict__ aff_d,
                                               float* __restrict__ out) {
  const int b = blockIdx.z, k0 = blockIdx.y * 128, n0 = blockIdx.x * 128;
  __shared__ float w_s[64][133];   // [cc][kk]
  __shared__ float h_s[64][132];   // [cc][nn]
  const int tid = threadIdx.x;
  const int kg = tid / 16, ng = tid % 16;
  float acc[8][8] = {};
  for (int c0 = 0; c0 < C_; c0 += 64) {
    // stage W (transposed)
    for (int q = tid; q < 64 * 128 / 4; q += 256) {
      int kk = q / 16, c4 = q % 16;
      float4 v = *reinterpret_cast<const float4*>(w + (size_t)(k0 + kk) * C_ + c0 + c4 * 4);
      w_s[c4 * 4 + 0][kk] = v.x; w_s[c4 * 4 + 1][kk] = v.y;
      w_s[c4 * 4 + 2][kk] = v.z; w_s[c4 * 4 + 3][kk] = v.w;
    }
    // stage H = relu(a*x+d)
    for (int q = tid; q < 64 * 128 / 4; q += 256) {
      int cc = q / 32, n4 = q % 32;
      int c = c0 + cc;
      float a = aff_a[b * C_ + c], d = aff_d[b * C_ + c];
      float4 xv = *reinterpret_cast<const float4*>(x + (size_t)(b * C_ + c) * N_ + n0 + n4 * 4);
      float4 hv;
      hv.x = fmaxf(fmaf(a, xv.x, d), 0.f); hv.y = fmaxf(fmaf(a, xv.y, d), 0.f);
      hv.z = fmaxf(fmaf(a, xv.z, d), 0.f); hv.w = fmaxf(fmaf(a, xv.w, d), 0.f);
      *reinterpret_cast<float4*>(&h_s[cc][n4 * 4]) = hv;
    }
    __syncthreads();
    for (int cc = 0; cc < 64; ++cc) {
      float wv[8], hv[8];
#pragma unroll
      for (int i = 0; i < 8; ++i) wv[i] = w_s[cc][kg * 8 + i];
#pragma unroll
      for (int j = 0; j < 8; ++j) hv[j] = h_s[cc][ng + 16 * j];
#pragma unroll
      for (int i = 0; i < 8; ++i)
#pragma unroll
        for (int j = 0; j < 8; ++j) acc[i][j] = fmaf(wv[i], hv[j], acc[i][j]);
    }
    __syncthreads();
  }
#pragma unroll
  for (int i = 0; i < 8; ++i) {
    int k = k0 + kg * 8 + i;
    float bv = bias[k];
#pragma unroll
    for (int j = 0; j < 8; ++j)
      out[(size_t)(b * K_ + k) * N_ + n0 + ng + 16 * j] = acc[i][j] + bv;
  }
}

// ---------------------------------------------------------------------------
// 4) per-(b,k) row max + sum(exp) over N
// ---------------------------------------------------------------------------
__global__ __launch_bounds__(256) void k_rowstat(const float* __restrict__ EB,
                                                 float* __restrict__ mx, float* __restrict__ rden) {
  const int row = blockIdx.x;
  const float4* e = reinterpret_cast<const float4*>(EB + (size_t)row * N_);
  float m = -1e30f, s = 0.f;
  for (int i = threadIdx.x; i < N_ / 4; i += 256) {
    float4 v = e[i];
    float lm = fmaxf(fmaxf(v.x, v.y), fmaxf(v.z, v.w));
    if (lm > m) { s *= __expf(m - lm); m = lm; }
    s += __expf(v.x - m) + __expf(v.y - m) + __expf(v.z - m) + __expf(v.w - m);
  }
  __shared__ float rm[256], rsum[256];
  rm[threadIdx.x] = m; rsum[threadIdx.x] = s;
  __syncthreads();
  for (int st = 128; st > 0; st >>= 1) {
    if (threadIdx.x < st) {
      float m1 = rm[threadIdx.x], s1 = rsum[threadIdx.x];
      float m2 = rm[threadIdx.x + st], s2 = rsum[threadIdx.x + st];
      float M = fmaxf(m1, m2);
      rm[threadIdx.x] = M;
      rsum[threadIdx.x] = s1 * __expf(m1 - M) + s2 * __expf(m2 - M);
    }
    __syncthreads();
  }
  if (threadIdx.x == 0) { mx[row] = rm[0]; rden[row] = 1.f / rsum[0]; }
}

// ---------------------------------------------------------------------------
// 5) x_down partials: part[s][b][c][k] = sum_{n in split} x[b,c,n]*exp(EB-mx)
//    tile 128c x 128k, contraction n chunks of 64, micro 8x8
// ---------------------------------------------------------------------------
__global__ __launch_bounds__(256) void k_xdown(const float* __restrict__ x,
                                               const float* __restrict__ EB,
                                               const float* __restrict__ mx,
                                               float* __restrict__ part) {
  const int b = blockIdx.z, sp = blockIdx.y, k0 = blockIdx.x * 128;
  const int nbase = sp * 1024;
  __shared__ float x_s[64][133];  // [nn][cc]
  __shared__ float p_s[64][133];  // [nn][kk]
  const int tid = threadIdx.x;
  const int cg = tid / 16, kg = tid % 16;
  float acc[8][8] = {};
  for (int nc = 0; nc < 1024; nc += 64) {
    const int n0 = nbase + nc;
    for (int q = tid; q < 64 * 128 / 4; q += 256) {
      int cc = q / 16, n4 = q % 16;
      float4 v = *reinterpret_cast<const float4*>(x + (size_t)(b * C_ + cc) * N_ + n0 + n4 * 4);
      x_s[n4 * 4 + 0][cc] = v.x; x_s[n4 * 4 + 1][cc] = v.y;
      x_s[n4 * 4 + 2][cc] = v.z; x_s[n4 * 4 + 3][cc] = v.w;
    }
    for (int q = tid; q < 64 * 128 / 4; q += 256) {
      int kk = q / 16, n4 = q % 16;
      int k = k0 + kk;
      float mv = mx[b * K_ + k];
      float4 v = *reinterpret_cast<const float4*>(EB + (size_t)(b * K_ + k) * N_ + n0 + n4 * 4);
      p_s[n4 * 4 + 0][kk] = __expf(v.x - mv); p_s[n4 * 4 + 1][kk] = __expf(v.y - mv);
      p_s[n4 * 4 + 2][kk] = __expf(v.z - mv); p_s[n4 * 4 + 3][kk] = __expf(v.w - mv);
    }
    __syncthreads();
    for (int nn = 0; nn < 64; ++nn) {
      float xv[8], pv[8];
#pragma unroll
      for (int i = 0; i < 8; ++i) xv[i] = x_s[nn][cg * 8 + i];
#pragma unroll
      for (int j = 0; j < 8; ++j) pv[j] = p_s[nn][kg + 16 * j];
#pragma unroll
      for (int i = 0; i < 8; ++i)
#pragma unroll
        for (int j = 0; j < 8; ++j) acc[i][j] = fmaf(xv[i], pv[j], acc[i][j]);
    }
    __syncthreads();
  }
#pragma unroll
  for (int i = 0; i < 8; ++i) {
    int c = cg * 8 + i;
#pragma unroll
    for (int j = 0; j < 8; ++j)
      part[(((size_t)sp * B_ + b) * C_ + c) * K_ + k0 + kg + 16 * j] = acc[i][j];
  }
}

// 6) reduce split partials, scale by 1/den -> x_down[b][c][k]
__global__ __launch_bounds__(256) void k_xdown_red(const float* __restrict__ part,
                                                   const float* __restrict__ rden,
                                                   float* __restrict__ xd) {
  int e = blockIdx.x * 256 + threadIdx.x;  // B*C*K
  int k = e % K_;
  int c = (e / K_) % C_;
  int b = e / (K_ * C_);
  float s = 0.f;
  for (int sp = 0; sp < 8; sp++) s += part[(((size_t)sp * B_ + b) * C_ + c) * K_ + k];
  xd[e] = s * rden[b * K_ + k];
}

// ---------------------------------------------------------------------------
// 7) per-batch: gram over clusters + top-6 neighbors (feature-space KNN)
//    feats[b,ch=k,pt=p] = xd[b][p][k]
// ---------------------------------------------------------------------------
__global__ __launch_bounds__(256) void k_gram_topk(const float* __restrict__ xd,
                                                   int* __restrict__ idx) {
  const int b = blockIdx.x;
  __shared__ float Ds[64][133];     // [kk][p]
  __shared__ float pd_s[128][129];  // gram
  __shared__ float sq_s[128];
  const int tid = threadIdx.x;
  const int pg = tid / 16, qg = tid % 16;
  float acc[8][8] = {};
  for (int k0 = 0; k0 < K_; k0 += 64) {
    for (int q = tid; q < 64 * 128 / 4; q += 256) {
      int p = q / 16, k4 = q % 16;
      float4 v = *reinterpret_cast<const float4*>(xd + (size_t)(b * C_ + p) * K_ + k0 + k4 * 4);
      Ds[k4 * 4 + 0][p] = v.x; Ds[k4 * 4 + 1][p] = v.y;
      Ds[k4 * 4 + 2][p] = v.z; Ds[k4 * 4 + 3][p] = v.w;
    }
    __syncthreads();
    for (int kk = 0; kk < 64; ++kk) {
      float av[8], bv[8];
#pragma unroll
      for (int i = 0; i < 8; ++i) av[i] = Ds[kk][pg * 8 + i];
#pragma unroll
      for (int j = 0; j < 8; ++j) bv[j] = Ds[kk][qg + 16 * j];
#pragma unroll
      for (int i = 0; i < 8; ++i)
#pragma unroll
        for (int j = 0; j < 8; ++j) acc[i][j] = fmaf(av[i], bv[j], acc[i][j]);
    }
    __syncthreads();
  }
#pragma unroll
  for (int i = 0; i < 8; ++i)
#pragma unroll
    for (int j = 0; j < 8; ++j) pd_s[pg * 8 + i][qg + 16 * j] = acc[i][j];
  __syncthreads();
  if (tid < 128) sq_s[tid] = pd_s[tid][tid];
  __syncthreads();
  if (tid < 128) {
    const int p = tid;
    float bv[6]; int bi[6];
#pragma unroll
    for (int j = 0; j < 6; j++) { bv[j] = -1e30f; bi[j] = 0; }
    float sp2 = sq_s[p];
    for (int q = 0; q < 128; q++) {
      float v = 2.f * pd_s[p][q] - sp2 - sq_s[q];
      if (v > bv[5]) {
        int pos = 5;
        while (pos > 0 && v > bv[pos - 1]) { bv[pos] = bv[pos - 1]; bi[pos] = bi[pos - 1]; pos--; }
        bv[pos] = v; bi[pos] = q;
      }
    }
#pragma unroll
    for (int j = 0; j < 6; j++) idx[(b * P_ + p) * NB_ + j] = bi[j];
  }
}

// ---------------------------------------------------------------------------
// 8) U = (W1a+W1b)@feats ; V = W1b@feats   (which = blockIdx.x)
// ---------------------------------------------------------------------------
__global__ __launch_bounds__(256) void k_uv(const float* __restrict__ xd,
                                            const float* __restrict__ w1,
                                            float* __restrict__ U, float* __restrict__ V) {
  const int b = blockIdx.z, o0 = blockIdx.y * 128, which = blockIdx.x;
  __shared__ float a_s[64][133];  // [kk][oo]
  __shared__ float b_s[64][133];  // [kk][p]
  const int tid = threadIdx.x;
  const int og = tid / 16, pg = tid % 16;
  float acc[8][8] = {};
  for (int k0 = 0; k0 < K_; k0 += 64) {
    for (int q = tid; q < 64 * 128 / 4; q += 256) {
      int oo = q / 16, k4 = q % 16;
      const float* wr = w1 + (size_t)(o0 + oo) * 512 + k0 + k4 * 4;
      float4 vb = *reinterpret_cast<const float4*>(wr + 256);
      if (which == 0) {
        float4 va = *reinterpret_cast<const float4*>(wr);
        vb.x += va.x; vb.y += va.y; vb.z += va.z; vb.w += va.w;
      }
      a_s[k4 * 4 + 0][oo] = vb.x; a_s[k4 * 4 + 1][oo] = vb.y;
      a_s[k4 * 4 + 2][oo] = vb.z; a_s[k4 * 4 + 3][oo] = vb.w;
    }
    for (int q = tid; q < 64 * 128 / 4; q += 256) {
      int p = q / 16, k4 = q % 16;
      float4 v = *reinterpret_cast<const float4*>(xd + (size_t)(b * C_ + p) * K_ + k0 + k4 * 4);
      b_s[k4 * 4 + 0][p] = v.x; b_s[k4 * 4 + 1][p] = v.y;
      b_s[k4 * 4 + 2][p] = v.z; b_s[k4 * 4 + 3][p] = v.w;
    }
    __syncthreads();
    for (int kk = 0; kk < 64; ++kk) {
      float av[8], bv[8];
#pragma unroll
      for (int i = 0; i < 8; ++i) av[i] = a_s[kk][og * 8 + i];
#pragma unroll
      for (int j = 0; j < 8; ++j) bv[j] = b_s[kk][pg + 16 * j];
#pragma unroll
      for (int i = 0; i < 8; ++i)
#pragma unroll
        for (int j = 0; j < 8; ++j) acc[i][j] = fmaf(av[i], bv[j], acc[i][j]);
    }
    __syncthreads();
  }
  float* outp = (which == 0) ? U : V;
#pragma unroll
  for (int i = 0; i < 8; ++i)
#pragma unroll
    for (int j = 0; j < 8; ++j)
      outp[(size_t)(b * K_ + o0 + og * 8 + i) * P_ + pg + 16 * j] = acc[i][j];
}

// 9) g1[b,o,p,j] = U[p] - V[idx[p,j]] + b1[o]
__global__ __launch_bounds__(256) void k_edge(const float* __restrict__ U,
                                              const float* __restrict__ V,
                                              const int* __restrict__ idx,
                                              const float* __restrict__ b1,
                                              float* __restrict__ g1) {
  const int o = blockIdx.x, b = blockIdx.y;
  __shared__ float U_s[128], V_s[128];
  const int tid = threadIdx.x;
  if (tid < 128) {
    U_s[tid] = U[(size_t)(b * K_ + o) * P_ + tid];
    V_s[tid] = V[(size_t)(b * K_ + o) * P_ + tid];
  }
  __syncthreads();
  const float bias = b1[o];
  for (int e = tid; e < P_ * NB_; e += 256) {
    int p = e / NB_;
    int q = idx[b * P_ * NB_ + e];
    g1[(size_t)(b * K_ + o) * (P_ * NB_) + e] = U_s[p] + bias - V_s[q];
  }
}

// 10/12) BN stats per channel o over (b, p, j); emit scale/shift
__global__ __launch_bounds__(256) void k_bnstat(const float* __restrict__ g,
                                                const float* __restrict__ gamma,
                                                const float* __restrict__ beta,
                                                float* __restrict__ scale,
                                                float* __restrict__ shift) {
  const int o = blockIdx.x;
  float s = 0.f, ss = 0.f;
  for (int e = threadIdx.x; e < B_ * P_ * NB_; e += 256) {
    int b = e / (P_ * NB_), r = e % (P_ * NB_);
    float v = g[(size_t)(b * K_ + o) * (P_ * NB_) + r];
    s += v; ss += v * v;
  }
  __shared__ float rs[256], rq[256];
  rs[threadIdx.x] = s; rq[threadIdx.x] = ss;
  __syncthreads();
  for (int st = 128; st > 0; st >>= 1) {
    if (threadIdx.x < st) { rs[threadIdx.x] += rs[threadIdx.x + st]; rq[threadIdx.x] += rq[threadIdx.x + st]; }
    __syncthreads();
  }
  if (threadIdx.x == 0) {
    const float cnt = (float)(B_ * P_ * NB_);
    float m = rs[0] / cnt;
    float var = rq[0] / cnt - m * m;
    float sc = gamma[o] * rsqrtf(var + 1e-5f);
    scale[o] = sc; shift[o] = -m * sc + beta[o];
  }
}

// 11) g2 = W2 @ relu(bn1(g1)) + b2 ; tile 128o x 128pj
__global__ __launch_bounds__(256) void k_conv2(const float* __restrict__ g1,
                                               const float* __restrict__ w2,
                                               const float* __restrict__ b2,
                                               const float* __restrict__ bn1s,
                                               const float* __restrict__ bn1h,
                                               float* __restrict__ g2) {
  const int b = blockIdx.z, o0 = blockIdx.y * 128, n0 = blockIdx.x * 128;
  __shared__ float a_s[64][133];  // [cc][oo]
  __shared__ float b_s[64][132];  // [cc][nn]
  const int tid = threadIdx.x;
  const int og = tid / 16, ng = tid % 16;
  float acc[8][8] = {};
  for (int c0 = 0; c0 < K_; c0 += 64) {
    for (int q = tid; q < 64 * 128 / 4; q += 256) {
      int oo = q / 16, c4 = q % 16;
      float4 v = *reinterpret_cast<const float4*>(w2 + (size_t)(o0 + oo) * K_ + c0 + c4 * 4);
      a_s[c4 * 4 + 0][oo] = v.x; a_s[c4 * 4 + 1][oo] = v.y;
      a_s[c4 * 4 + 2][oo] = v.z; a_s[c4 * 4 + 3][oo] = v.w;
    }
    for (int q = tid; q < 64 * 128 / 4; q += 256) {
      int cc = q / 32, n4 = q % 32;
      int c = c0 + cc;
      float sc = bn1s[c], sh = bn1h[c];
      float4 v = *reinterpret_cast<const float4*>(g1 + (size_t)(b * K_ + c) * (P_ * NB_) + n0 + n4 * 4);
      float4 hv;
      hv.x = fmaxf(fmaf(sc, v.x, sh), 0.f); hv.y = fmaxf(fmaf(sc, v.y, sh), 0.f);
      hv.z = fmaxf(fmaf(sc, v.z, sh), 0.f); hv.w = fmaxf(fmaf(sc, v.w, sh), 0.f);
      *reinterpret_cast<float4*>(&b_s[cc][n4 * 4]) = hv;
    }
    __syncthreads();
    for (int cc = 0; cc < 64; ++cc) {
      float av[8], bv[8];
#pragma unroll
      for (int i = 0; i < 8; ++i) av[i] = a_s[cc][og * 8 + i];
#pragma unroll
      for (int j = 0; j < 8; ++j) bv[j] = b_s[cc][ng + 16 * j];
#pragma unroll
      for (int i = 0; i < 8; ++i)
#pragma unroll
        for (int j = 0; j < 8; ++j) acc[i][j] = fmaf(av[i], bv[j], acc[i][j]);
    }
    __syncthreads();
  }
#pragma unroll
  for (int i = 0; i < 8; ++i) {
    int o = o0 + og * 8 + i;
    float bb = b2[o];
#pragma unroll
    for (int j = 0; j < 8; ++j)
      g2[(size_t)(b * K_ + o) * (P_ * NB_) + n0 + ng + 16 * j] = acc[i][j] + bb;
  }
}

// 13) gmax[b][k][c] = max_j relu(bn2(g2))
__global__ __launch_bounds__(256) void k_gmax(const float* __restrict__ g2,
                                              const float* __restrict__ bn2s,
                                              const float* __restrict__ bn2h,
                                              float* __restrict__ gmax) {
  int e = blockIdx.x * 256 + threadIdx.x;  // B*K*P
  int c = e % P_;
  int k = (e / P_) % K_;
  int b = e / (P_ * K_);
  const float* gp = g2 + (size_t)(b * K_ + k) * (P_ * NB_) + c * NB_;
  float sc = bn2s[k], sh = bn2h[k];
  float m = 0.f;
#pragma unroll
  for (int j = 0; j < NB_; j++) m = fmaxf(m, fmaf(sc, gp[j], sh));
  gmax[e] = m;
}

// 14) M2[b][o][k] = sum_c sc_w[o,128+c] * gmax[b][k][c]
__global__ __launch_bounds__(256) void k_m2(const float* __restrict__ gmax,
                                            const float* __restrict__ scw,
                                            float* __restrict__ M2) {
  const int b = blockIdx.y, k0 = blockIdx.x * 128;
  __shared__ float a_s[64][133];  // [cc][oo]
  __shared__ float b_s[64][133];  // [cc][kk]
  const int tid = threadIdx.x;
  const int og = tid / 16, kg = tid % 16;
  float acc[8][8] = {};
  for (int c0 = 0; c0 < C_; c0 += 64) {
    for (int q = tid; q < 64 * 128 / 4; q += 256) {
      int oo = q / 16, c4 = q % 16;
      float4 v = *reinterpret_cast<const float4*>(scw + (size_t)oo * 256 + 128 + c0 + c4 * 4);
      a_s[c4 * 4 + 0][oo] = v.x; a_s[c4 * 4 + 1][oo] = v.y;
      a_s[c4 * 4 + 2][oo] = v.z; a_s[c4 * 4 + 3][oo] = v.w;
    }
    for (int q = tid; q < 64 * 128 / 4; q += 256) {
      int kk = q / 16, c4 = q % 16;
      float4 v = *reinterpret_cast<const float4*>(gmax + (size_t)(b * K_ + k0 + kk) * P_ + c0 + c4 * 4);
      b_s[c4 * 4 + 0][kk] = v.x; b_s[c4 * 4 + 1][kk] = v.y;
      b_s[c4 * 4 + 2][kk] = v.z; b_s[c4 * 4 + 3][kk] = v.w;
    }
    __syncthreads();
    for (int cc = 0; cc < 64; ++cc) {
      float av[8], bv[8];
#pragma unroll
      for (int i = 0; i < 8; ++i) av[i] = a_s[cc][og * 8 + i];
#pragma unroll
      for (int j = 0; j < 8; ++j) bv[j] = b_s[cc][kg + 16 * j];
#pragma unroll
      for (int i = 0; i < 8; ++i)
#pragma unroll
        for (int j = 0; j < 8; ++j) acc[i][j] = fmaf(av[i], bv[j], acc[i][j]);
    }
    __syncthreads();
  }
#pragma unroll
  for (int i = 0; i < 8; ++i)
#pragma unroll
    for (int j = 0; j < 8; ++j)
      M2[(size_t)(b * C_ + og * 8 + i) * K_ + k0 + kg + 16 * j] = acc[i][j];
}

// ---------------------------------------------------------------------------
// 16) out[b,o,n] = sum_c A[o,c] x[b,c,n] + sum_k M2[b,o,k] softmax_k(EB)[k,n] + scb[o]
//     per block: 32 points; softmax over k=256 in LDS; 4x4 micro GEMM
// ---------------------------------------------------------------------------
__global__ __launch_bounds__(256) void k_final(const float* __restrict__ EB,
                                               const float* __restrict__ x,
                                               const float* __restrict__ M2,
                                               const float* __restrict__ scw,
                                               const float* __restrict__ scb,
                                               float* __restrict__ out) {
  const int b = blockIdx.y, n0 = blockIdx.x * 32;
  __shared__ float e2_s[256][33];
  __shared__ float x_s[128][33];
  __shared__ float a_s[32][133];
  __shared__ float redm[8][33], reds[8][33];
  __shared__ float fm[32], fr[32];
  const int tid = threadIdx.x;
  for (int q = tid; q < 256 * 32 / 4; q += 256) {
    int k = q / 8, n4 = q % 8;
    float4 v = *reinterpret_cast<const float4*>(EB + (size_t)(b * K_ + k) * N_ + n0 + n4 * 4);
    e2_s[k][n4 * 4 + 0] = v.x; e2_s[k][n4 * 4 + 1] = v.y;
    e2_s[k][n4 * 4 + 2] = v.z; e2_s[k][n4 * 4 + 3] = v.w;
  }
  for (int q = tid; q < 128 * 32 / 4; q += 256) {
    int c = q / 8, n4 = q % 8;
    float4 v = *reinterpret_cast<const float4*>(x + (size_t)(b * C_ + c) * N_ + n0 + n4 * 4);
    x_s[c][n4 * 4 + 0] = v.x; x_s[c][n4 * 4 + 1] = v.y;
    x_s[c][n4 * 4 + 2] = v.z; x_s[c][n4 * 4 + 3] = v.w;
  }
  __syncthreads();
  // softmax over k per column
  const int col = tid % 32, sub = tid / 32;
  {
    float m = -1e30f, s = 0.f;
    for (int i = 0; i < 32; i++) {
      float v = e2_s[sub * 32 + i][col];
      if (v > m) { s *= __expf(m - v); m = v; }
      s += __expf(v - m);
    }
    redm[sub][col] = m; reds[sub][col] = s;
  }
  __syncthreads();
  if (sub == 0) {
    float M = redm[0][col], S = reds[0][col];
    for (int t = 1; t < 8; t++) {
      float m2 = redm[t][col], s2 = reds[t][col];
      float Mn = fmaxf(M, m2);
      S = S * __expf(M - Mn) + s2 * __expf(m2 - Mn);
      M = Mn;
    }
    fm[col] = M; fr[col] = 1.f / S;
  }
  __syncthreads();
  {
    float Mv = fm[col], Rv = fr[col];
    for (int i = 0; i < 32; i++) {
      int k = sub * 32 + i;
      e2_s[k][col] = __expf(e2_s[k][col] - Mv) * Rv;
    }
  }
  __syncthreads();
  // GEMM: out(128 x 32) = A@x + M2@S
  const int og = tid / 8, ng = tid % 8;  // o = og*4..+3, n = ng*4..+3
  float acc[4][4] = {};
  for (int c0 = 0; c0 < C_; c0 += 32) {
    for (int q = tid; q < 32 * 128 / 4; q += 256) {
      int oo = q / 8, c4 = q % 8;
      float4 v = *reinterpret_cast<const float4*>(scw + (size_t)oo * 256 + c0 + c4 * 4);
      a_s[c4 * 4 + 0][oo] = v.x; a_s[c4 * 4 + 1][oo] = v.y;
      a_s[c4 * 4 + 2][oo] = v.z; a_s[c4 * 4 + 3][oo] = v.w;
    }
    __syncthreads();
    for (int cc = 0; cc < 32; ++cc) {
      float av[4], xv[4];
#pragma unroll
      for (int i = 0; i < 4; ++i) av[i] = a_s[cc][og * 4 + i];
#pragma unroll
      for (int j = 0; j < 4; ++j) xv[j] = x_s[c0 + cc][ng * 4 + j];
#pragma unroll
      for (int i = 0; i < 4; ++i)
#pragma unroll
        for (int j = 0; j < 4; ++j) acc[i][j] = fmaf(av[i], xv[j], acc[i][j]);
    }
    __syncthreads();
  }
  for (int k0 = 0; k0 < K_; k0 += 32) {
    for (int q = tid; q < 32 * 128 / 4; q += 256) {
      int oo = q / 8, k4 = q % 8;
      float4 v = *reinterpret_cast<const float4*>(M2 + (size_t)(b * C_ + oo) * K_ + k0 + k4 * 4);
      a_s[k4 * 4 + 0][oo] = v.x; a_s[k4 * 4 + 1][oo] = v.y;
      a_s[k4 * 4 + 2][oo] = v.z; a_s[k4 * 4 + 3][oo] = v.w;
    }
    __syncthreads();
    for (int kk = 0; kk < 32; ++kk) {
      float av[4], sv[4];
#pragma unroll
      for (int i = 0; i < 4; ++i) av[i] = a_s[kk][og * 4 + i];
#pragma unroll
      for (int j = 0; j < 4; ++j) sv[j] = e2_s[k0 + kk][ng * 4 + j];
#pragma unroll
      for (int i = 0; i < 4; ++i)
#pragma unroll
        for (int j = 0; j < 4; ++j) acc[i][j] = fmaf(av[i], sv[j], acc[i][j]);
    }
    __syncthreads();
  }
#pragma unroll
  for (int i = 0; i < 4; ++i) {
    int o = og * 4 + i;
    float bv = scb[o];
    float4 r;
    r.x = acc[i][0] + bv; r.y = acc[i][1] + bv; r.z = acc[i][2] + bv; r.w = acc[i][3] + bv;
    *reinterpret_cast<float4*>(out + (size_t)(b * C_ + o) * N_ + n0 + ng * 4) = r;
  }
}

// ---------------------------------------------------------------------------
extern "C" void kernel_launch(void* const* d_in, const int* in_sizes, int n_in,
                              void* d_out, int out_size, void* d_ws, size_t ws_size,
                              hipStream_t stream) {
  (void)in_sizes; (void)n_in; (void)out_size; (void)ws_size;
  const float* x      = (const float*)d_in[0];
  const float* dpg    = (const float*)d_in[1];
  const float* dpb    = (const float*)d_in[2];
  const float* dpw    = (const float*)d_in[3];
  const float* dpbias = (const float*)d_in[4];
  const float* dug    = (const float*)d_in[5];
  const float* dub    = (const float*)d_in[6];
  const float* duw    = (const float*)d_in[7];
  const float* dubias = (const float*)d_in[8];
  const float* w1     = (const float*)d_in[9];
  const float* b1     = (const float*)d_in[10];
  const float* g1g    = (const float*)d_in[11];
  const float* g1b    = (const float*)d_in[12];
  const float* w2     = (const float*)d_in[13];
  const float* b2     = (const float*)d_in[14];
  const float* g2g    = (const float*)d_in[15];
  const float* g2b    = (const float*)d_in[16];
  const float* scw    = (const float*)d_in[17];
  const float* scb    = (const float*)d_in[18];
  float* out = (float*)d_out;
  float* ws  = (float*)d_ws;

  float* EB    = ws;                 // 33,554,432 floats (B*K*N)
  float* m_in  = EB + 33554432;      // 2048
  float* v_in  = m_in + 2048;
  float* r_in  = v_in + 2048;
  float* a_dp  = r_in + 2048;
  float* d_dp  = a_dp + 2048;
  float* a_du  = d_dp + 2048;
  float* d_du  = a_du + 2048;
  float* mx    = d_du + 2048;        // 4096
  float* rden  = mx + 4096;          // 4096
  float* xd    = rden + 4096;        // 524288
  float* U     = xd + 524288;        // 524288
  float* V     = U + 524288;         // 524288
  int*   idxb  = (int*)(V + 524288); // 12288
  float* g1buf = (float*)(idxb + 12288);   // 3,145,728
  float* g2buf = g1buf + 3145728;          // 3,145,728
  float* bn1s  = g2buf + 3145728;    // 256
  float* bn1h  = bn1s + 256;
  float* bn2s  = bn1h + 256;
  float* bn2h  = bn2s + 256;
  float* gmax  = bn2h + 256;         // 524288
  float* M2    = gmax + 524288;      // 524288
  // split-k partials alias the (later-used) g1/g2 region: 4,194,304 floats
  float* part  = g1buf;

  k_instat<<<dim3(B_ * C_), 256, 0, stream>>>(x, m_in, v_in, r_in);
  k_affine<<<1, 128, 0, stream>>>(m_in, v_in, r_in, dpg, dpb, dug, dub, a_dp, d_dp, a_du, d_du);
  k_embed<<<dim3(64, 2, 16), 256, 0, stream>>>(x, dpw, dpbias, a_dp, d_dp, EB);
  k_rowstat<<<dim3(B_ * K_), 256, 0, stream>>>(EB, mx, rden);
  k_xdown<<<dim3(2, 8, 16), 256, 0, stream>>>(x, EB, mx, part);
  k_xdown_red<<<dim3(2048), 256, 0, stream>>>(part, rden, xd);
  k_gram_topk<<<dim3(16), 256, 0, stream>>>(xd, idxb);
  k_uv<<<dim3(2, 2, 16), 256, 0, stream>>>(xd, w1, U, V);
  k_edge<<<dim3(256, 16), 256, 0, stream>>>(U, V, idxb, b1, g1buf);
  k_bnstat<<<dim3(256), 256, 0, stream>>>(g1buf, g1g, g1b, bn1s, bn1h);
  k_conv2<<<dim3(6, 2, 16), 256, 0, stream>>>(g1buf, w2, b2, bn1s, bn1h, g2buf);
  k_bnstat<<<dim3(256), 256, 0, stream>>>(g2buf, g2g, g2b, bn2s, bn2h);
  k_gmax<<<dim3(2048), 256, 0, stream>>>(g2buf, bn2s, bn2h, gmax);
  k_m2<<<dim3(2, 16), 256, 0, stream>>>(gmax, scw, M2);
  k_embed<<<dim3(64, 2, 16), 256, 0, stream>>>(x, duw, dubias, a_du, d_du, EB);
  k_final<<<dim3(256, 16), 256, 0, stream>>>(EB, x, M2, scw, scb, out);
}

// Round 2
// 553.696 us; speedup vs baseline: 1.8926x; 1.8926x over previous
//
#include <hip/hip_runtime.h>

typedef __attribute__((ext_vector_type(4))) float f32x4;
typedef __attribute__((ext_vector_type(8))) short s16x8;
typedef __attribute__((ext_vector_type(8))) unsigned short u16x8;
typedef __attribute__((ext_vector_type(4))) unsigned short u16x4;

namespace {
constexpr int B_ = 16, C_ = 128, N_ = 8192, K_ = 256, P_ = 128, NB_ = 6;
}

__device__ __forceinline__ float bf2f(unsigned short h) {
  return __uint_as_float(((unsigned int)h) << 16);
}
__device__ __forceinline__ unsigned short f2bf(float f) {
  unsigned int u = __float_as_uint(f);
  return (unsigned short)((u + 0x7fffu + ((u >> 16) & 1u)) >> 16);
}

// ---------------------------------------------------------------------------
// 0) transpose + convert: xh[b][n][c] bf16 from x[b][c][n] fp32
// ---------------------------------------------------------------------------
__global__ __launch_bounds__(256) void k_prep(const float* __restrict__ x,
                                              unsigned short* __restrict__ xh) {
  const int chunk = blockIdx.x, b = blockIdx.y;
  const int n0 = chunk * 64;
  __shared__ float ts[64][132];
  const int tid = threadIdx.x;
  for (int i = 0; i < 8; i++) {
    int q = tid + i * 256;
    int n4 = q & 15, c = q >> 4;
    float4 v = *reinterpret_cast<const float4*>(x + (size_t)(b * C_ + c) * N_ + n0 + 4 * n4);
    ts[4 * n4 + 0][c] = v.x; ts[4 * n4 + 1][c] = v.y;
    ts[4 * n4 + 2][c] = v.z; ts[4 * n4 + 3][c] = v.w;
  }
  __syncthreads();
  for (int i = 0; i < 4; i++) {
    int q = tid + i * 256;
    int cg = q & 15, nn = q >> 4;
    u16x8 o;
#pragma unroll
    for (int j = 0; j < 8; j++) o[j] = f2bf(ts[nn][8 * cg + j]);
    *reinterpret_cast<u16x8*>(xh + (size_t)(b * N_ + n0 + nn) * C_ + 8 * cg) = o;
  }
}

// ---------------------------------------------------------------------------
// 1) per-(b,c) instance-norm stats over N
// ---------------------------------------------------------------------------
__global__ __launch_bounds__(256) void k_instat(const float* __restrict__ x,
                                                float* __restrict__ m_o,
                                                float* __restrict__ v_o,
                                                float* __restrict__ r_o) {
  const int row = blockIdx.x;  // b*C + c
  const float4* xr = reinterpret_cast<const float4*>(x + (size_t)row * N_);
  float s = 0.f, ss = 0.f;
  for (int i = threadIdx.x; i < N_ / 4; i += 256) {
    float4 v = xr[i];
    s += v.x + v.y + v.z + v.w;
    ss += v.x * v.x + v.y * v.y + v.z * v.z + v.w * v.w;
  }
  __shared__ float rs[256], rq[256];
  rs[threadIdx.x] = s; rq[threadIdx.x] = ss;
  __syncthreads();
  for (int st = 128; st > 0; st >>= 1) {
    if (threadIdx.x < st) { rs[threadIdx.x] += rs[threadIdx.x + st]; rq[threadIdx.x] += rq[threadIdx.x + st]; }
    __syncthreads();
  }
  if (threadIdx.x == 0) {
    float m = rs[0] / N_;
    float v = rq[0] / N_ - m * m;
    m_o[row] = m; v_o[row] = v; r_o[row] = rsqrtf(v + 1e-3f);
  }
}

// ---------------------------------------------------------------------------
// 2) fold IN+BN into per-(b,c) affine (BN mean of IN(x) is analytically 0)
// ---------------------------------------------------------------------------
__global__ void k_affine(const float* __restrict__ m_in, const float* __restrict__ v_in,
                         const float* __restrict__ r_in,
                         const float* __restrict__ dpg, const float* __restrict__ dpb,
                         const float* __restrict__ dug, const float* __restrict__ dub,
                         float* __restrict__ a_dp, float* __restrict__ d_dp,
                         float* __restrict__ a_du, float* __restrict__ d_du) {
  int c = threadIdx.x;  // 128 threads
  float V = 0.f;
  for (int b = 0; b < B_; b++) { float v = v_in[b * C_ + c]; V += v / (v + 1e-3f); }
  V *= (1.f / B_);
  float R = rsqrtf(V + 1e-5f);
  float gdp = dpg[c], bdp = dpb[c], gdu = dug[c], bdu = dub[c];
  for (int b = 0; b < B_; b++) {
    int i = b * C_ + c;
    float r = r_in[i], m = m_in[i];
    float sdp = r * R * gdp;
    a_dp[i] = sdp; d_dp[i] = -m * sdp + bdp;
    float sdu = r * R * gdu;
    a_du[i] = sdu; d_du[i] = -m * sdu + bdu;
  }
}

// ---------------------------------------------------------------------------
// 3) embed MFMA: out[k,n] = sum_c w[k,c]*relu(a*x+d) + bias  (bf16 MFMA)
//    MODE 0: write EB [b][k][n] bf16 ; MODE 1: write EBT [b][n][k] bf16
// ---------------------------------------------------------------------------
template <int MODE>
__global__ __launch_bounds__(256) void k_embed_mfma(const unsigned short* __restrict__ xh,
                                                    const float* __restrict__ w,
                                                    const float* __restrict__ bias,
                                                    const float* __restrict__ aff_a,
                                                    const float* __restrict__ aff_d,
                                                    unsigned short* __restrict__ outp) {
  const int n0 = blockIdx.x * 128, k0 = blockIdx.y * 128, b = blockIdx.z;
  __shared__ __align__(16) unsigned short smem[2 * 128 * 72];
  unsigned short (*a_s)[72] = reinterpret_cast<unsigned short(*)[72]>(smem);         // [k][c]
  unsigned short (*b_s)[72] = reinterpret_cast<unsigned short(*)[72]>(smem + 128 * 72); // [n][c]
  unsigned short (*e_s)[136] = reinterpret_cast<unsigned short(*)[136]>(smem);       // epilogue
  __shared__ float aff_as[128], aff_ds[128], bias_s[128];
  const int tid = threadIdx.x;
  const int lane = tid & 63, wid = tid >> 6;
  const int wr = wid >> 1, wc = wid & 1;
  const int l15 = lane & 15, l4 = lane >> 4;
  if (tid < 128) {
    aff_as[tid] = aff_a[b * C_ + tid];
    aff_ds[tid] = aff_d[b * C_ + tid];
    bias_s[tid] = bias[k0 + tid];
  }
  __syncthreads();
  f32x4 acc[4][4] = {};
  for (int c0 = 0; c0 < C_; c0 += 64) {
    for (int i = 0; i < 8; i++) {
      int q = tid + i * 256;
      int cq = q & 15, kk = q >> 4;
      float4 v = *reinterpret_cast<const float4*>(w + (size_t)(k0 + kk) * C_ + c0 + 4 * cq);
      u16x4 p; p[0] = f2bf(v.x); p[1] = f2bf(v.y); p[2] = f2bf(v.z); p[3] = f2bf(v.w);
      *reinterpret_cast<u16x4*>(&a_s[kk][4 * cq]) = p;
    }
    for (int i = 0; i < 4; i++) {
      int q = tid + i * 256;
      int co = q & 7, nn = q >> 3;
      u16x8 v = *reinterpret_cast<const u16x8*>(xh + (size_t)(b * N_ + n0 + nn) * C_ + c0 + 8 * co);
      u16x8 h;
#pragma unroll
      for (int j = 0; j < 8; j++) {
        int c = c0 + 8 * co + j;
        h[j] = f2bf(fmaxf(fmaf(aff_as[c], bf2f(v[j]), aff_ds[c]), 0.f));
      }
      *reinterpret_cast<u16x8*>(&b_s[nn][8 * co]) = h;
    }
    __syncthreads();
#pragma unroll
    for (int ks = 0; ks < 64; ks += 32) {
      s16x8 af[4], bfv[4];
#pragma unroll
      for (int m = 0; m < 4; m++)
        af[m] = *reinterpret_cast<const s16x8*>(&a_s[wr * 64 + m * 16 + l15][ks + 8 * l4]);
#pragma unroll
      for (int n = 0; n < 4; n++)
        bfv[n] = *reinterpret_cast<const s16x8*>(&b_s[wc * 64 + n * 16 + l15][ks + 8 * l4]);
#pragma unroll
      for (int m = 0; m < 4; m++)
#pragma unroll
        for (int n = 0; n < 4; n++)
          acc[m][n] = __builtin_amdgcn_mfma_f32_16x16x32_bf16(af[m], bfv[n], acc[m][n], 0, 0, 0);
    }
    __syncthreads();
  }
#pragma unroll
  for (int m = 0; m < 4; m++)
#pragma unroll
    for (int n = 0; n < 4; n++) {
      int kl = wr * 64 + m * 16 + 4 * l4;
      int nl = wc * 64 + n * 16 + l15;
#pragma unroll
      for (int r = 0; r < 4; r++)
        e_s[kl + r][nl] = f2bf(acc[m][n][r] + bias_s[kl + r]);
    }
  __syncthreads();
  if (MODE == 0) {
    for (int i = 0; i < 8; i++) {
      int q = tid + i * 256;
      int cg = q & 15, kk = q >> 4;
      u16x8 v = *reinterpret_cast<const u16x8*>(&e_s[kk][8 * cg]);
      *reinterpret_cast<u16x8*>(outp + (size_t)(b * K_ + k0 + kk) * N_ + n0 + 8 * cg) = v;
    }
  } else {
    for (int i = 0; i < 8; i++) {
      int q = tid + i * 256;
      int kg = q & 15, nn = q >> 4;
      u16x8 v;
#pragma unroll
      for (int j = 0; j < 8; j++) v[j] = e_s[8 * kg + j][nn];
      *reinterpret_cast<u16x8*>(outp + (size_t)(b * N_ + n0 + nn) * K_ + k0 + 8 * kg) = v;
    }
  }
}

// ---------------------------------------------------------------------------
// 4) per-(b,k) row max + sum(exp) over N (bf16 input)
// ---------------------------------------------------------------------------
__global__ __launch_bounds__(256) void k_rowstat(const unsigned short* __restrict__ EB,
                                                 float* __restrict__ mx, float* __restrict__ rden) {
  const int row = blockIdx.x;
  float m = -1e30f, s = 0.f;
  for (int i = threadIdx.x; i < N_ / 8; i += 256) {
    u16x8 v = *reinterpret_cast<const u16x8*>(EB + (size_t)row * N_ + 8 * i);
    float f[8];
#pragma unroll
    for (int j = 0; j < 8; j++) f[j] = bf2f(v[j]);
    float lm = f[0];
#pragma unroll
    for (int j = 1; j < 8; j++) lm = fmaxf(lm, f[j]);
    if (lm > m) { s *= __expf(m - lm); m = lm; }
#pragma unroll
    for (int j = 0; j < 8; j++) s += __expf(f[j] - m);
  }
  __shared__ float rm[256], rsum[256];
  rm[threadIdx.x] = m; rsum[threadIdx.x] = s;
  __syncthreads();
  for (int st = 128; st > 0; st >>= 1) {
    if (threadIdx.x < st) {
      float m1 = rm[threadIdx.x], s1 = rsum[threadIdx.x];
      float m2 = rm[threadIdx.x + st], s2 = rsum[threadIdx.x + st];
      float M = fmaxf(m1, m2);
      rm[threadIdx.x] = M;
      rsum[threadIdx.x] = s1 * __expf(m1 - M) + s2 * __expf(m2 - M);
    }
    __syncthreads();
  }
  if (threadIdx.x == 0) { mx[row] = rm[0]; rden[row] = 1.f / rsum[0]; }
}

// ---------------------------------------------------------------------------
// 5) x_down partials via MFMA: part[sp][b][c][k] = sum_n x[c,n]*exp(EB[k,n]-mx)
// ---------------------------------------------------------------------------
__global__ __launch_bounds__(256) void k_xdown_mfma(const float* __restrict__ x,
                                                    const unsigned short* __restrict__ EB,
                                                    const float* __restrict__ mx,
                                                    float* __restrict__ part) {
  const int k0 = blockIdx.x * 128, sp = blockIdx.y, b = blockIdx.z;
  const int nbase = sp * 1024;
  __shared__ __align__(16) unsigned short a_s[128][72];  // [c][n]
  __shared__ __align__(16) unsigned short p_s[128][72];  // [k][n]
  __shared__ float mxs[128];
  const int tid = threadIdx.x, lane = tid & 63, wid = tid >> 6;
  const int wr = wid >> 1, wc = wid & 1, l15 = lane & 15, l4 = lane >> 4;
  if (tid < 128) mxs[tid] = mx[b * K_ + k0 + tid];
  __syncthreads();
  f32x4 acc[4][4] = {};
  for (int nc = 0; nc < 1024; nc += 64) {
    const int n0 = nbase + nc;
    for (int i = 0; i < 8; i++) {
      int q = tid + i * 256;
      int nq = q & 15, cc = q >> 4;
      float4 v = *reinterpret_cast<const float4*>(x + (size_t)(b * C_ + cc) * N_ + n0 + 4 * nq);
      u16x4 p; p[0] = f2bf(v.x); p[1] = f2bf(v.y); p[2] = f2bf(v.z); p[3] = f2bf(v.w);
      *reinterpret_cast<u16x4*>(&a_s[cc][4 * nq]) = p;
    }
    for (int i = 0; i < 4; i++) {
      int q = tid + i * 256;
      int nq = q & 7, kk = q >> 3;
      u16x8 v = *reinterpret_cast<const u16x8*>(EB + (size_t)(b * K_ + k0 + kk) * N_ + n0 + 8 * nq);
      float mv = mxs[kk];
      u16x8 p;
#pragma unroll
      for (int j = 0; j < 8; j++) p[j] = f2bf(__expf(bf2f(v[j]) - mv));
      *reinterpret_cast<u16x8*>(&p_s[kk][8 * nq]) = p;
    }
    __syncthreads();
#pragma unroll
    for (int ks = 0; ks < 64; ks += 32) {
      s16x8 af[4], bfv[4];
#pragma unroll
      for (int m = 0; m < 4; m++)
        af[m] = *reinterpret_cast<const s16x8*>(&a_s[wr * 64 + m * 16 + l15][ks + 8 * l4]);
#pragma unroll
      for (int n = 0; n < 4; n++)
        bfv[n] = *reinterpret_cast<const s16x8*>(&p_s[wc * 64 + n * 16 + l15][ks + 8 * l4]);
#pragma unroll
      for (int m = 0; m < 4; m++)
#pragma unroll
        for (int n = 0; n < 4; n++)
          acc[m][n] = __builtin_amdgcn_mfma_f32_16x16x32_bf16(af[m], bfv[n], acc[m][n], 0, 0, 0);
    }
    __syncthreads();
  }
#pragma unroll
  for (int m = 0; m < 4; m++)
#pragma unroll
    for (int n = 0; n < 4; n++) {
      int c = wr * 64 + m * 16 + 4 * l4;
      int k = k0 + wc * 64 + n * 16 + l15;
#pragma unroll
      for (int r = 0; r < 4; r++)
        part[((size_t)(sp * B_ + b) * C_ + c + r) * K_ + k] = acc[m][n][r];
    }
}

// 6) reduce split partials, scale by 1/den -> x_down[b][c][k]
__global__ __launch_bounds__(256) void k_xdown_red(const float* __restrict__ part,
                                                   const float* __restrict__ rden,
                                                   float* __restrict__ xd) {
  int e = blockIdx.x * 256 + threadIdx.x;  // B*C*K
  int k = e % K_;
  int c = (e / K_) % C_;
  int b = e / (K_ * C_);
  float s = 0.f;
  for (int sp = 0; sp < 8; sp++) s += part[((size_t)(sp * B_ + b) * C_ + c) * K_ + k];
  xd[e] = s * rden[b * K_ + k];
}

// ---------------------------------------------------------------------------
// 7) per-batch gram + top-6 neighbors (fp32, unchanged)
// ---------------------------------------------------------------------------
__global__ __launch_bounds__(256) void k_gram_topk(const float* __restrict__ xd,
                                                   int* __restrict__ idx) {
  const int b = blockIdx.x;
  __shared__ float Ds[64][133];
  __shared__ float pd_s[128][129];
  __shared__ float sq_s[128];
  const int tid = threadIdx.x;
  const int pg = tid / 16, qg = tid % 16;
  float acc[8][8] = {};
  for (int k0 = 0; k0 < K_; k0 += 64) {
    for (int q = tid; q < 64 * 128 / 4; q += 256) {
      int p = q / 16, k4 = q % 16;
      float4 v = *reinterpret_cast<const float4*>(xd + (size_t)(b * C_ + p) * K_ + k0 + k4 * 4);
      Ds[k4 * 4 + 0][p] = v.x; Ds[k4 * 4 + 1][p] = v.y;
      Ds[k4 * 4 + 2][p] = v.z; Ds[k4 * 4 + 3][p] = v.w;
    }
    __syncthreads();
    for (int kk = 0; kk < 64; ++kk) {
      float av[8], bv[8];
#pragma unroll
      for (int i = 0; i < 8; ++i) av[i] = Ds[kk][pg * 8 + i];
#pragma unroll
      for (int j = 0; j < 8; ++j) bv[j] = Ds[kk][qg + 16 * j];
#pragma unroll
      for (int i = 0; i < 8; ++i)
#pragma unroll
        for (int j = 0; j < 8; ++j) acc[i][j] = fmaf(av[i], bv[j], acc[i][j]);
    }
    __syncthreads();
  }
#pragma unroll
  for (int i = 0; i < 8; ++i)
#pragma unroll
    for (int j = 0; j < 8; ++j) pd_s[pg * 8 + i][qg + 16 * j] = acc[i][j];
  __syncthreads();
  if (tid < 128) sq_s[tid] = pd_s[tid][tid];
  __syncthreads();
  if (tid < 128) {
    const int p = tid;
    float bv[6]; int bi[6];
#pragma unroll
    for (int j = 0; j < 6; j++) { bv[j] = -1e30f; bi[j] = 0; }
    float sp2 = sq_s[p];
    for (int q = 0; q < 128; q++) {
      float v = 2.f * pd_s[p][q] - sp2 - sq_s[q];
      if (v > bv[5]) {
        int pos = 5;
        while (pos > 0 && v > bv[pos - 1]) { bv[pos] = bv[pos - 1]; bi[pos] = bi[pos - 1]; pos--; }
        bv[pos] = v; bi[pos] = q;
      }
    }
#pragma unroll
    for (int j = 0; j < 6; j++) idx[(b * P_ + p) * NB_ + j] = bi[j];
  }
}

// ---------------------------------------------------------------------------
// 8) U = (W1a+W1b)@feats ; V = W1b@feats  (fp32, unchanged)
// ---------------------------------------------------------------------------
__global__ __launch_bounds__(256) void k_uv(const float* __restrict__ xd,
                                            const float* __restrict__ w1,
                                            float* __restrict__ U, float* __restrict__ V) {
  const int b = blockIdx.z, o0 = blockIdx.y * 128, which = blockIdx.x;
  __shared__ float a_s[64][133];
  __shared__ float b_s[64][133];
  const int tid = threadIdx.x;
  const int og = tid / 16, pg = tid % 16;
  float acc[8][8] = {};
  for (int k0 = 0; k0 < K_; k0 += 64) {
    for (int q = tid; q < 64 * 128 / 4; q += 256) {
      int oo = q / 16, k4 = q % 16;
      const float* wr = w1 + (size_t)(o0 + oo) * 512 + k0 + k4 * 4;
      float4 vb = *reinterpret_cast<const float4*>(wr + 256);
      if (which == 0) {
        float4 va = *reinterpret_cast<const float4*>(wr);
        vb.x += va.x; vb.y += va.y; vb.z += va.z; vb.w += va.w;
      }
      a_s[k4 * 4 + 0][oo] = vb.x; a_s[k4 * 4 + 1][oo] = vb.y;
      a_s[k4 * 4 + 2][oo] = vb.z; a_s[k4 * 4 + 3][oo] = vb.w;
    }
    for (int q = tid; q < 64 * 128 / 4; q += 256) {
      int p = q / 16, k4 = q % 16;
      float4 v = *reinterpret_cast<const float4*>(xd + (size_t)(b * C_ + p) * K_ + k0 + k4 * 4);
      b_s[k4 * 4 + 0][p] = v.x; b_s[k4 * 4 + 1][p] = v.y;
      b_s[k4 * 4 + 2][p] = v.z; b_s[k4 * 4 + 3][p] = v.w;
    }
    __syncthreads();
    for (int kk = 0; kk < 64; ++kk) {
      float av[8], bv[8];
#pragma unroll
      for (int i = 0; i < 8; ++i) av[i] = a_s[kk][og * 8 + i];
#pragma unroll
      for (int j = 0; j < 8; ++j) bv[j] = b_s[kk][pg + 16 * j];
#pragma unroll
      for (int i = 0; i < 8; ++i)
#pragma unroll
        for (int j = 0; j < 8; ++j) acc[i][j] = fmaf(av[i], bv[j], acc[i][j]);
    }
    __syncthreads();
  }
  float* outp = (which == 0) ? U : V;
#pragma unroll
  for (int i = 0; i < 8; ++i)
#pragma unroll
    for (int j = 0; j < 8; ++j)
      outp[(size_t)(b * K_ + o0 + og * 8 + i) * P_ + pg + 16 * j] = acc[i][j];
}

// 9) g1[b,o,p,j] = U[p] - V[idx[p,j]] + b1[o]
__global__ __launch_bounds__(256) void k_edge(const float* __restrict__ U,
                                              const float* __restrict__ V,
                                              const int* __restrict__ idx,
                                              const float* __restrict__ b1,
                                              float* __restrict__ g1) {
  const int o = blockIdx.x, b = blockIdx.y;
  __shared__ float U_s[128], V_s[128];
  const int tid = threadIdx.x;
  if (tid < 128) {
    U_s[tid] = U[(size_t)(b * K_ + o) * P_ + tid];
    V_s[tid] = V[(size_t)(b * K_ + o) * P_ + tid];
  }
  __syncthreads();
  const float bias = b1[o];
  for (int e = tid; e < P_ * NB_; e += 256) {
    int p = e / NB_;
    int q = idx[b * P_ * NB_ + e];
    g1[(size_t)(b * K_ + o) * (P_ * NB_) + e] = U_s[p] + bias - V_s[q];
  }
}

// 10/12) BN stats per channel o over (b,p,j)
__global__ __launch_bounds__(256) void k_bnstat(const float* __restrict__ g,
                                                const float* __restrict__ gamma,
                                                const float* __restrict__ beta,
                                                float* __restrict__ scale,
                                                float* __restrict__ shift) {
  const int o = blockIdx.x;
  float s = 0.f, ss = 0.f;
  for (int e = threadIdx.x; e < B_ * P_ * NB_; e += 256) {
    int b = e / (P_ * NB_), r = e % (P_ * NB_);
    float v = g[(size_t)(b * K_ + o) * (P_ * NB_) + r];
    s += v; ss += v * v;
  }
  __shared__ float rs[256], rq[256];
  rs[threadIdx.x] = s; rq[threadIdx.x] = ss;
  __syncthreads();
  for (int st = 128; st > 0; st >>= 1) {
    if (threadIdx.x < st) { rs[threadIdx.x] += rs[threadIdx.x + st]; rq[threadIdx.x] += rq[threadIdx.x + st]; }
    __syncthreads();
  }
  if (threadIdx.x == 0) {
    const float cnt = (float)(B_ * P_ * NB_);
    float m = rs[0] / cnt;
    float var = rq[0] / cnt - m * m;
    float sc = gamma[o] * rsqrtf(var + 1e-5f);
    scale[o] = sc; shift[o] = -m * sc + beta[o];
  }
}

// 11) g2 = W2 @ relu(bn1(g1)) + b2 (fp32, unchanged)
__global__ __launch_bounds__(256) void k_conv2(const float* __restrict__ g1,
                                               const float* __restrict__ w2,
                                               const float* __restrict__ b2,
                                               const float* __restrict__ bn1s,
                                               const float* __restrict__ bn1h,
                                               float* __restrict__ g2) {
  const int b = blockIdx.z, o0 = blockIdx.y * 128, n0 = blockIdx.x * 128;
  __shared__ float a_s[64][133];
  __shared__ float b_s[64][132];
  const int tid = threadIdx.x;
  const int og = tid / 16, ng = tid % 16;
  float acc[8][8] = {};
  for (int c0 = 0; c0 < K_; c0 += 64) {
    for (int q = tid; q < 64 * 128 / 4; q += 256) {
      int oo = q / 16, c4 = q % 16;
      float4 v = *reinterpret_cast<const float4*>(w2 + (size_t)(o0 + oo) * K_ + c0 + c4 * 4);
      a_s[c4 * 4 + 0][oo] = v.x; a_s[c4 * 4 + 1][oo] = v.y;
      a_s[c4 * 4 + 2][oo] = v.z; a_s[c4 * 4 + 3][oo] = v.w;
    }
    for (int q = tid; q < 64 * 128 / 4; q += 256) {
      int cc = q / 32, n4 = q % 32;
      int c = c0 + cc;
      float sc = bn1s[c], sh = bn1h[c];
      float4 v = *reinterpret_cast<const float4*>(g1 + (size_t)(b * K_ + c) * (P_ * NB_) + n0 + n4 * 4);
      float4 hv;
      hv.x = fmaxf(fmaf(sc, v.x, sh), 0.f); hv.y = fmaxf(fmaf(sc, v.y, sh), 0.f);
      hv.z = fmaxf(fmaf(sc, v.z, sh), 0.f); hv.w = fmaxf(fmaf(sc, v.w, sh), 0.f);
      *reinterpret_cast<float4*>(&b_s[cc][n4 * 4]) = hv;
    }
    __syncthreads();
    for (int cc = 0; cc < 64; ++cc) {
      float av[8], bv[8];
#pragma unroll
      for (int i = 0; i < 8; ++i) av[i] = a_s[cc][og * 8 + i];
#pragma unroll
      for (int j = 0; j < 8; ++j) bv[j] = b_s[cc][ng + 16 * j];
#pragma unroll
      for (int i = 0; i < 8; ++i)
#pragma unroll
        for (int j = 0; j < 8; ++j) acc[i][j] = fmaf(av[i], bv[j], acc[i][j]);
    }
    __syncthreads();
  }
#pragma unroll
  for (int i = 0; i < 8; ++i) {
    int o = o0 + og * 8 + i;
    float bb = b2[o];
#pragma unroll
    for (int j = 0; j < 8; ++j)
      g2[(size_t)(b * K_ + o) * (P_ * NB_) + n0 + ng + 16 * j] = acc[i][j] + bb;
  }
}

// 13) gmax[b][k][c] = max_j relu(bn2(g2))
__global__ __launch_bounds__(256) void k_gmax(const float* __restrict__ g2,
                                              const float* __restrict__ bn2s,
                                              const float* __restrict__ bn2h,
                                              float* __restrict__ gmax) {
  int e = blockIdx.x * 256 + threadIdx.x;  // B*K*P
  int c = e % P_;
  int k = (e / P_) % K_;
  int b = e / (P_ * K_);
  const float* gp = g2 + (size_t)(b * K_ + k) * (P_ * NB_) + c * NB_;
  float sc = bn2s[k], sh = bn2h[k];
  float m = 0.f;
#pragma unroll
  for (int j = 0; j < NB_; j++) m = fmaxf(m, fmaf(sc, gp[j], sh));
  gmax[e] = m;
}

// 14) M2[b][o][k] = sum_c sc_w[o,128+c] * gmax[b][k][c]
__global__ __launch_bounds__(256) void k_m2(const float* __restrict__ gmax,
                                            const float* __restrict__ scw,
                                            float* __restrict__ M2) {
  const int b = blockIdx.y, k0 = blockIdx.x * 128;
  __shared__ float a_s[64][133];
  __shared__ float b_s[64][133];
  const int tid = threadIdx.x;
  const int og = tid / 16, kg = tid % 16;
  float acc[8][8] = {};
  for (int c0 = 0; c0 < C_; c0 += 64) {
    for (int q = tid; q < 64 * 128 / 4; q += 256) {
      int oo = q / 16, c4 = q % 16;
      float4 v = *reinterpret_cast<const float4*>(scw + (size_t)oo * 256 + 128 + c0 + c4 * 4);
      a_s[c4 * 4 + 0][oo] = v.x; a_s[c4 * 4 + 1][oo] = v.y;
      a_s[c4 * 4 + 2][oo] = v.z; a_s[c4 * 4 + 3][oo] = v.w;
    }
    for (int q = tid; q < 64 * 128 / 4; q += 256) {
      int kk = q / 16, c4 = q % 16;
      float4 v = *reinterpret_cast<const float4*>(gmax + (size_t)(b * K_ + k0 + kk) * P_ + c0 + c4 * 4);
      b_s[c4 * 4 + 0][kk] = v.x; b_s[c4 * 4 + 1][kk] = v.y;
      b_s[c4 * 4 + 2][kk] = v.z; b_s[c4 * 4 + 3][kk] = v.w;
    }
    __syncthreads();
    for (int cc = 0; cc < 64; ++cc) {
      float av[8], bv[8];
#pragma unroll
      for (int i = 0; i < 8; ++i) av[i] = a_s[cc][og * 8 + i];
#pragma unroll
      for (int j = 0; j < 8; ++j) bv[j] = b_s[cc][kg + 16 * j];
#pragma unroll
      for (int i = 0; i < 8; ++i)
#pragma unroll
        for (int j = 0; j < 8; ++j) acc[i][j] = fmaf(av[i], bv[j], acc[i][j]);
    }
    __syncthreads();
  }
#pragma unroll
  for (int i = 0; i < 8; ++i)
#pragma unroll
    for (int j = 0; j < 8; ++j)
      M2[(size_t)(b * C_ + og * 8 + i) * K_ + k0 + kg + 16 * j] = acc[i][j];
}

// ---------------------------------------------------------------------------
// 15) per-(b,n) softmax-over-k stats from EBT[b][n][k] bf16
// ---------------------------------------------------------------------------
__global__ __launch_bounds__(256) void k_colstat(const unsigned short* __restrict__ EBT,
                                                 float* __restrict__ mx2, float* __restrict__ rs2) {
  const int wid = threadIdx.x >> 6, lane = threadIdx.x & 63;
  const int bn = blockIdx.x * 4 + wid;  // b*N + n
  u16x4 v = *reinterpret_cast<const u16x4*>(EBT + (size_t)bn * K_ + 4 * lane);
  float f0 = bf2f(v[0]), f1 = bf2f(v[1]), f2 = bf2f(v[2]), f3 = bf2f(v[3]);
  float m = fmaxf(fmaxf(f0, f1), fmaxf(f2, f3));
  for (int o = 32; o > 0; o >>= 1) m = fmaxf(m, __shfl_xor(m, o));
  float s = __expf(f0 - m) + __expf(f1 - m) + __expf(f2 - m) + __expf(f3 - m);
  for (int o = 32; o > 0; o >>= 1) s += __shfl_xor(s, o);
  if (lane == 0) { mx2[bn] = m; rs2[bn] = 1.f / s; }
}

// ---------------------------------------------------------------------------
// 16) out[o,n] = scw[:, :C]@x + M2@softmax_k(EB2) + scb   (bf16 MFMA)
// ---------------------------------------------------------------------------
__global__ __launch_bounds__(256) void k_final_mfma(const unsigned short* __restrict__ EBT,
                                                    const unsigned short* __restrict__ xh,
                                                    const float* __restrict__ M2,
                                                    const float* __restrict__ scw,
                                                    const float* __restrict__ scb,
                                                    const float* __restrict__ mx2,
                                                    const float* __restrict__ rs2,
                                                    float* __restrict__ out) {
  const int n0 = blockIdx.x * 128, b = blockIdx.y;
  __shared__ __align__(16) unsigned short a_s[128][72];
  __shared__ __align__(16) unsigned short b_s[128][72];
  __shared__ float mx2s[128], rs2s[128], scb_s[128];
  const int tid = threadIdx.x, lane = tid & 63, wid = tid >> 6;
  const int wr = wid >> 1, wc = wid & 1, l15 = lane & 15, l4 = lane >> 4;
  if (tid < 128) {
    mx2s[tid] = mx2[b * N_ + n0 + tid];
    rs2s[tid] = rs2[b * N_ + n0 + tid];
    scb_s[tid] = scb[tid];
  }
  __syncthreads();
  f32x4 acc[4][4] = {};
  // phase A: c-contraction (raw x part)
  for (int c0 = 0; c0 < C_; c0 += 64) {
    for (int i = 0; i < 8; i++) {
      int q = tid + i * 256;
      int cq = q & 15, oo = q >> 4;
      float4 v = *reinterpret_cast<const float4*>(scw + (size_t)oo * 256 + c0 + 4 * cq);
      u16x4 p; p[0] = f2bf(v.x); p[1] = f2bf(v.y); p[2] = f2bf(v.z); p[3] = f2bf(v.w);
      *reinterpret_cast<u16x4*>(&a_s[oo][4 * cq]) = p;
    }
    for (int i = 0; i < 4; i++) {
      int q = tid + i * 256;
      int co = q & 7, nn = q >> 3;
      u16x8 v = *reinterpret_cast<const u16x8*>(xh + (size_t)(b * N_ + n0 + nn) * C_ + c0 + 8 * co);
      *reinterpret_cast<u16x8*>(&b_s[nn][8 * co]) = v;
    }
    __syncthreads();
#pragma unroll
    for (int ks = 0; ks < 64; ks += 32) {
      s16x8 af[4], bfv[4];
#pragma unroll
      for (int m = 0; m < 4; m++)
        af[m] = *reinterpret_cast<const s16x8*>(&a_s[wr * 64 + m * 16 + l15][ks + 8 * l4]);
#pragma unroll
      for (int n = 0; n < 4; n++)
        bfv[n] = *reinterpret_cast<const s16x8*>(&b_s[wc * 64 + n * 16 + l15][ks + 8 * l4]);
#pragma unroll
      for (int m = 0; m < 4; m++)
#pragma unroll
        for (int n = 0; n < 4; n++)
          acc[m][n] = __builtin_amdgcn_mfma_f32_16x16x32_bf16(af[m], bfv[n], acc[m][n], 0, 0, 0);
    }
    __syncthreads();
  }
  // phase B: k-contraction (M2 @ softmax)
  for (int k0 = 0; k0 < K_; k0 += 64) {
    for (int i = 0; i < 8; i++) {
      int q = tid + i * 256;
      int kq = q & 15, oo = q >> 4;
      float4 v = *reinterpret_cast<const float4*>(M2 + (size_t)(b * C_ + oo) * K_ + k0 + 4 * kq);
      u16x4 p; p[0] = f2bf(v.x); p[1] = f2bf(v.y); p[2] = f2bf(v.z); p[3] = f2bf(v.w);
      *reinterpret_cast<u16x4*>(&a_s[oo][4 * kq]) = p;
    }
    for (int i = 0; i < 4; i++) {
      int q = tid + i * 256;
      int kg = q & 7, nn = q >> 3;
      u16x8 v = *reinterpret_cast<const u16x8*>(EBT + (size_t)(b * N_ + n0 + nn) * K_ + k0 + 8 * kg);
      float mv = mx2s[nn], rv = rs2s[nn];
      u16x8 p;
#pragma unroll
      for (int j = 0; j < 8; j++) p[j] = f2bf(__expf(bf2f(v[j]) - mv) * rv);
      *reinterpret_cast<u16x8*>(&b_s[nn][8 * kg]) = p;
    }
    __syncthreads();
#pragma unroll
    for (int ks = 0; ks < 64; ks += 32) {
      s16x8 af[4], bfv[4];
#pragma unroll
      for (int m = 0; m < 4; m++)
        af[m] = *reinterpret_cast<const s16x8*>(&a_s[wr * 64 + m * 16 + l15][ks + 8 * l4]);
#pragma unroll
      for (int n = 0; n < 4; n++)
        bfv[n] = *reinterpret_cast<const s16x8*>(&b_s[wc * 64 + n * 16 + l15][ks + 8 * l4]);
#pragma unroll
      for (int m = 0; m < 4; m++)
#pragma unroll
        for (int n = 0; n < 4; n++)
          acc[m][n] = __builtin_amdgcn_mfma_f32_16x16x32_bf16(af[m], bfv[n], acc[m][n], 0, 0, 0);
    }
    __syncthreads();
  }
#pragma unroll
  for (int m = 0; m < 4; m++)
#pragma unroll
    for (int n = 0; n < 4; n++) {
      int o = wr * 64 + m * 16 + 4 * l4;
      int nn = n0 + wc * 64 + n * 16 + l15;
#pragma unroll
      for (int r = 0; r < 4; r++)
        out[(size_t)(b * C_ + o + r) * N_ + nn] = acc[m][n][r] + scb_s[o + r];
    }
}

// ---------------------------------------------------------------------------
extern "C" void kernel_launch(void* const* d_in, const int* in_sizes, int n_in,
                              void* d_out, int out_size, void* d_ws, size_t ws_size,
                              hipStream_t stream) {
  (void)in_sizes; (void)n_in; (void)out_size; (void)ws_size;
  const float* x      = (const float*)d_in[0];
  const float* dpg    = (const float*)d_in[1];
  const float* dpb    = (const float*)d_in[2];
  const float* dpw    = (const float*)d_in[3];
  const float* dpbias = (const float*)d_in[4];
  const float* dug    = (const float*)d_in[5];
  const float* dub    = (const float*)d_in[6];
  const float* duw    = (const float*)d_in[7];
  const float* dubias = (const float*)d_in[8];
  const float* w1     = (const float*)d_in[9];
  const float* b1     = (const float*)d_in[10];
  const float* g1g    = (const float*)d_in[11];
  const float* g1b    = (const float*)d_in[12];
  const float* w2     = (const float*)d_in[13];
  const float* b2     = (const float*)d_in[14];
  const float* g2g    = (const float*)d_in[15];
  const float* g2b    = (const float*)d_in[16];
  const float* scw    = (const float*)d_in[17];
  const float* scb    = (const float*)d_in[18];
  float* out = (float*)d_out;
  float* ws  = (float*)d_ws;

  // workspace layout (float-slot units)
  unsigned short* EB = (unsigned short*)ws;            // 16,777,216 slots (B*K*N bf16)
  unsigned short* xh = (unsigned short*)(ws + 16777216); // 8,388,608 slots (B*N*C bf16)
  float* m_in  = ws + 16777216 + 8388608;
  float* v_in  = m_in + 2048;
  float* r_in  = v_in + 2048;
  float* a_dp  = r_in + 2048;
  float* d_dp  = a_dp + 2048;
  float* a_du  = d_dp + 2048;
  float* d_du  = a_du + 2048;
  float* mx    = d_du + 2048;        // 4096
  float* rden  = mx + 4096;          // 4096
  float* mx2   = rden + 4096;        // 131072
  float* rs2   = mx2 + 131072;       // 131072
  float* xd    = rs2 + 131072;       // 524288
  float* U     = xd + 524288;
  float* V     = U + 524288;
  int*   idxb  = (int*)(V + 524288); // 12288
  float* g1buf = (float*)(idxb + 12288);   // 3,145,728
  float* g2buf = g1buf + 3145728;          // 3,145,728
  float* bn1s  = g2buf + 3145728;
  float* bn1h  = bn1s + 256;
  float* bn2s  = bn1h + 256;
  float* bn2h  = bn2s + 256;
  float* gmax  = bn2h + 256;         // 524288
  float* M2    = gmax + 524288;      // 524288
  float* part  = g1buf;              // 8*16*128*256 = 4,194,304 aliases g1+g2

  k_prep<<<dim3(128, 16), 256, 0, stream>>>(x, xh);
  k_instat<<<dim3(B_ * C_), 256, 0, stream>>>(x, m_in, v_in, r_in);
  k_affine<<<1, 128, 0, stream>>>(m_in, v_in, r_in, dpg, dpb, dug, dub, a_dp, d_dp, a_du, d_du);
  k_embed_mfma<0><<<dim3(64, 2, 16), 256, 0, stream>>>(xh, dpw, dpbias, a_dp, d_dp, EB);
  k_rowstat<<<dim3(B_ * K_), 256, 0, stream>>>(EB, mx, rden);
  k_xdown_mfma<<<dim3(2, 8, 16), 256, 0, stream>>>(x, EB, mx, part);
  k_xdown_red<<<dim3(2048), 256, 0, stream>>>(part, rden, xd);
  k_gram_topk<<<dim3(16), 256, 0, stream>>>(xd, idxb);
  k_uv<<<dim3(2, 2, 16), 256, 0, stream>>>(xd, w1, U, V);
  k_edge<<<dim3(256, 16), 256, 0, stream>>>(U, V, idxb, b1, g1buf);
  k_bnstat<<<dim3(256), 256, 0, stream>>>(g1buf, g1g, g1b, bn1s, bn1h);
  k_conv2<<<dim3(6, 2, 16), 256, 0, stream>>>(g1buf, w2, b2, bn1s, bn1h, g2buf);
  k_bnstat<<<dim3(256), 256, 0, stream>>>(g2buf, g2g, g2b, bn2s, bn2h);
  k_gmax<<<dim3(2048), 256, 0, stream>>>(g2buf, bn2s, bn2h, gmax);
  k_m2<<<dim3(2, 16), 256, 0, stream>>>(gmax, scw, M2);
  k_embed_mfma<1><<<dim3(64, 2, 16), 256, 0, stream>>>(xh, duw, dubias, a_du, d_du, EB);
  k_colstat<<<dim3(B_ * N_ / 4), 256, 0, stream>>>(EB, mx2, rs2);
  k_final_mfma<<<dim3(64, 16), 256, 0, stream>>>(EB, xh, M2, scw, scb, mx2, rs2, out);
}

// Round 3
// 474.764 us; speedup vs baseline: 2.2072x; 1.1663x over previous
//
#include <hip/hip_runtime.h>

typedef __attribute__((ext_vector_type(4))) float f32x4;
typedef __attribute__((ext_vector_type(8))) short s16x8;
typedef __attribute__((ext_vector_type(8))) unsigned short u16x8;
typedef __attribute__((ext_vector_type(4))) unsigned short u16x4;

namespace {
constexpr int B_ = 16, C_ = 128, N_ = 8192, K_ = 256, P_ = 128, NB_ = 6;
}

__device__ __forceinline__ float bf2f(unsigned short h) {
  return __uint_as_float(((unsigned int)h) << 16);
}
__device__ __forceinline__ unsigned short f2bf(float f) {
  unsigned int u = __float_as_uint(f);
  return (unsigned short)((u + 0x7fffu + ((u >> 16) & 1u)) >> 16);
}

// ---------------------------------------------------------------------------
// 0) transpose + convert: xh[b][n][c] bf16 from x[b][c][n] fp32
// ---------------------------------------------------------------------------
__global__ __launch_bounds__(256) void k_prep(const float* __restrict__ x,
                                              unsigned short* __restrict__ xh) {
  const int chunk = blockIdx.x, b = blockIdx.y;
  const int n0 = chunk * 64;
  __shared__ float ts[64][132];
  const int tid = threadIdx.x;
  for (int i = 0; i < 8; i++) {
    int q = tid + i * 256;
    int n4 = q & 15, c = q >> 4;
    float4 v = *reinterpret_cast<const float4*>(x + (size_t)(b * C_ + c) * N_ + n0 + 4 * n4);
    ts[4 * n4 + 0][c] = v.x; ts[4 * n4 + 1][c] = v.y;
    ts[4 * n4 + 2][c] = v.z; ts[4 * n4 + 3][c] = v.w;
  }
  __syncthreads();
  for (int i = 0; i < 4; i++) {
    int q = tid + i * 256;
    int cg = q & 15, nn = q >> 4;
    u16x8 o;
#pragma unroll
    for (int j = 0; j < 8; j++) o[j] = f2bf(ts[nn][8 * cg + j]);
    *reinterpret_cast<u16x8*>(xh + (size_t)(b * N_ + n0 + nn) * C_ + 8 * cg) = o;
  }
}

// ---------------------------------------------------------------------------
// 1) per-(b,c) instance-norm stats over N
// ---------------------------------------------------------------------------
__global__ __launch_bounds__(256) void k_instat(const float* __restrict__ x,
                                                float* __restrict__ m_o,
                                                float* __restrict__ v_o,
                                                float* __restrict__ r_o) {
  const int row = blockIdx.x;  // b*C + c
  const float4* xr = reinterpret_cast<const float4*>(x + (size_t)row * N_);
  float s = 0.f, ss = 0.f;
  for (int i = threadIdx.x; i < N_ / 4; i += 256) {
    float4 v = xr[i];
    s += v.x + v.y + v.z + v.w;
    ss += v.x * v.x + v.y * v.y + v.z * v.z + v.w * v.w;
  }
  __shared__ float rs[256], rq[256];
  rs[threadIdx.x] = s; rq[threadIdx.x] = ss;
  __syncthreads();
  for (int st = 128; st > 0; st >>= 1) {
    if (threadIdx.x < st) { rs[threadIdx.x] += rs[threadIdx.x + st]; rq[threadIdx.x] += rq[threadIdx.x + st]; }
    __syncthreads();
  }
  if (threadIdx.x == 0) {
    float m = rs[0] / N_;
    float v = rq[0] / N_ - m * m;
    m_o[row] = m; v_o[row] = v; r_o[row] = rsqrtf(v + 1e-3f);
  }
}

// ---------------------------------------------------------------------------
// 2) fold IN+BN into per-(b,c) affine (BN mean of IN(x) is analytically 0)
// ---------------------------------------------------------------------------
__global__ void k_affine(const float* __restrict__ m_in, const float* __restrict__ v_in,
                         const float* __restrict__ r_in,
                         const float* __restrict__ dpg, const float* __restrict__ dpb,
                         const float* __restrict__ dug, const float* __restrict__ dub,
                         float* __restrict__ a_dp, float* __restrict__ d_dp,
                         float* __restrict__ a_du, float* __restrict__ d_du) {
  int c = threadIdx.x;  // 128 threads
  float V = 0.f;
  for (int b = 0; b < B_; b++) { float v = v_in[b * C_ + c]; V += v / (v + 1e-3f); }
  V *= (1.f / B_);
  float R = rsqrtf(V + 1e-5f);
  float gdp = dpg[c], bdp = dpb[c], gdu = dug[c], bdu = dub[c];
  for (int b = 0; b < B_; b++) {
    int i = b * C_ + c;
    float r = r_in[i], m = m_in[i];
    float sdp = r * R * gdp;
    a_dp[i] = sdp; d_dp[i] = -m * sdp + bdp;
    float sdu = r * R * gdu;
    a_du[i] = sdu; d_du[i] = -m * sdu + bdu;
  }
}

// ---------------------------------------------------------------------------
// 3) embed MFMA: out[k,n] = sum_c w[k,c]*relu(a*x+d) + bias  (bf16 MFMA)
//    MODE 0: write EB [b][k][n] bf16 ; MODE 1: write EBT [b][n][k] bf16
// ---------------------------------------------------------------------------
template <int MODE>
__global__ __launch_bounds__(256) void k_embed_mfma(const unsigned short* __restrict__ xh,
                                                    const float* __restrict__ w,
                                                    const float* __restrict__ bias,
                                                    const float* __restrict__ aff_a,
                                                    const float* __restrict__ aff_d,
                                                    unsigned short* __restrict__ outp) {
  const int n0 = blockIdx.x * 128, k0 = blockIdx.y * 128, b = blockIdx.z;
  __shared__ __align__(16) unsigned short smem[2 * 128 * 72];
  unsigned short (*a_s)[72] = reinterpret_cast<unsigned short(*)[72]>(smem);         // [k][c]
  unsigned short (*b_s)[72] = reinterpret_cast<unsigned short(*)[72]>(smem + 128 * 72); // [n][c]
  unsigned short (*e_s)[136] = reinterpret_cast<unsigned short(*)[136]>(smem);       // epilogue
  __shared__ float aff_as[128], aff_ds[128], bias_s[128];
  const int tid = threadIdx.x;
  const int lane = tid & 63, wid = tid >> 6;
  const int wr = wid >> 1, wc = wid & 1;
  const int l15 = lane & 15, l4 = lane >> 4;
  if (tid < 128) {
    aff_as[tid] = aff_a[b * C_ + tid];
    aff_ds[tid] = aff_d[b * C_ + tid];
    bias_s[tid] = bias[k0 + tid];
  }
  __syncthreads();
  f32x4 acc[4][4] = {};
  for (int c0 = 0; c0 < C_; c0 += 64) {
    for (int i = 0; i < 8; i++) {
      int q = tid + i * 256;
      int cq = q & 15, kk = q >> 4;
      float4 v = *reinterpret_cast<const float4*>(w + (size_t)(k0 + kk) * C_ + c0 + 4 * cq);
      u16x4 p; p[0] = f2bf(v.x); p[1] = f2bf(v.y); p[2] = f2bf(v.z); p[3] = f2bf(v.w);
      *reinterpret_cast<u16x4*>(&a_s[kk][4 * cq]) = p;
    }
    for (int i = 0; i < 4; i++) {
      int q = tid + i * 256;
      int co = q & 7, nn = q >> 3;
      u16x8 v = *reinterpret_cast<const u16x8*>(xh + (size_t)(b * N_ + n0 + nn) * C_ + c0 + 8 * co);
      u16x8 h;
#pragma unroll
      for (int j = 0; j < 8; j++) {
        int c = c0 + 8 * co + j;
        h[j] = f2bf(fmaxf(fmaf(aff_as[c], bf2f(v[j]), aff_ds[c]), 0.f));
      }
      *reinterpret_cast<u16x8*>(&b_s[nn][8 * co]) = h;
    }
    __syncthreads();
#pragma unroll
    for (int ks = 0; ks < 64; ks += 32) {
      s16x8 af[4], bfv[4];
#pragma unroll
      for (int m = 0; m < 4; m++)
        af[m] = *reinterpret_cast<const s16x8*>(&a_s[wr * 64 + m * 16 + l15][ks + 8 * l4]);
#pragma unroll
      for (int n = 0; n < 4; n++)
        bfv[n] = *reinterpret_cast<const s16x8*>(&b_s[wc * 64 + n * 16 + l15][ks + 8 * l4]);
#pragma unroll
      for (int m = 0; m < 4; m++)
#pragma unroll
        for (int n = 0; n < 4; n++)
          acc[m][n] = __builtin_amdgcn_mfma_f32_16x16x32_bf16(af[m], bfv[n], acc[m][n], 0, 0, 0);
    }
    __syncthreads();
  }
#pragma unroll
  for (int m = 0; m < 4; m++)
#pragma unroll
    for (int n = 0; n < 4; n++) {
      int kl = wr * 64 + m * 16 + 4 * l4;
      int nl = wc * 64 + n * 16 + l15;
#pragma unroll
      for (int r = 0; r < 4; r++)
        e_s[kl + r][nl] = f2bf(acc[m][n][r] + bias_s[kl + r]);
    }
  __syncthreads();
  if (MODE == 0) {
    for (int i = 0; i < 8; i++) {
      int q = tid + i * 256;
      int cg = q & 15, kk = q >> 4;
      u16x8 v = *reinterpret_cast<const u16x8*>(&e_s[kk][8 * cg]);
      *reinterpret_cast<u16x8*>(outp + (size_t)(b * K_ + k0 + kk) * N_ + n0 + 8 * cg) = v;
    }
  } else {
    for (int i = 0; i < 8; i++) {
      int q = tid + i * 256;
      int kg = q & 15, nn = q >> 4;
      u16x8 v;
#pragma unroll
      for (int j = 0; j < 8; j++) v[j] = e_s[8 * kg + j][nn];
      *reinterpret_cast<u16x8*>(outp + (size_t)(b * N_ + n0 + nn) * K_ + k0 + 8 * kg) = v;
    }
  }
}

// ---------------------------------------------------------------------------
// 4) per-(b,k) row max + sum(exp) over N (bf16 input)
// ---------------------------------------------------------------------------
__global__ __launch_bounds__(256) void k_rowstat(const unsigned short* __restrict__ EB,
                                                 float* __restrict__ mx, float* __restrict__ rden) {
  const int row = blockIdx.x;
  float m = -1e30f, s = 0.f;
  for (int i = threadIdx.x; i < N_ / 8; i += 256) {
    u16x8 v = *reinterpret_cast<const u16x8*>(EB + (size_t)row * N_ + 8 * i);
    float f[8];
#pragma unroll
    for (int j = 0; j < 8; j++) f[j] = bf2f(v[j]);
    float lm = f[0];
#pragma unroll
    for (int j = 1; j < 8; j++) lm = fmaxf(lm, f[j]);
    if (lm > m) { s *= __expf(m - lm); m = lm; }
#pragma unroll
    for (int j = 0; j < 8; j++) s += __expf(f[j] - m);
  }
  __shared__ float rm[256], rsum[256];
  rm[threadIdx.x] = m; rsum[threadIdx.x] = s;
  __syncthreads();
  for (int st = 128; st > 0; st >>= 1) {
    if (threadIdx.x < st) {
      float m1 = rm[threadIdx.x], s1 = rsum[threadIdx.x];
      float m2 = rm[threadIdx.x + st], s2 = rsum[threadIdx.x + st];
      float M = fmaxf(m1, m2);
      rm[threadIdx.x] = M;
      rsum[threadIdx.x] = s1 * __expf(m1 - M) + s2 * __expf(m2 - M);
    }
    __syncthreads();
  }
  if (threadIdx.x == 0) { mx[row] = rm[0]; rden[row] = 1.f / rsum[0]; }
}

// ---------------------------------------------------------------------------
// 5) x_down partials via MFMA: part[sp][b][c][k] = sum_n x[c,n]*exp(EB[k,n]-mx)
// ---------------------------------------------------------------------------
__global__ __launch_bounds__(256) void k_xdown_mfma(const float* __restrict__ x,
                                                    const unsigned short* __restrict__ EB,
                                                    const float* __restrict__ mx,
                                                    float* __restrict__ part) {
  const int k0 = blockIdx.x * 128, sp = blockIdx.y, b = blockIdx.z;
  const int nbase = sp * 1024;
  __shared__ __align__(16) unsigned short a_s[128][72];  // [c][n]
  __shared__ __align__(16) unsigned short p_s[128][72];  // [k][n]
  __shared__ float mxs[128];
  const int tid = threadIdx.x, lane = tid & 63, wid = tid >> 6;
  const int wr = wid >> 1, wc = wid & 1, l15 = lane & 15, l4 = lane >> 4;
  if (tid < 128) mxs[tid] = mx[b * K_ + k0 + tid];
  __syncthreads();
  f32x4 acc[4][4] = {};
  for (int nc = 0; nc < 1024; nc += 64) {
    const int n0 = nbase + nc;
    for (int i = 0; i < 8; i++) {
      int q = tid + i * 256;
      int nq = q & 15, cc = q >> 4;
      float4 v = *reinterpret_cast<const float4*>(x + (size_t)(b * C_ + cc) * N_ + n0 + 4 * nq);
      u16x4 p; p[0] = f2bf(v.x); p[1] = f2bf(v.y); p[2] = f2bf(v.z); p[3] = f2bf(v.w);
      *reinterpret_cast<u16x4*>(&a_s[cc][4 * nq]) = p;
    }
    for (int i = 0; i < 4; i++) {
      int q = tid + i * 256;
      int nq = q & 7, kk = q >> 3;
      u16x8 v = *reinterpret_cast<const u16x8*>(EB + (size_t)(b * K_ + k0 + kk) * N_ + n0 + 8 * nq);
      float mv = mxs[kk];
      u16x8 p;
#pragma unroll
      for (int j = 0; j < 8; j++) p[j] = f2bf(__expf(bf2f(v[j]) - mv));
      *reinterpret_cast<u16x8*>(&p_s[kk][8 * nq]) = p;
    }
    __syncthreads();
#pragma unroll
    for (int ks = 0; ks < 64; ks += 32) {
      s16x8 af[4], bfv[4];
#pragma unroll
      for (int m = 0; m < 4; m++)
        af[m] = *reinterpret_cast<const s16x8*>(&a_s[wr * 64 + m * 16 + l15][ks + 8 * l4]);
#pragma unroll
      for (int n = 0; n < 4; n++)
        bfv[n] = *reinterpret_cast<const s16x8*>(&p_s[wc * 64 + n * 16 + l15][ks + 8 * l4]);
#pragma unroll
      for (int m = 0; m < 4; m++)
#pragma unroll
        for (int n = 0; n < 4; n++)
          acc[m][n] = __builtin_amdgcn_mfma_f32_16x16x32_bf16(af[m], bfv[n], acc[m][n], 0, 0, 0);
    }
    __syncthreads();
  }
#pragma unroll
  for (int m = 0; m < 4; m++)
#pragma unroll
    for (int n = 0; n < 4; n++) {
      int c = wr * 64 + m * 16 + 4 * l4;
      int k = k0 + wc * 64 + n * 16 + l15;
#pragma unroll
      for (int r = 0; r < 4; r++)
        part[((size_t)(sp * B_ + b) * C_ + c + r) * K_ + k] = acc[m][n][r];
    }
}

// 6) reduce split partials, scale by 1/den -> x_down[b][c][k]
__global__ __launch_bounds__(256) void k_xdown_red(const float* __restrict__ part,
                                                   const float* __restrict__ rden,
                                                   float* __restrict__ xd) {
  int e = blockIdx.x * 256 + threadIdx.x;  // B*C*K
  int k = e % K_;
  int c = (e / K_) % C_;
  int b = e / (K_ * C_);
  float s = 0.f;
  for (int sp = 0; sp < 8; sp++) s += part[((size_t)(sp * B_ + b) * C_ + c) * K_ + k];
  xd[e] = s * rden[b * K_ + k];
}

// ---------------------------------------------------------------------------
// 7a) gram tiles: pd[b][p][q] = sum_k xd[b][p][k]*xd[b][q][k]
//     grid (4 ptiles, 16 b); 32x128 tile; k-chunks of 32
// ---------------------------------------------------------------------------
__global__ __launch_bounds__(256) void k_gram(const float* __restrict__ xd,
                                              float* __restrict__ pd) {
  const int p0 = blockIdx.x * 32, b = blockIdx.y;
  __shared__ float A[32][36];    // [kk][pp]
  __shared__ float Bt[32][132];  // [kk][q]
  const int tid = threadIdx.x;
  const int tr = tid >> 5, tc = tid & 31;
  float acc[4][4] = {};
  for (int k0 = 0; k0 < K_; k0 += 32) {
    {
      int pp = tid >> 3, k4 = tid & 7;
      float4 v = *reinterpret_cast<const float4*>(xd + (size_t)(b * C_ + p0 + pp) * K_ + k0 + 4 * k4);
      A[4 * k4 + 0][pp] = v.x; A[4 * k4 + 1][pp] = v.y;
      A[4 * k4 + 2][pp] = v.z; A[4 * k4 + 3][pp] = v.w;
    }
    for (int i = 0; i < 4; i++) {
      int q = tid + i * 256;
      int qq = q >> 3, k4 = q & 7;
      float4 v = *reinterpret_cast<const float4*>(xd + (size_t)(b * C_ + qq) * K_ + k0 + 4 * k4);
      Bt[4 * k4 + 0][qq] = v.x; Bt[4 * k4 + 1][qq] = v.y;
      Bt[4 * k4 + 2][qq] = v.z; Bt[4 * k4 + 3][qq] = v.w;
    }
    __syncthreads();
    for (int kk = 0; kk < 32; ++kk) {
      float4 av = *reinterpret_cast<const float4*>(&A[kk][tr * 4]);
      float4 bv = *reinterpret_cast<const float4*>(&Bt[kk][tc * 4]);
      float a[4] = {av.x, av.y, av.z, av.w};
      float bb[4] = {bv.x, bv.y, bv.z, bv.w};
#pragma unroll
      for (int i = 0; i < 4; ++i)
#pragma unroll
        for (int j = 0; j < 4; ++j) acc[i][j] = fmaf(a[i], bb[j], acc[i][j]);
    }
    __syncthreads();
  }
#pragma unroll
  for (int i = 0; i < 4; ++i) {
    float4 r; r.x = acc[i][0]; r.y = acc[i][1]; r.z = acc[i][2]; r.w = acc[i][3];
    *reinterpret_cast<float4*>(pd + (size_t)(b * P_ + p0 + tr * 4 + i) * P_ + tc * 4) = r;
  }
}

// 7b) sq[b][p] = ||xd[b][p][:]||^2
__global__ __launch_bounds__(128) void k_sq(const float* __restrict__ xd,
                                            float* __restrict__ sq) {
  const int b = blockIdx.x, p = threadIdx.x;
  const float4* r = reinterpret_cast<const float4*>(xd + (size_t)(b * C_ + p) * K_);
  float s = 0.f;
  for (int i = 0; i < K_ / 4; i++) { float4 v = r[i]; s += v.x * v.x + v.y * v.y + v.z * v.z + v.w * v.w; }
  sq[b * P_ + p] = s;
}

// 7c) top-6 per point: one wave per point, 6 rounds of wave argmax
//     comparator (v desc, q asc) == jax top_k lower-index-first tie rule
__global__ __launch_bounds__(256) void k_topk(const float* __restrict__ pd,
                                              const float* __restrict__ sq,
                                              int* __restrict__ idx) {
  const int wid = threadIdx.x >> 6, lane = threadIdx.x & 63;
  const int gp = blockIdx.x * 4 + wid;  // b*P + p
  const int b = gp >> 7;
  const float* row = pd + (size_t)gp * P_;
  // -sq[p] term is a constant shift per row: rank-invariant, dropped.
  float v0 = 2.f * row[lane] - sq[b * P_ + lane];
  float v1 = 2.f * row[lane + 64] - sq[b * P_ + lane + 64];
  int q0 = lane, q1 = lane + 64;
#pragma unroll
  for (int j = 0; j < NB_; j++) {
    float bv; int bq;
    if (v0 > v1 || (v0 == v1 && q0 < q1)) { bv = v0; bq = q0; } else { bv = v1; bq = q1; }
#pragma unroll
    for (int o = 32; o > 0; o >>= 1) {
      float ov = __shfl_xor(bv, o); int oq = __shfl_xor(bq, o);
      if (ov > bv || (ov == bv && oq < bq)) { bv = ov; bq = oq; }
    }
    if (lane == 0) idx[gp * NB_ + j] = bq;
    if (q0 == bq) v0 = -3.0e38f;
    if (q1 == bq) v1 = -3.0e38f;
  }
}

// ---------------------------------------------------------------------------
// 8) U = (W1a+W1b)@feats ; V = W1b@feats  (fp32)
// ---------------------------------------------------------------------------
__global__ __launch_bounds__(256) void k_uv(const float* __restrict__ xd,
                                            const float* __restrict__ w1,
                                            float* __restrict__ U, float* __restrict__ V) {
  const int b = blockIdx.z, o0 = blockIdx.y * 128, which = blockIdx.x;
  __shared__ float a_s[64][133];
  __shared__ float b_s[64][133];
  const int tid = threadIdx.x;
  const int og = tid / 16, pg = tid % 16;
  float acc[8][8] = {};
  for (int k0 = 0; k0 < K_; k0 += 64) {
    for (int q = tid; q < 64 * 128 / 4; q += 256) {
      int oo = q / 16, k4 = q % 16;
      const float* wr = w1 + (size_t)(o0 + oo) * 512 + k0 + k4 * 4;
      float4 vb = *reinterpret_cast<const float4*>(wr + 256);
      if (which == 0) {
        float4 va = *reinterpret_cast<const float4*>(wr);
        vb.x += va.x; vb.y += va.y; vb.z += va.z; vb.w += va.w;
      }
      a_s[k4 * 4 + 0][oo] = vb.x; a_s[k4 * 4 + 1][oo] = vb.y;
      a_s[k4 * 4 + 2][oo] = vb.z; a_s[k4 * 4 + 3][oo] = vb.w;
    }
    for (int q = tid; q < 64 * 128 / 4; q += 256) {
      int p = q / 16, k4 = q % 16;
      float4 v = *reinterpret_cast<const float4*>(xd + (size_t)(b * C_ + p) * K_ + k0 + k4 * 4);
      b_s[k4 * 4 + 0][p] = v.x; b_s[k4 * 4 + 1][p] = v.y;
      b_s[k4 * 4 + 2][p] = v.z; b_s[k4 * 4 + 3][p] = v.w;
    }
    __syncthreads();
    for (int kk = 0; kk < 64; ++kk) {
      float av[8], bv[8];
#pragma unroll
      for (int i = 0; i < 8; ++i) av[i] = a_s[kk][og * 8 + i];
#pragma unroll
      for (int j = 0; j < 8; ++j) bv[j] = b_s[kk][pg + 16 * j];
#pragma unroll
      for (int i = 0; i < 8; ++i)
#pragma unroll
        for (int j = 0; j < 8; ++j) acc[i][j] = fmaf(av[i], bv[j], acc[i][j]);
    }
    __syncthreads();
  }
  float* outp = (which == 0) ? U : V;
#pragma unroll
  for (int i = 0; i < 8; ++i)
#pragma unroll
    for (int j = 0; j < 8; ++j)
      outp[(size_t)(b * K_ + o0 + og * 8 + i) * P_ + pg + 16 * j] = acc[i][j];
}

// 9) g1[b,o,p,j] = U[p] - V[idx[p,j]] + b1[o]
__global__ __launch_bounds__(256) void k_edge(const float* __restrict__ U,
                                              const float* __restrict__ V,
                                              const int* __restrict__ idx,
                                              const float* __restrict__ b1,
                                              float* __restrict__ g1) {
  const int o = blockIdx.x, b = blockIdx.y;
  __shared__ float U_s[128], V_s[128];
  const int tid = threadIdx.x;
  if (tid < 128) {
    U_s[tid] = U[(size_t)(b * K_ + o) * P_ + tid];
    V_s[tid] = V[(size_t)(b * K_ + o) * P_ + tid];
  }
  __syncthreads();
  const float bias = b1[o];
  for (int e = tid; e < P_ * NB_; e += 256) {
    int p = e / NB_;
    int q = idx[b * P_ * NB_ + e];
    g1[(size_t)(b * K_ + o) * (P_ * NB_) + e] = U_s[p] + bias - V_s[q];
  }
}

// 10/12) BN stats per channel o over (b,p,j)
__global__ __launch_bounds__(256) void k_bnstat(const float* __restrict__ g,
                                                const float* __restrict__ gamma,
                                                const float* __restrict__ beta,
                                                float* __restrict__ scale,
                                                float* __restrict__ shift) {
  const int o = blockIdx.x;
  float s = 0.f, ss = 0.f;
  for (int e = threadIdx.x; e < B_ * P_ * NB_; e += 256) {
    int b = e / (P_ * NB_), r = e % (P_ * NB_);
    float v = g[(size_t)(b * K_ + o) * (P_ * NB_) + r];
    s += v; ss += v * v;
  }
  __shared__ float rs[256], rq[256];
  rs[threadIdx.x] = s; rq[threadIdx.x] = ss;
  __syncthreads();
  for (int st = 128; st > 0; st >>= 1) {
    if (threadIdx.x < st) { rs[threadIdx.x] += rs[threadIdx.x + st]; rq[threadIdx.x] += rq[threadIdx.x + st]; }
    __syncthreads();
  }
  if (threadIdx.x == 0) {
    const float cnt = (float)(B_ * P_ * NB_);
    float m = rs[0] / cnt;
    float var = rq[0] / cnt - m * m;
    float sc = gamma[o] * rsqrtf(var + 1e-5f);
    scale[o] = sc; shift[o] = -m * sc + beta[o];
  }
}

// 11) g2 = W2 @ relu(bn1(g1)) + b2 (fp32)
__global__ __launch_bounds__(256) void k_conv2(const float* __restrict__ g1,
                                               const float* __restrict__ w2,
                                               const float* __restrict__ b2,
                                               const float* __restrict__ bn1s,
                                               const float* __restrict__ bn1h,
                                               float* __restrict__ g2) {
  const int b = blockIdx.z, o0 = blockIdx.y * 128, n0 = blockIdx.x * 128;
  __shared__ float a_s[64][133];
  __shared__ float b_s[64][132];
  const int tid = threadIdx.x;
  const int og = tid / 16, ng = tid % 16;
  float acc[8][8] = {};
  for (int c0 = 0; c0 < K_; c0 += 64) {
    for (int q = tid; q < 64 * 128 / 4; q += 256) {
      int oo = q / 16, c4 = q % 16;
      float4 v = *reinterpret_cast<const float4*>(w2 + (size_t)(o0 + oo) * K_ + c0 + c4 * 4);
      a_s[c4 * 4 + 0][oo] = v.x; a_s[c4 * 4 + 1][oo] = v.y;
      a_s[c4 * 4 + 2][oo] = v.z; a_s[c4 * 4 + 3][oo] = v.w;
    }
    for (int q = tid; q < 64 * 128 / 4; q += 256) {
      int cc = q / 32, n4 = q % 32;
      int c = c0 + cc;
      float sc = bn1s[c], sh = bn1h[c];
      float4 v = *reinterpret_cast<const float4*>(g1 + (size_t)(b * K_ + c) * (P_ * NB_) + n0 + n4 * 4);
      float4 hv;
      hv.x = fmaxf(fmaf(sc, v.x, sh), 0.f); hv.y = fmaxf(fmaf(sc, v.y, sh), 0.f);
      hv.z = fmaxf(fmaf(sc, v.z, sh), 0.f); hv.w = fmaxf(fmaf(sc, v.w, sh), 0.f);
      *reinterpret_cast<float4*>(&b_s[cc][n4 * 4]) = hv;
    }
    __syncthreads();
    for (int cc = 0; cc < 64; ++cc) {
      float av[8], bv[8];
#pragma unroll
      for (int i = 0; i < 8; ++i) av[i] = a_s[cc][og * 8 + i];
#pragma unroll
      for (int j = 0; j < 8; ++j) bv[j] = b_s[cc][ng + 16 * j];
#pragma unroll
      for (int i = 0; i < 8; ++i)
#pragma unroll
        for (int j = 0; j < 8; ++j) acc[i][j] = fmaf(av[i], bv[j], acc[i][j]);
    }
    __syncthreads();
  }
#pragma unroll
  for (int i = 0; i < 8; ++i) {
    int o = o0 + og * 8 + i;
    float bb = b2[o];
#pragma unroll
    for (int j = 0; j < 8; ++j)
      g2[(size_t)(b * K_ + o) * (P_ * NB_) + n0 + ng + 16 * j] = acc[i][j] + bb;
  }
}

// 13) gmax[b][k][c] = max_j relu(bn2(g2))
__global__ __launch_bounds__(256) void k_gmax(const float* __restrict__ g2,
                                              const float* __restrict__ bn2s,
                                              const float* __restrict__ bn2h,
                                              float* __restrict__ gmax) {
  int e = blockIdx.x * 256 + threadIdx.x;  // B*K*P
  int c = e % P_;
  int k = (e / P_) % K_;
  int b = e / (P_ * K_);
  const float* gp = g2 + (size_t)(b * K_ + k) * (P_ * NB_) + c * NB_;
  float sc = bn2s[k], sh = bn2h[k];
  float m = 0.f;
#pragma unroll
  for (int j = 0; j < NB_; j++) m = fmaxf(m, fmaf(sc, gp[j], sh));
  gmax[e] = m;
}

// 14) M2[b][o][k] = sum_c sc_w[o,128+c] * gmax[b][k][c]
__global__ __launch_bounds__(256) void k_m2(const float* __restrict__ gmax,
                                            const float* __restrict__ scw,
                                            float* __restrict__ M2) {
  const int b = blockIdx.y, k0 = blockIdx.x * 128;
  __shared__ float a_s[64][133];
  __shared__ float b_s[64][133];
  const int tid = threadIdx.x;
  const int og = tid / 16, kg = tid % 16;
  float acc[8][8] = {};
  for (int c0 = 0; c0 < C_; c0 += 64) {
    for (int q = tid; q < 64 * 128 / 4; q += 256) {
      int oo = q / 16, c4 = q % 16;
      float4 v = *reinterpret_cast<const float4*>(scw + (size_t)oo * 256 + 128 + c0 + c4 * 4);
      a_s[c4 * 4 + 0][oo] = v.x; a_s[c4 * 4 + 1][oo] = v.y;
      a_s[c4 * 4 + 2][oo] = v.z; a_s[c4 * 4 + 3][oo] = v.w;
    }
    for (int q = tid; q < 64 * 128 / 4; q += 256) {
      int kk = q / 16, c4 = q % 16;
      float4 v = *reinterpret_cast<const float4*>(gmax + (size_t)(b * K_ + k0 + kk) * P_ + c0 + c4 * 4);
      b_s[c4 * 4 + 0][kk] = v.x; b_s[c4 * 4 + 1][kk] = v.y;
      b_s[c4 * 4 + 2][kk] = v.z; b_s[c4 * 4 + 3][kk] = v.w;
    }
    __syncthreads();
    for (int cc = 0; cc < 64; ++cc) {
      float av[8], bv[8];
#pragma unroll
      for (int i = 0; i < 8; ++i) av[i] = a_s[cc][og * 8 + i];
#pragma unroll
      for (int j = 0; j < 8; ++j) bv[j] = b_s[cc][kg + 16 * j];
#pragma unroll
      for (int i = 0; i < 8; ++i)
#pragma unroll
        for (int j = 0; j < 8; ++j) acc[i][j] = fmaf(av[i], bv[j], acc[i][j]);
    }
    __syncthreads();
  }
#pragma unroll
  for (int i = 0; i < 8; ++i)
#pragma unroll
    for (int j = 0; j < 8; ++j)
      M2[(size_t)(b * C_ + og * 8 + i) * K_ + k0 + kg + 16 * j] = acc[i][j];
}

// ---------------------------------------------------------------------------
// 15) per-(b,n) softmax-over-k stats from EBT[b][n][k] bf16
// ---------------------------------------------------------------------------
__global__ __launch_bounds__(256) void k_colstat(const unsigned short* __restrict__ EBT,
                                                 float* __restrict__ mx2, float* __restrict__ rs2) {
  const int wid = threadIdx.x >> 6, lane = threadIdx.x & 63;
  const int bn = blockIdx.x * 4 + wid;  // b*N + n
  u16x4 v = *reinterpret_cast<const u16x4*>(EBT + (size_t)bn * K_ + 4 * lane);
  float f0 = bf2f(v[0]), f1 = bf2f(v[1]), f2 = bf2f(v[2]), f3 = bf2f(v[3]);
  float m = fmaxf(fmaxf(f0, f1), fmaxf(f2, f3));
  for (int o = 32; o > 0; o >>= 1) m = fmaxf(m, __shfl_xor(m, o));
  float s = __expf(f0 - m) + __expf(f1 - m) + __expf(f2 - m) + __expf(f3 - m);
  for (int o = 32; o > 0; o >>= 1) s += __shfl_xor(s, o);
  if (lane == 0) { mx2[bn] = m; rs2[bn] = 1.f / s; }
}

// ---------------------------------------------------------------------------
// 16) out[o,n] = scw[:, :C]@x + M2@softmax_k(EB2) + scb   (bf16 MFMA)
// ---------------------------------------------------------------------------
__global__ __launch_bounds__(256) void k_final_mfma(const unsigned short* __restrict__ EBT,
                                                    const unsigned short* __restrict__ xh,
                                                    const float* __restrict__ M2,
                                                    const float* __restrict__ scw,
                                                    const float* __restrict__ scb,
                                                    const float* __restrict__ mx2,
                                                    const float* __restrict__ rs2,
                                                    float* __restrict__ out) {
  const int n0 = blockIdx.x * 128, b = blockIdx.y;
  __shared__ __align__(16) unsigned short a_s[128][72];
  __shared__ __align__(16) unsigned short b_s[128][72];
  __shared__ float mx2s[128], rs2s[128], scb_s[128];
  const int tid = threadIdx.x, lane = tid & 63, wid = tid >> 6;
  const int wr = wid >> 1, wc = wid & 1, l15 = lane & 15, l4 = lane >> 4;
  if (tid < 128) {
    mx2s[tid] = mx2[b * N_ + n0 + tid];
    rs2s[tid] = rs2[b * N_ + n0 + tid];
    scb_s[tid] = scb[tid];
  }
  __syncthreads();
  f32x4 acc[4][4] = {};
  // phase A: c-contraction (raw x part)
  for (int c0 = 0; c0 < C_; c0 += 64) {
    for (int i = 0; i < 8; i++) {
      int q = tid + i * 256;
      int cq = q & 15, oo = q >> 4;
      float4 v = *reinterpret_cast<const float4*>(scw + (size_t)oo * 256 + c0 + 4 * cq);
      u16x4 p; p[0] = f2bf(v.x); p[1] = f2bf(v.y); p[2] = f2bf(v.z); p[3] = f2bf(v.w);
      *reinterpret_cast<u16x4*>(&a_s[oo][4 * cq]) = p;
    }
    for (int i = 0; i < 4; i++) {
      int q = tid + i * 256;
      int co = q & 7, nn = q >> 3;
      u16x8 v = *reinterpret_cast<const u16x8*>(xh + (size_t)(b * N_ + n0 + nn) * C_ + c0 + 8 * co);
      *reinterpret_cast<u16x8*>(&b_s[nn][8 * co]) = v;
    }
    __syncthreads();
#pragma unroll
    for (int ks = 0; ks < 64; ks += 32) {
      s16x8 af[4], bfv[4];
#pragma unroll
      for (int m = 0; m < 4; m++)
        af[m] = *reinterpret_cast<const s16x8*>(&a_s[wr * 64 + m * 16 + l15][ks + 8 * l4]);
#pragma unroll
      for (int n = 0; n < 4; n++)
        bfv[n] = *reinterpret_cast<const s16x8*>(&b_s[wc * 64 + n * 16 + l15][ks + 8 * l4]);
#pragma unroll
      for (int m = 0; m < 4; m++)
#pragma unroll
        for (int n = 0; n < 4; n++)
          acc[m][n] = __builtin_amdgcn_mfma_f32_16x16x32_bf16(af[m], bfv[n], acc[m][n], 0, 0, 0);
    }
    __syncthreads();
  }
  // phase B: k-contraction (M2 @ softmax)
  for (int k0 = 0; k0 < K_; k0 += 64) {
    for (int i = 0; i < 8; i++) {
      int q = tid + i * 256;
      int kq = q & 15, oo = q >> 4;
      float4 v = *reinterpret_cast<const float4*>(M2 + (size_t)(b * C_ + oo) * K_ + k0 + 4 * kq);
      u16x4 p; p[0] = f2bf(v.x); p[1] = f2bf(v.y); p[2] = f2bf(v.z); p[3] = f2bf(v.w);
      *reinterpret_cast<u16x4*>(&a_s[oo][4 * kq]) = p;
    }
    for (int i = 0; i < 4; i++) {
      int q = tid + i * 256;
      int kg = q & 7, nn = q >> 3;
      u16x8 v = *reinterpret_cast<const u16x8*>(EBT + (size_t)(b * N_ + n0 + nn) * K_ + k0 + 8 * kg);
      float mv = mx2s[nn], rv = rs2s[nn];
      u16x8 p;
#pragma unroll
      for (int j = 0; j < 8; j++) p[j] = f2bf(__expf(bf2f(v[j]) - mv) * rv);
      *reinterpret_cast<u16x8*>(&b_s[nn][8 * kg]) = p;
    }
    __syncthreads();
#pragma unroll
    for (int ks = 0; ks < 64; ks += 32) {
      s16x8 af[4], bfv[4];
#pragma unroll
      for (int m = 0; m < 4; m++)
        af[m] = *reinterpret_cast<const s16x8*>(&a_s[wr * 64 + m * 16 + l15][ks + 8 * l4]);
#pragma unroll
      for (int n = 0; n < 4; n++)
        bfv[n] = *reinterpret_cast<const s16x8*>(&b_s[wc * 64 + n * 16 + l15][ks + 8 * l4]);
#pragma unroll
      for (int m = 0; m < 4; m++)
#pragma unroll
        for (int n = 0; n < 4; n++)
          acc[m][n] = __builtin_amdgcn_mfma_f32_16x16x32_bf16(af[m], bfv[n], acc[m][n], 0, 0, 0);
    }
    __syncthreads();
  }
#pragma unroll
  for (int m = 0; m < 4; m++)
#pragma unroll
    for (int n = 0; n < 4; n++) {
      int o = wr * 64 + m * 16 + 4 * l4;
      int nn = n0 + wc * 64 + n * 16 + l15;
#pragma unroll
      for (int r = 0; r < 4; r++)
        out[(size_t)(b * C_ + o + r) * N_ + nn] = acc[m][n][r] + scb_s[o + r];
    }
}

// ---------------------------------------------------------------------------
extern "C" void kernel_launch(void* const* d_in, const int* in_sizes, int n_in,
                              void* d_out, int out_size, void* d_ws, size_t ws_size,
                              hipStream_t stream) {
  (void)in_sizes; (void)n_in; (void)out_size; (void)ws_size;
  const float* x      = (const float*)d_in[0];
  const float* dpg    = (const float*)d_in[1];
  const float* dpb    = (const float*)d_in[2];
  const float* dpw    = (const float*)d_in[3];
  const float* dpbias = (const float*)d_in[4];
  const float* dug    = (const float*)d_in[5];
  const float* dub    = (const float*)d_in[6];
  const float* duw    = (const float*)d_in[7];
  const float* dubias = (const float*)d_in[8];
  const float* w1     = (const float*)d_in[9];
  const float* b1     = (const float*)d_in[10];
  const float* g1g    = (const float*)d_in[11];
  const float* g1b    = (const float*)d_in[12];
  const float* w2     = (const float*)d_in[13];
  const float* b2     = (const float*)d_in[14];
  const float* g2g    = (const float*)d_in[15];
  const float* g2b    = (const float*)d_in[16];
  const float* scw    = (const float*)d_in[17];
  const float* scb    = (const float*)d_in[18];
  float* out = (float*)d_out;
  float* ws  = (float*)d_ws;

  // workspace layout (float-slot units)
  unsigned short* EB = (unsigned short*)ws;              // B*K*N bf16 (16,777,216 float-slots)
  unsigned short* xh = (unsigned short*)(ws + 16777216); // B*N*C bf16 (8,388,608 float-slots)
  float* m_in  = ws + 16777216 + 8388608;
  float* v_in  = m_in + 2048;
  float* r_in  = v_in + 2048;
  float* a_dp  = r_in + 2048;
  float* d_dp  = a_dp + 2048;
  float* a_du  = d_dp + 2048;
  float* d_du  = a_du + 2048;
  float* mx    = d_du + 2048;        // 4096
  float* rden  = mx + 4096;          // 4096
  float* mx2   = rden + 4096;        // 131072
  float* rs2   = mx2 + 131072;       // 131072
  float* xd    = rs2 + 131072;       // 524288
  float* U     = xd + 524288;
  float* V     = U + 524288;
  int*   idxb  = (int*)(V + 524288); // 12288
  float* g1buf = (float*)(idxb + 12288);   // 3,145,728
  float* g2buf = g1buf + 3145728;          // 3,145,728
  float* bn1s  = g2buf + 3145728;
  float* bn1h  = bn1s + 256;
  float* bn2s  = bn1h + 256;
  float* bn2h  = bn2s + 256;
  float* gmax  = bn2h + 256;         // 524288
  float* M2    = gmax + 524288;      // 524288
  float* pd    = M2 + 524288;        // 262144 (B*P*P)
  float* sq    = pd + 262144;        // 2048
  float* part  = g1buf;              // split-k partials alias g1+g2 region

  k_prep<<<dim3(128, 16), 256, 0, stream>>>(x, xh);
  k_instat<<<dim3(B_ * C_), 256, 0, stream>>>(x, m_in, v_in, r_in);
  k_affine<<<1, 128, 0, stream>>>(m_in, v_in, r_in, dpg, dpb, dug, dub, a_dp, d_dp, a_du, d_du);
  k_embed_mfma<0><<<dim3(64, 2, 16), 256, 0, stream>>>(xh, dpw, dpbias, a_dp, d_dp, EB);
  k_rowstat<<<dim3(B_ * K_), 256, 0, stream>>>(EB, mx, rden);
  k_xdown_mfma<<<dim3(2, 8, 16), 256, 0, stream>>>(x, EB, mx, part);
  k_xdown_red<<<dim3(2048), 256, 0, stream>>>(part, rden, xd);
  k_gram<<<dim3(4, 16), 256, 0, stream>>>(xd, pd);
  k_sq<<<dim3(16), 128, 0, stream>>>(xd, sq);
  k_topk<<<dim3(512), 256, 0, stream>>>(pd, sq, idxb);
  k_uv<<<dim3(2, 2, 16), 256, 0, stream>>>(xd, w1, U, V);
  k_edge<<<dim3(256, 16), 256, 0, stream>>>(U, V, idxb, b1, g1buf);
  k_bnstat<<<dim3(256), 256, 0, stream>>>(g1buf, g1g, g1b, bn1s, bn1h);
  k_conv2<<<dim3(6, 2, 16), 256, 0, stream>>>(g1buf, w2, b2, bn1s, bn1h, g2buf);
  k_bnstat<<<dim3(256), 256, 0, stream>>>(g2buf, g2g, g2b, bn2s, bn2h);
  k_gmax<<<dim3(2048), 256, 0, stream>>>(g2buf, bn2s, bn2h, gmax);
  k_m2<<<dim3(2, 16), 256, 0, stream>>>(gmax, scw, M2);
  k_embed_mfma<1><<<dim3(64, 2, 16), 256, 0, stream>>>(xh, duw, dubias, a_du, d_du, EB);
  k_colstat<<<dim3(B_ * N_ / 4), 256, 0, stream>>>(EB, mx2, rs2);
  k_final_mfma<<<dim3(64, 16), 256, 0, stream>>>(EB, xh, M2, scw, scb, mx2, rs2, out);
}

// Round 4
// 415.998 us; speedup vs baseline: 2.5190x; 1.1413x over previous
//
#include <hip/hip_runtime.h>

typedef __attribute__((ext_vector_type(4))) float f32x4;
typedef __attribute__((ext_vector_type(8))) short s16x8;
typedef __attribute__((ext_vector_type(8))) unsigned short u16x8;
typedef __attribute__((ext_vector_type(4))) unsigned short u16x4;

namespace {
constexpr int B_ = 16, C_ = 128, N_ = 8192, K_ = 256, P_ = 128, NB_ = 6;
constexpr int NSP = 16;  // xdown n-splits
}

__device__ __forceinline__ float bf2f(unsigned short h) {
  return __uint_as_float(((unsigned int)h) << 16);
}
__device__ __forceinline__ unsigned short f2bf(float f) {
  unsigned int u = __float_as_uint(f);
  return (unsigned short)((u + 0x7fffu + ((u >> 16) & 1u)) >> 16);
}
// async global->LDS, 16B per lane, lane l writes lds_base + l*16
__device__ __forceinline__ void gload_lds16(const void* gsrc, void* ldsdst) {
  __builtin_amdgcn_global_load_lds(
      (const __attribute__((address_space(1))) void*)gsrc,
      (__attribute__((address_space(3))) void*)ldsdst, 16, 0, 0);
}

// ---------------------------------------------------------------------------
// 0) prep: xh[b][n][c] bf16 (transpose) + xcn[b][c][n] bf16 (straight) from x
// ---------------------------------------------------------------------------
__global__ __launch_bounds__(256) void k_prep(const float* __restrict__ x,
                                              unsigned short* __restrict__ xh,
                                              unsigned short* __restrict__ xcn) {
  const int chunk = blockIdx.x, b = blockIdx.y;
  const int n0 = chunk * 64;
  __shared__ float ts[64][132];
  const int tid = threadIdx.x;
  for (int i = 0; i < 8; i++) {
    int q = tid + i * 256;
    int n4 = q & 15, c = q >> 4;
    float4 v = *reinterpret_cast<const float4*>(x + (size_t)(b * C_ + c) * N_ + n0 + 4 * n4);
    ts[4 * n4 + 0][c] = v.x; ts[4 * n4 + 1][c] = v.y;
    ts[4 * n4 + 2][c] = v.z; ts[4 * n4 + 3][c] = v.w;
    u16x4 p; p[0] = f2bf(v.x); p[1] = f2bf(v.y); p[2] = f2bf(v.z); p[3] = f2bf(v.w);
    *reinterpret_cast<u16x4*>(xcn + (size_t)(b * C_ + c) * N_ + n0 + 4 * n4) = p;
  }
  __syncthreads();
  for (int i = 0; i < 4; i++) {
    int q = tid + i * 256;
    int cg = q & 15, nn = q >> 4;
    u16x8 o;
#pragma unroll
    for (int j = 0; j < 8; j++) o[j] = f2bf(ts[nn][8 * cg + j]);
    *reinterpret_cast<u16x8*>(xh + (size_t)(b * N_ + n0 + nn) * C_ + 8 * cg) = o;
  }
}

// 0b) convert weights to bf16 once
__global__ __launch_bounds__(256) void k_wconv(const float* __restrict__ dpw,
                                               const float* __restrict__ duw,
                                               const float* __restrict__ scw,
                                               unsigned short* __restrict__ dpwh,
                                               unsigned short* __restrict__ duwh,
                                               unsigned short* __restrict__ scah) {
  int t = blockIdx.x * 256 + threadIdx.x;
  if (t < 32768) { dpwh[t] = f2bf(dpw[t]); duwh[t] = f2bf(duw[t]); }
  if (t < 16384) { int o = t >> 7, c = t & 127; scah[t] = f2bf(scw[o * 256 + c]); }
}

// ---------------------------------------------------------------------------
// 1) per-(b,c) instance-norm stats over N
// ---------------------------------------------------------------------------
__global__ __launch_bounds__(256) void k_instat(const float* __restrict__ x,
                                                float* __restrict__ m_o,
                                                float* __restrict__ v_o,
                                                float* __restrict__ r_o) {
  const int row = blockIdx.x;  // b*C + c
  const float4* xr = reinterpret_cast<const float4*>(x + (size_t)row * N_);
  float s = 0.f, ss = 0.f;
  for (int i = threadIdx.x; i < N_ / 4; i += 256) {
    float4 v = xr[i];
    s += v.x + v.y + v.z + v.w;
    ss += v.x * v.x + v.y * v.y + v.z * v.z + v.w * v.w;
  }
  __shared__ float rs[256], rq[256];
  rs[threadIdx.x] = s; rq[threadIdx.x] = ss;
  __syncthreads();
  for (int st = 128; st > 0; st >>= 1) {
    if (threadIdx.x < st) { rs[threadIdx.x] += rs[threadIdx.x + st]; rq[threadIdx.x] += rq[threadIdx.x + st]; }
    __syncthreads();
  }
  if (threadIdx.x == 0) {
    float m = rs[0] / N_;
    float v = rq[0] / N_ - m * m;
    m_o[row] = m; v_o[row] = v; r_o[row] = rsqrtf(v + 1e-3f);
  }
}

// ---------------------------------------------------------------------------
// 2) fold IN+BN into per-(b,c) affine (BN mean of IN(x) is analytically 0)
// ---------------------------------------------------------------------------
__global__ void k_affine(const float* __restrict__ m_in, const float* __restrict__ v_in,
                         const float* __restrict__ r_in,
                         const float* __restrict__ dpg, const float* __restrict__ dpb,
                         const float* __restrict__ dug, const float* __restrict__ dub,
                         float* __restrict__ a_dp, float* __restrict__ d_dp,
                         float* __restrict__ a_du, float* __restrict__ d_du) {
  int c = threadIdx.x;  // 128 threads
  float V = 0.f;
  for (int b = 0; b < B_; b++) { float v = v_in[b * C_ + c]; V += v / (v + 1e-3f); }
  V *= (1.f / B_);
  float R = rsqrtf(V + 1e-5f);
  float gdp = dpg[c], bdp = dpb[c], gdu = dug[c], bdu = dub[c];
  for (int b = 0; b < B_; b++) {
    int i = b * C_ + c;
    float r = r_in[i], m = m_in[i];
    float sdp = r * R * gdp;
    a_dp[i] = sdp; d_dp[i] = -m * sdp + bdp;
    float sdu = r * R * gdu;
    a_du[i] = sdu; d_du[i] = -m * sdu + bdu;
  }
}

// ---------------------------------------------------------------------------
// 3) embed via global_load_lds + fragment-time relu-affine transform
//    out[k,n] = sum_c w[k,c]*relu(a*x+d) + bias
//    MODE 0: EB [b][k][n] ; MODE 1: EBT [b][n][k]
//    LDS tiles linear [row][128c], XOR-swizzled chunks (chunk^=(row&7))
// ---------------------------------------------------------------------------
template <int MODE>
__global__ __launch_bounds__(256) void k_embed_g(const unsigned short* __restrict__ xh,
                                                 const unsigned short* __restrict__ wh,
                                                 const float* __restrict__ bias,
                                                 const float* __restrict__ aff_a,
                                                 const float* __restrict__ aff_d,
                                                 unsigned short* __restrict__ outp) {
  const int n0 = blockIdx.x * 128, k0 = blockIdx.y * 128, b = blockIdx.z;
  __shared__ __align__(16) unsigned short smem[2 * 128 * 128];
  unsigned short* tA = smem;              // [k][c] swizzled
  unsigned short* tB = smem + 128 * 128;  // [n][c] swizzled
  __shared__ float aff_as[128], aff_ds[128], bias_s[128];
  const int tid = threadIdx.x, lane = tid & 63, wid = tid >> 6;
  const int wr = wid >> 1, wc = wid & 1, l15 = lane & 15, l4 = lane >> 4;
  if (tid < 128) {
    aff_as[tid] = aff_a[b * C_ + tid];
    aff_ds[tid] = aff_d[b * C_ + tid];
    bias_s[tid] = bias[k0 + tid];
  }
  // stage: 32 calls per tile, 4 rows/call, inverse-swizzled global source
#pragma unroll
  for (int i = 0; i < 8; i++) {
    int call = wid * 8 + i;
    int row = call * 4 + (lane >> 4);
    int gch = (lane & 15) ^ (row & 7);
    gload_lds16(wh + (size_t)(k0 + row) * C_ + gch * 8, tA + call * 512);
    gload_lds16(xh + (size_t)(b * N_ + n0 + row) * C_ + gch * 8, tB + call * 512);
  }
  __syncthreads();
  f32x4 acc[4][4] = {};
#pragma unroll
  for (int ks = 0; ks < 128; ks += 32) {
    const int ch = (ks >> 3) + l4;
    s16x8 af[4], bfv[4];
#pragma unroll
    for (int m = 0; m < 4; m++) {
      int row = wr * 64 + m * 16 + l15;
      af[m] = *reinterpret_cast<const s16x8*>(tA + row * 128 + ((ch ^ (row & 7)) << 3));
    }
#pragma unroll
    for (int n = 0; n < 4; n++) {
      int row = wc * 64 + n * 16 + l15;
      s16x8 raw = *reinterpret_cast<const s16x8*>(tB + row * 128 + ((ch ^ (row & 7)) << 3));
      s16x8 h;
#pragma unroll
      for (int j = 0; j < 8; j++) {
        int c = ks + 8 * l4 + j;
        h[j] = (short)f2bf(fmaxf(fmaf(aff_as[c], bf2f((unsigned short)raw[j]), aff_ds[c]), 0.f));
      }
      bfv[n] = h;
    }
#pragma unroll
    for (int m = 0; m < 4; m++)
#pragma unroll
      for (int n = 0; n < 4; n++)
        acc[m][n] = __builtin_amdgcn_mfma_f32_16x16x32_bf16(af[m], bfv[n], acc[m][n], 0, 0, 0);
  }
  __syncthreads();
  // epilogue through LDS (aliases tiles); orientation depends on MODE
  unsigned short (*e_s)[136] = reinterpret_cast<unsigned short(*)[136]>(smem);
#pragma unroll
  for (int m = 0; m < 4; m++)
#pragma unroll
    for (int n = 0; n < 4; n++) {
      int kl = wr * 64 + m * 16 + 4 * l4;
      int nl = wc * 64 + n * 16 + l15;
#pragma unroll
      for (int r = 0; r < 4; r++) {
        unsigned short v = f2bf(acc[m][n][r] + bias_s[kl + r]);
        if (MODE == 0) e_s[kl + r][nl] = v;
        else           e_s[nl][kl + r] = v;
      }
    }
  __syncthreads();
  if (MODE == 0) {
    for (int i = 0; i < 8; i++) {
      int q = tid + i * 256;
      int cg = q & 15, kk = q >> 4;
      u16x8 v = *reinterpret_cast<const u16x8*>(&e_s[kk][8 * cg]);
      *reinterpret_cast<u16x8*>(outp + (size_t)(b * K_ + k0 + kk) * N_ + n0 + 8 * cg) = v;
    }
  } else {
    for (int i = 0; i < 8; i++) {
      int q = tid + i * 256;
      int kg = q & 15, nn = q >> 4;
      u16x8 v = *reinterpret_cast<const u16x8*>(&e_s[nn][8 * kg]);
      *reinterpret_cast<u16x8*>(outp + (size_t)(b * N_ + n0 + nn) * K_ + k0 + 8 * kg) = v;
    }
  }
}

// ---------------------------------------------------------------------------
// 4) per-(b,k) row max + sum(exp) over N (bf16 input)
// ---------------------------------------------------------------------------
__global__ __launch_bounds__(256) void k_rowstat(const unsigned short* __restrict__ EB,
                                                 float* __restrict__ mx, float* __restrict__ rden) {
  const int row = blockIdx.x;
  float m = -1e30f, s = 0.f;
  for (int i = threadIdx.x; i < N_ / 8; i += 256) {
    u16x8 v = *reinterpret_cast<const u16x8*>(EB + (size_t)row * N_ + 8 * i);
    float f[8];
#pragma unroll
    for (int j = 0; j < 8; j++) f[j] = bf2f(v[j]);
    float lm = f[0];
#pragma unroll
    for (int j = 1; j < 8; j++) lm = fmaxf(lm, f[j]);
    if (lm > m) { s *= __expf(m - lm); m = lm; }
#pragma unroll
    for (int j = 0; j < 8; j++) s += __expf(f[j] - m);
  }
  __shared__ float rm[256], rsum[256];
  rm[threadIdx.x] = m; rsum[threadIdx.x] = s;
  __syncthreads();
  for (int st = 128; st > 0; st >>= 1) {
    if (threadIdx.x < st) {
      float m1 = rm[threadIdx.x], s1 = rsum[threadIdx.x];
      float m2 = rm[threadIdx.x + st], s2 = rsum[threadIdx.x + st];
      float M = fmaxf(m1, m2);
      rm[threadIdx.x] = M;
      rsum[threadIdx.x] = s1 * __expf(m1 - M) + s2 * __expf(m2 - M);
    }
    __syncthreads();
  }
  if (threadIdx.x == 0) { mx[row] = rm[0]; rden[row] = 1.f / rsum[0]; }
}

// ---------------------------------------------------------------------------
// 5) x_down partials: part[sp][b][c][k] = sum_{n in split} x[c,n]*exp(EB[k,n]-mx)
//    global_load_lds staging; exp at fragment-read time
// ---------------------------------------------------------------------------
__global__ __launch_bounds__(256) void k_xdown_g(const unsigned short* __restrict__ xcn,
                                                 const unsigned short* __restrict__ EB,
                                                 const float* __restrict__ mx,
                                                 float* __restrict__ part) {
  const int k0 = blockIdx.x * 128, sp = blockIdx.y, b = blockIdx.z;
  const int nbase = sp * (N_ / NSP);
  __shared__ __align__(16) unsigned short smem[2 * 128 * 128];
  unsigned short* tA = smem;              // [c][n]
  unsigned short* tB = smem + 128 * 128;  // [k][n]
  __shared__ float mxs[128];
  const int tid = threadIdx.x, lane = tid & 63, wid = tid >> 6;
  const int wr = wid >> 1, wc = wid & 1, l15 = lane & 15, l4 = lane >> 4;
  if (tid < 128) mxs[tid] = mx[b * K_ + k0 + tid];
  f32x4 acc[4][4] = {};
  for (int nc = 0; nc < N_ / NSP; nc += 128) {
    const int n0 = nbase + nc;
#pragma unroll
    for (int i = 0; i < 8; i++) {
      int call = wid * 8 + i;
      int row = call * 4 + (lane >> 4);
      int gch = (lane & 15) ^ (row & 7);
      gload_lds16(xcn + (size_t)(b * C_ + row) * N_ + n0 + gch * 8, tA + call * 512);
      gload_lds16(EB + (size_t)(b * K_ + k0 + row) * N_ + n0 + gch * 8, tB + call * 512);
    }
    __syncthreads();
#pragma unroll
    for (int ks = 0; ks < 128; ks += 32) {
      const int ch = (ks >> 3) + l4;
      s16x8 af[4], bfv[4];
#pragma unroll
      for (int m = 0; m < 4; m++) {
        int row = wr * 64 + m * 16 + l15;
        af[m] = *reinterpret_cast<const s16x8*>(tA + row * 128 + ((ch ^ (row & 7)) << 3));
      }
#pragma unroll
      for (int n = 0; n < 4; n++) {
        int row = wc * 64 + n * 16 + l15;
        s16x8 raw = *reinterpret_cast<const s16x8*>(tB + row * 128 + ((ch ^ (row & 7)) << 3));
        float mv = mxs[row];
        s16x8 h;
#pragma unroll
        for (int j = 0; j < 8; j++)
          h[j] = (short)f2bf(__expf(bf2f((unsigned short)raw[j]) - mv));
        bfv[n] = h;
      }
#pragma unroll
      for (int m = 0; m < 4; m++)
#pragma unroll
        for (int n = 0; n < 4; n++)
          acc[m][n] = __builtin_amdgcn_mfma_f32_16x16x32_bf16(af[m], bfv[n], acc[m][n], 0, 0, 0);
    }
    __syncthreads();
  }
#pragma unroll
  for (int m = 0; m < 4; m++)
#pragma unroll
    for (int n = 0; n < 4; n++) {
      int c = wr * 64 + m * 16 + 4 * l4;
      int k = k0 + wc * 64 + n * 16 + l15;
#pragma unroll
      for (int r = 0; r < 4; r++)
        part[((size_t)(sp * B_ + b) * C_ + c + r) * K_ + k] = acc[m][n][r];
    }
}

// 6) reduce split partials, scale by 1/den -> x_down[b][c][k]
__global__ __launch_bounds__(256) void k_xdown_red(const float* __restrict__ part,
                                                   const float* __restrict__ rden,
                                                   float* __restrict__ xd) {
  int e = blockIdx.x * 256 + threadIdx.x;  // B*C*K
  int k = e % K_;
  int c = (e / K_) % C_;
  int b = e / (K_ * C_);
  float s = 0.f;
  for (int sp = 0; sp < NSP; sp++) s += part[((size_t)(sp * B_ + b) * C_ + c) * K_ + k];
  xd[e] = s * rden[b * K_ + k];
}

// ---------------------------------------------------------------------------
// 7a) gram tiles: pd[b][p][q] = sum_k xd[b][p][k]*xd[b][q][k]
// ---------------------------------------------------------------------------
__global__ __launch_bounds__(256) void k_gram(const float* __restrict__ xd,
                                              float* __restrict__ pd) {
  const int p0 = blockIdx.x * 32, b = blockIdx.y;
  __shared__ float A[32][36];
  __shared__ float Bt[32][132];
  const int tid = threadIdx.x;
  const int tr = tid >> 5, tc = tid & 31;
  float acc[4][4] = {};
  for (int k0 = 0; k0 < K_; k0 += 32) {
    {
      int pp = tid >> 3, k4 = tid & 7;
      float4 v = *reinterpret_cast<const float4*>(xd + (size_t)(b * C_ + p0 + pp) * K_ + k0 + 4 * k4);
      A[4 * k4 + 0][pp] = v.x; A[4 * k4 + 1][pp] = v.y;
      A[4 * k4 + 2][pp] = v.z; A[4 * k4 + 3][pp] = v.w;
    }
    for (int i = 0; i < 4; i++) {
      int q = tid + i * 256;
      int qq = q >> 3, k4 = q & 7;
      float4 v = *reinterpret_cast<const float4*>(xd + (size_t)(b * C_ + qq) * K_ + k0 + 4 * k4);
      Bt[4 * k4 + 0][qq] = v.x; Bt[4 * k4 + 1][qq] = v.y;
      Bt[4 * k4 + 2][qq] = v.z; Bt[4 * k4 + 3][qq] = v.w;
    }
    __syncthreads();
    for (int kk = 0; kk < 32; ++kk) {
      float4 av = *reinterpret_cast<const float4*>(&A[kk][tr * 4]);
      float4 bv = *reinterpret_cast<const float4*>(&Bt[kk][tc * 4]);
      float a[4] = {av.x, av.y, av.z, av.w};
      float bb[4] = {bv.x, bv.y, bv.z, bv.w};
#pragma unroll
      for (int i = 0; i < 4; ++i)
#pragma unroll
        for (int j = 0; j < 4; ++j) acc[i][j] = fmaf(a[i], bb[j], acc[i][j]);
    }
    __syncthreads();
  }
#pragma unroll
  for (int i = 0; i < 4; ++i) {
    float4 r; r.x = acc[i][0]; r.y = acc[i][1]; r.z = acc[i][2]; r.w = acc[i][3];
    *reinterpret_cast<float4*>(pd + (size_t)(b * P_ + p0 + tr * 4 + i) * P_ + tc * 4) = r;
  }
}

// 7b) sq[b][p] = ||xd[b][p][:]||^2
__global__ __launch_bounds__(128) void k_sq(const float* __restrict__ xd,
                                            float* __restrict__ sq) {
  const int b = blockIdx.x, p = threadIdx.x;
  const float4* r = reinterpret_cast<const float4*>(xd + (size_t)(b * C_ + p) * K_);
  float s = 0.f;
  for (int i = 0; i < K_ / 4; i++) { float4 v = r[i]; s += v.x * v.x + v.y * v.y + v.z * v.z + v.w * v.w; }
  sq[b * P_ + p] = s;
}

// 7c) top-6 per point: one wave per point, 6 rounds of wave argmax
__global__ __launch_bounds__(256) void k_topk(const float* __restrict__ pd,
                                              const float* __restrict__ sq,
                                              int* __restrict__ idx) {
  const int wid = threadIdx.x >> 6, lane = threadIdx.x & 63;
  const int gp = blockIdx.x * 4 + wid;  // b*P + p
  const int b = gp >> 7;
  const float* row = pd + (size_t)gp * P_;
  float v0 = 2.f * row[lane] - sq[b * P_ + lane];
  float v1 = 2.f * row[lane + 64] - sq[b * P_ + lane + 64];
  int q0 = lane, q1 = lane + 64;
#pragma unroll
  for (int j = 0; j < NB_; j++) {
    float bv; int bq;
    if (v0 > v1 || (v0 == v1 && q0 < q1)) { bv = v0; bq = q0; } else { bv = v1; bq = q1; }
#pragma unroll
    for (int o = 32; o > 0; o >>= 1) {
      float ov = __shfl_xor(bv, o); int oq = __shfl_xor(bq, o);
      if (ov > bv || (ov == bv && oq < bq)) { bv = ov; bq = oq; }
    }
    if (lane == 0) idx[gp * NB_ + j] = bq;
    if (q0 == bq) v0 = -3.0e38f;
    if (q1 == bq) v1 = -3.0e38f;
  }
}

// ---------------------------------------------------------------------------
// 8) U = (W1a+W1b)@feats ; V = W1b@feats  (fp32)
// ---------------------------------------------------------------------------
__global__ __launch_bounds__(256) void k_uv(const float* __restrict__ xd,
                                            const float* __restrict__ w1,
                                            float* __restrict__ U, float* __restrict__ V) {
  const int b = blockIdx.z, o0 = blockIdx.y * 128, which = blockIdx.x;
  __shared__ float a_s[64][133];
  __shared__ float b_s[64][133];
  const int tid = threadIdx.x;
  const int og = tid / 16, pg = tid % 16;
  float acc[8][8] = {};
  for (int k0 = 0; k0 < K_; k0 += 64) {
    for (int q = tid; q < 64 * 128 / 4; q += 256) {
      int oo = q / 16, k4 = q % 16;
      const float* wr = w1 + (size_t)(o0 + oo) * 512 + k0 + k4 * 4;
      float4 vb = *reinterpret_cast<const float4*>(wr + 256);
      if (which == 0) {
        float4 va = *reinterpret_cast<const float4*>(wr);
        vb.x += va.x; vb.y += va.y; vb.z += va.z; vb.w += va.w;
      }
      a_s[k4 * 4 + 0][oo] = vb.x; a_s[k4 * 4 + 1][oo] = vb.y;
      a_s[k4 * 4 + 2][oo] = vb.z; a_s[k4 * 4 + 3][oo] = vb.w;
    }
    for (int q = tid; q < 64 * 128 / 4; q += 256) {
      int p = q / 16, k4 = q % 16;
      float4 v = *reinterpret_cast<const float4*>(xd + (size_t)(b * C_ + p) * K_ + k0 + k4 * 4);
      b_s[k4 * 4 + 0][p] = v.x; b_s[k4 * 4 + 1][p] = v.y;
      b_s[k4 * 4 + 2][p] = v.z; b_s[k4 * 4 + 3][p] = v.w;
    }
    __syncthreads();
    for (int kk = 0; kk < 64; ++kk) {
      float av[8], bv[8];
#pragma unroll
      for (int i = 0; i < 8; ++i) av[i] = a_s[kk][og * 8 + i];
#pragma unroll
      for (int j = 0; j < 8; ++j) bv[j] = b_s[kk][pg + 16 * j];
#pragma unroll
      for (int i = 0; i < 8; ++i)
#pragma unroll
        for (int j = 0; j < 8; ++j) acc[i][j] = fmaf(av[i], bv[j], acc[i][j]);
    }
    __syncthreads();
  }
  float* outp = (which == 0) ? U : V;
#pragma unroll
  for (int i = 0; i < 8; ++i)
#pragma unroll
    for (int j = 0; j < 8; ++j)
      outp[(size_t)(b * K_ + o0 + og * 8 + i) * P_ + pg + 16 * j] = acc[i][j];
}

// 9) g1[b,o,p,j] = U[p] - V[idx[p,j]] + b1[o]
__global__ __launch_bounds__(256) void k_edge(const float* __restrict__ U,
                                              const float* __restrict__ V,
                                              const int* __restrict__ idx,
                                              const float* __restrict__ b1,
                                              float* __restrict__ g1) {
  const int o = blockIdx.x, b = blockIdx.y;
  __shared__ float U_s[128], V_s[128];
  const int tid = threadIdx.x;
  if (tid < 128) {
    U_s[tid] = U[(size_t)(b * K_ + o) * P_ + tid];
    V_s[tid] = V[(size_t)(b * K_ + o) * P_ + tid];
  }
  __syncthreads();
  const float bias = b1[o];
  for (int e = tid; e < P_ * NB_; e += 256) {
    int p = e / NB_;
    int q = idx[b * P_ * NB_ + e];
    g1[(size_t)(b * K_ + o) * (P_ * NB_) + e] = U_s[p] + bias - V_s[q];
  }
}

// 10/12) BN stats per channel o over (b,p,j)
__global__ __launch_bounds__(256) void k_bnstat(const float* __restrict__ g,
                                                const float* __restrict__ gamma,
                                                const float* __restrict__ beta,
                                                float* __restrict__ scale,
                                                float* __restrict__ shift) {
  const int o = blockIdx.x;
  float s = 0.f, ss = 0.f;
  for (int e = threadIdx.x; e < B_ * P_ * NB_; e += 256) {
    int b = e / (P_ * NB_), r = e % (P_ * NB_);
    float v = g[(size_t)(b * K_ + o) * (P_ * NB_) + r];
    s += v; ss += v * v;
  }
  __shared__ float rs[256], rq[256];
  rs[threadIdx.x] = s; rq[threadIdx.x] = ss;
  __syncthreads();
  for (int st = 128; st > 0; st >>= 1) {
    if (threadIdx.x < st) { rs[threadIdx.x] += rs[threadIdx.x + st]; rq[threadIdx.x] += rq[threadIdx.x + st]; }
    __syncthreads();
  }
  if (threadIdx.x == 0) {
    const float cnt = (float)(B_ * P_ * NB_);
    float m = rs[0] / cnt;
    float var = rq[0] / cnt - m * m;
    float sc = gamma[o] * rsqrtf(var + 1e-5f);
    scale[o] = sc; shift[o] = -m * sc + beta[o];
  }
}

// 11) g2 = W2 @ relu(bn1(g1)) + b2 (fp32)
__global__ __launch_bounds__(256) void k_conv2(const float* __restrict__ g1,
                                               const float* __restrict__ w2,
                                               const float* __restrict__ b2,
                                               const float* __restrict__ bn1s,
                                               const float* __restrict__ bn1h,
                                               float* __restrict__ g2) {
  const int b = blockIdx.z, o0 = blockIdx.y * 128, n0 = blockIdx.x * 128;
  __shared__ float a_s[64][133];
  __shared__ float b_s[64][132];
  const int tid = threadIdx.x;
  const int og = tid / 16, ng = tid % 16;
  float acc[8][8] = {};
  for (int c0 = 0; c0 < K_; c0 += 64) {
    for (int q = tid; q < 64 * 128 / 4; q += 256) {
      int oo = q / 16, c4 = q % 16;
      float4 v = *reinterpret_cast<const float4*>(w2 + (size_t)(o0 + oo) * K_ + c0 + c4 * 4);
      a_s[c4 * 4 + 0][oo] = v.x; a_s[c4 * 4 + 1][oo] = v.y;
      a_s[c4 * 4 + 2][oo] = v.z; a_s[c4 * 4 + 3][oo] = v.w;
    }
    for (int q = tid; q < 64 * 128 / 4; q += 256) {
      int cc = q / 32, n4 = q % 32;
      int c = c0 + cc;
      float sc = bn1s[c], sh = bn1h[c];
      float4 v = *reinterpret_cast<const float4*>(g1 + (size_t)(b * K_ + c) * (P_ * NB_) + n0 + n4 * 4);
      float4 hv;
      hv.x = fmaxf(fmaf(sc, v.x, sh), 0.f); hv.y = fmaxf(fmaf(sc, v.y, sh), 0.f);
      hv.z = fmaxf(fmaf(sc, v.z, sh), 0.f); hv.w = fmaxf(fmaf(sc, v.w, sh), 0.f);
      *reinterpret_cast<float4*>(&b_s[cc][n4 * 4]) = hv;
    }
    __syncthreads();
    for (int cc = 0; cc < 64; ++cc) {
      float av[8], bv[8];
#pragma unroll
      for (int i = 0; i < 8; ++i) av[i] = a_s[cc][og * 8 + i];
#pragma unroll
      for (int j = 0; j < 8; ++j) bv[j] = b_s[cc][ng + 16 * j];
#pragma unroll
      for (int i = 0; i < 8; ++i)
#pragma unroll
        for (int j = 0; j < 8; ++j) acc[i][j] = fmaf(av[i], bv[j], acc[i][j]);
    }
    __syncthreads();
  }
#pragma unroll
  for (int i = 0; i < 8; ++i) {
    int o = o0 + og * 8 + i;
    float bb = b2[o];
#pragma unroll
    for (int j = 0; j < 8; ++j)
      g2[(size_t)(b * K_ + o) * (P_ * NB_) + n0 + ng + 16 * j] = acc[i][j] + bb;
  }
}

// 13) gmax[b][k][c] = max_j relu(bn2(g2))
__global__ __launch_bounds__(256) void k_gmax(const float* __restrict__ g2,
                                              const float* __restrict__ bn2s,
                                              const float* __restrict__ bn2h,
                                              float* __restrict__ gmax) {
  int e = blockIdx.x * 256 + threadIdx.x;  // B*K*P
  int c = e % P_;
  int k = (e / P_) % K_;
  int b = e / (P_ * K_);
  const float* gp = g2 + (size_t)(b * K_ + k) * (P_ * NB_) + c * NB_;
  float sc = bn2s[k], sh = bn2h[k];
  float m = 0.f;
#pragma unroll
  for (int j = 0; j < NB_; j++) m = fmaxf(m, fmaf(sc, gp[j], sh));
  gmax[e] = m;
}

// 14) M2h[b][o][k] = bf16( sum_c sc_w[o,128+c] * gmax[b][k][c] )
__global__ __launch_bounds__(256) void k_m2(const float* __restrict__ gmax,
                                            const float* __restrict__ scw,
                                            unsigned short* __restrict__ M2h) {
  const int b = blockIdx.y, k0 = blockIdx.x * 128;
  __shared__ float a_s[64][133];
  __shared__ float b_s[64][133];
  const int tid = threadIdx.x;
  const int og = tid / 16, kg = tid % 16;
  float acc[8][8] = {};
  for (int c0 = 0; c0 < C_; c0 += 64) {
    for (int q = tid; q < 64 * 128 / 4; q += 256) {
      int oo = q / 16, c4 = q % 16;
      float4 v = *reinterpret_cast<const float4*>(scw + (size_t)oo * 256 + 128 + c0 + c4 * 4);
      a_s[c4 * 4 + 0][oo] = v.x; a_s[c4 * 4 + 1][oo] = v.y;
      a_s[c4 * 4 + 2][oo] = v.z; a_s[c4 * 4 + 3][oo] = v.w;
    }
    for (int q = tid; q < 64 * 128 / 4; q += 256) {
      int kk = q / 16, c4 = q % 16;
      float4 v = *reinterpret_cast<const float4*>(gmax + (size_t)(b * K_ + k0 + kk) * P_ + c0 + c4 * 4);
      b_s[c4 * 4 + 0][kk] = v.x; b_s[c4 * 4 + 1][kk] = v.y;
      b_s[c4 * 4 + 2][kk] = v.z; b_s[c4 * 4 + 3][kk] = v.w;
    }
    __syncthreads();
    for (int cc = 0; cc < 64; ++cc) {
      float av[8], bv[8];
#pragma unroll
      for (int i = 0; i < 8; ++i) av[i] = a_s[cc][og * 8 + i];
#pragma unroll
      for (int j = 0; j < 8; ++j) bv[j] = b_s[cc][kg + 16 * j];
#pragma unroll
      for (int i = 0; i < 8; ++i)
#pragma unroll
        for (int j = 0; j < 8; ++j) acc[i][j] = fmaf(av[i], bv[j], acc[i][j]);
    }
    __syncthreads();
  }
#pragma unroll
  for (int i = 0; i < 8; ++i)
#pragma unroll
    for (int j = 0; j < 8; ++j)
      M2h[(size_t)(b * C_ + og * 8 + i) * K_ + k0 + kg + 16 * j] = f2bf(acc[i][j]);
}

// ---------------------------------------------------------------------------
// 15) per-(b,n) softmax-over-k stats from EBT[b][n][k] bf16
// ---------------------------------------------------------------------------
__global__ __launch_bounds__(256) void k_colstat(const unsigned short* __restrict__ EBT,
                                                 float* __restrict__ mx2, float* __restrict__ rs2) {
  const int wid = threadIdx.x >> 6, lane = threadIdx.x & 63;
  const int bn = blockIdx.x * 4 + wid;  // b*N + n
  u16x4 v = *reinterpret_cast<const u16x4*>(EBT + (size_t)bn * K_ + 4 * lane);
  float f0 = bf2f(v[0]), f1 = bf2f(v[1]), f2 = bf2f(v[2]), f3 = bf2f(v[3]);
  float m = fmaxf(fmaxf(f0, f1), fmaxf(f2, f3));
  for (int o = 32; o > 0; o >>= 1) m = fmaxf(m, __shfl_xor(m, o));
  float s = __expf(f0 - m) + __expf(f1 - m) + __expf(f2 - m) + __expf(f3 - m);
  for (int o = 32; o > 0; o >>= 1) s += __shfl_xor(s, o);
  if (lane == 0) { mx2[bn] = m; rs2[bn] = 1.f / s; }
}

// ---------------------------------------------------------------------------
// 16) out[o,n] = scwA@x + M2@softmax_k(EBT) + scb  (global_load_lds staging)
// ---------------------------------------------------------------------------
__global__ __launch_bounds__(256) void k_final_g(const unsigned short* __restrict__ EBT,
                                                 const unsigned short* __restrict__ xh,
                                                 const unsigned short* __restrict__ M2h,
                                                 const unsigned short* __restrict__ scah,
                                                 const float* __restrict__ scb,
                                                 const float* __restrict__ mx2,
                                                 const float* __restrict__ rs2,
                                                 float* __restrict__ out) {
  const int n0 = blockIdx.x * 128, b = blockIdx.y;
  __shared__ __align__(16) unsigned short smem[2 * 128 * 128];
  unsigned short* tA = smem;
  unsigned short* tB = smem + 128 * 128;
  __shared__ float mx2s[128], rs2s[128], scb_s[128];
  const int tid = threadIdx.x, lane = tid & 63, wid = tid >> 6;
  const int wr = wid >> 1, wc = wid & 1, l15 = lane & 15, l4 = lane >> 4;
  if (tid < 128) {
    mx2s[tid] = mx2[b * N_ + n0 + tid];
    rs2s[tid] = rs2[b * N_ + n0 + tid];
    scb_s[tid] = scb[tid];
  }
  f32x4 acc[4][4] = {};
  // ---- phase A: contraction over c (scwA @ x) ----
#pragma unroll
  for (int i = 0; i < 8; i++) {
    int call = wid * 8 + i;
    int row = call * 4 + (lane >> 4);
    int gch = (lane & 15) ^ (row & 7);
    gload_lds16(scah + (size_t)row * C_ + gch * 8, tA + call * 512);
    gload_lds16(xh + (size_t)(b * N_ + n0 + row) * C_ + gch * 8, tB + call * 512);
  }
  __syncthreads();
#pragma unroll
  for (int ks = 0; ks < 128; ks += 32) {
    const int ch = (ks >> 3) + l4;
    s16x8 af[4], bfv[4];
#pragma unroll
    for (int m = 0; m < 4; m++) {
      int row = wr * 64 + m * 16 + l15;
      af[m] = *reinterpret_cast<const s16x8*>(tA + row * 128 + ((ch ^ (row & 7)) << 3));
    }
#pragma unroll
    for (int n = 0; n < 4; n++) {
      int row = wc * 64 + n * 16 + l15;
      bfv[n] = *reinterpret_cast<const s16x8*>(tB + row * 128 + ((ch ^ (row & 7)) << 3));
    }
#pragma unroll
    for (int m = 0; m < 4; m++)
#pragma unroll
      for (int n = 0; n < 4; n++)
        acc[m][n] = __builtin_amdgcn_mfma_f32_16x16x32_bf16(af[m], bfv[n], acc[m][n], 0, 0, 0);
  }
  __syncthreads();
  // ---- phase B: contraction over k (M2 @ softmax), two 128-halves ----
  for (int kh = 0; kh < K_; kh += 128) {
#pragma unroll
    for (int i = 0; i < 8; i++) {
      int call = wid * 8 + i;
      int row = call * 4 + (lane >> 4);
      int gch = (lane & 15) ^ (row & 7);
      gload_lds16(M2h + (size_t)(b * C_ + row) * K_ + kh + gch * 8, tA + call * 512);
      gload_lds16(EBT + (size_t)(b * N_ + n0 + row) * K_ + kh + gch * 8, tB + call * 512);
    }
    __syncthreads();
#pragma unroll
    for (int ks = 0; ks < 128; ks += 32) {
      const int ch = (ks >> 3) + l4;
      s16x8 af[4], bfv[4];
#pragma unroll
      for (int m = 0; m < 4; m++) {
        int row = wr * 64 + m * 16 + l15;
        af[m] = *reinterpret_cast<const s16x8*>(tA + row * 128 + ((ch ^ (row & 7)) << 3));
      }
#pragma unroll
      for (int n = 0; n < 4; n++) {
        int row = wc * 64 + n * 16 + l15;
        s16x8 raw = *reinterpret_cast<const s16x8*>(tB + row * 128 + ((ch ^ (row & 7)) << 3));
        float mv = mx2s[row], rv = rs2s[row];
        s16x8 h;
#pragma unroll
        for (int j = 0; j < 8; j++)
          h[j] = (short)f2bf(__expf(bf2f((unsigned short)raw[j]) - mv) * rv);
        bfv[n] = h;
      }
#pragma unroll
      for (int m = 0; m < 4; m++)
#pragma unroll
        for (int n = 0; n < 4; n++)
          acc[m][n] = __builtin_amdgcn_mfma_f32_16x16x32_bf16(af[m], bfv[n], acc[m][n], 0, 0, 0);
    }
    __syncthreads();
  }
#pragma unroll
  for (int m = 0; m < 4; m++)
#pragma unroll
    for (int n = 0; n < 4; n++) {
      int o = wr * 64 + m * 16 + 4 * l4;
      int nn = n0 + wc * 64 + n * 16 + l15;
#pragma unroll
      for (int r = 0; r < 4; r++)
        out[(size_t)(b * C_ + o + r) * N_ + nn] = acc[m][n][r] + scb_s[o + r];
    }
}

// ---------------------------------------------------------------------------
extern "C" void kernel_launch(void* const* d_in, const int* in_sizes, int n_in,
                              void* d_out, int out_size, void* d_ws, size_t ws_size,
                              hipStream_t stream) {
  (void)in_sizes; (void)n_in; (void)out_size; (void)ws_size;
  const float* x      = (const float*)d_in[0];
  const float* dpg    = (const float*)d_in[1];
  const float* dpb    = (const float*)d_in[2];
  const float* dpw    = (const float*)d_in[3];
  const float* dpbias = (const float*)d_in[4];
  const float* dug    = (const float*)d_in[5];
  const float* dub    = (const float*)d_in[6];
  const float* duw    = (const float*)d_in[7];
  const float* dubias = (const float*)d_in[8];
  const float* w1     = (const float*)d_in[9];
  const float* b1     = (const float*)d_in[10];
  const float* g1g    = (const float*)d_in[11];
  const float* g1b    = (const float*)d_in[12];
  const float* w2     = (const float*)d_in[13];
  const float* b2     = (const float*)d_in[14];
  const float* g2g    = (const float*)d_in[15];
  const float* g2b    = (const float*)d_in[16];
  const float* scw    = (const float*)d_in[17];
  const float* scb    = (const float*)d_in[18];
  float* out = (float*)d_out;
  float* ws  = (float*)d_ws;

  // workspace layout (float-slot units)
  unsigned short* EB  = (unsigned short*)ws;               // B*K*N bf16 (16,777,216 slots); later EBT
  unsigned short* xh  = (unsigned short*)(ws + 16777216);  // B*N*C bf16 (8,388,608 slots)
  unsigned short* xcn = (unsigned short*)(ws + 25165824);  // B*C*N bf16 (8,388,608 slots)
  float* base  = ws + 33554432;
  float* m_in  = base;               // 2048
  float* v_in  = m_in + 2048;
  float* r_in  = v_in + 2048;
  float* a_dp  = r_in + 2048;
  float* d_dp  = a_dp + 2048;
  float* a_du  = d_dp + 2048;
  float* d_du  = a_du + 2048;
  float* mx    = d_du + 2048;        // 4096
  float* rden  = mx + 4096;          // 4096
  float* mx2   = rden + 4096;        // 131072
  float* rs2   = mx2 + 131072;       // 131072
  float* xd    = rs2 + 131072;       // 524288
  float* U     = xd + 524288;        // 524288
  float* V     = U + 524288;         // 524288
  int*   idxb  = (int*)(V + 524288); // 12288
  float* bn1s  = (float*)(idxb + 12288);
  float* bn1h  = bn1s + 256;
  float* bn2s  = bn1h + 256;
  float* bn2h  = bn2s + 256;
  float* sq    = bn2h + 256;         // 2048
  float* pd    = sq + 2048;          // 262144
  float* gmax  = pd + 262144;        // 524288
  unsigned short* dpwh = (unsigned short*)(gmax + 524288);       // 32768 shorts (16384 slots)
  unsigned short* duwh = (unsigned short*)(gmax + 524288 + 16384);
  unsigned short* scah = (unsigned short*)(gmax + 524288 + 32768); // 16384 shorts (8192 slots)
  unsigned short* M2h  = (unsigned short*)(gmax + 524288 + 40960); // 524288 shorts (262144 slots)
  float* part  = gmax + 524288 + 40960 + 262144;  // NSP*B*C*K = 8,388,608
  float* g1buf = part;                             // reuse after xdown_red
  float* g2buf = part + 3145728;

  k_prep<<<dim3(128, 16), 256, 0, stream>>>(x, xh, xcn);
  k_wconv<<<dim3(128), 256, 0, stream>>>(dpw, duw, scw, dpwh, duwh, scah);
  k_instat<<<dim3(B_ * C_), 256, 0, stream>>>(x, m_in, v_in, r_in);
  k_affine<<<1, 128, 0, stream>>>(m_in, v_in, r_in, dpg, dpb, dug, dub, a_dp, d_dp, a_du, d_du);
  k_embed_g<0><<<dim3(64, 2, 16), 256, 0, stream>>>(xh, dpwh, dpbias, a_dp, d_dp, EB);
  k_rowstat<<<dim3(B_ * K_), 256, 0, stream>>>(EB, mx, rden);
  k_xdown_g<<<dim3(2, NSP, 16), 256, 0, stream>>>(xcn, EB, mx, part);
  k_xdown_red<<<dim3(2048), 256, 0, stream>>>(part, rden, xd);
  k_gram<<<dim3(4, 16), 256, 0, stream>>>(xd, pd);
  k_sq<<<dim3(16), 128, 0, stream>>>(xd, sq);
  k_topk<<<dim3(512), 256, 0, stream>>>(pd, sq, idxb);
  k_uv<<<dim3(2, 2, 16), 256, 0, stream>>>(xd, w1, U, V);
  k_edge<<<dim3(256, 16), 256, 0, stream>>>(U, V, idxb, b1, g1buf);
  k_bnstat<<<dim3(256), 256, 0, stream>>>(g1buf, g1g, g1b, bn1s, bn1h);
  k_conv2<<<dim3(6, 2, 16), 256, 0, stream>>>(g1buf, w2, b2, bn1s, bn1h, g2buf);
  k_bnstat<<<dim3(256), 256, 0, stream>>>(g2buf, g2g, g2b, bn2s, bn2h);
  k_gmax<<<dim3(2048), 256, 0, stream>>>(g2buf, bn2s, bn2h, gmax);
  k_m2<<<dim3(2, 16), 256, 0, stream>>>(gmax, scw, M2h);
  k_embed_g<1><<<dim3(64, 2, 16), 256, 0, stream>>>(xh, duwh, dubias, a_du, d_du, EB);
  k_colstat<<<dim3(B_ * N_ / 4), 256, 0, stream>>>(EB, mx2, rs2);
  k_final_g<<<dim3(64, 16), 256, 0, stream>>>(EB, xh, M2h, scah, scb, mx2, rs2, out);
}

// Round 5
// 309.074 us; speedup vs baseline: 3.3905x; 1.3459x over previous
//
#include <hip/hip_runtime.h>

typedef __attribute__((ext_vector_type(4))) float f32x4;
typedef __attribute__((ext_vector_type(8))) short s16x8;
typedef __attribute__((ext_vector_type(8))) unsigned short u16x8;
typedef __attribute__((ext_vector_type(4))) unsigned short u16x4;

namespace {
constexpr int B_ = 16, C_ = 128, N_ = 8192, K_ = 256, P_ = 128, NB_ = 6;
constexpr int NSP = 16;  // xdown n-splits
}

__device__ __forceinline__ float bf2f(unsigned short h) {
  return __uint_as_float(((unsigned int)h) << 16);
}
__device__ __forceinline__ unsigned short f2bf(float f) {
  unsigned int u = __float_as_uint(f);
  return (unsigned short)((u + 0x7fffu + ((u >> 16) & 1u)) >> 16);
}
// async global->LDS, 16B per lane, lane l writes lds_base + l*16
__device__ __forceinline__ void gload_lds16(const void* gsrc, void* ldsdst) {
  __builtin_amdgcn_global_load_lds(
      (const __attribute__((address_space(1))) void*)gsrc,
      (__attribute__((address_space(3))) void*)ldsdst, 16, 0, 0);
}

// ---------------------------------------------------------------------------
// 0) prep: xh[b][n][c] bf16 (transpose) + xcn[b][c][n] bf16 (straight) from x
// ---------------------------------------------------------------------------
__global__ __launch_bounds__(256) void k_prep(const float* __restrict__ x,
                                              unsigned short* __restrict__ xh,
                                              unsigned short* __restrict__ xcn) {
  const int chunk = blockIdx.x, b = blockIdx.y;
  const int n0 = chunk * 64;
  __shared__ float ts[64][132];
  const int tid = threadIdx.x;
  for (int i = 0; i < 8; i++) {
    int q = tid + i * 256;
    int n4 = q & 15, c = q >> 4;
    float4 v = *reinterpret_cast<const float4*>(x + (size_t)(b * C_ + c) * N_ + n0 + 4 * n4);
    ts[4 * n4 + 0][c] = v.x; ts[4 * n4 + 1][c] = v.y;
    ts[4 * n4 + 2][c] = v.z; ts[4 * n4 + 3][c] = v.w;
    u16x4 p; p[0] = f2bf(v.x); p[1] = f2bf(v.y); p[2] = f2bf(v.z); p[3] = f2bf(v.w);
    *reinterpret_cast<u16x4*>(xcn + (size_t)(b * C_ + c) * N_ + n0 + 4 * n4) = p;
  }
  __syncthreads();
  for (int i = 0; i < 4; i++) {
    int q = tid + i * 256;
    int cg = q & 15, nn = q >> 4;
    u16x8 o;
#pragma unroll
    for (int j = 0; j < 8; j++) o[j] = f2bf(ts[nn][8 * cg + j]);
    *reinterpret_cast<u16x8*>(xh + (size_t)(b * N_ + n0 + nn) * C_ + 8 * cg) = o;
  }
}

// 0b) convert all weights to bf16 once
__global__ __launch_bounds__(256) void k_wconv(const float* __restrict__ dpw,
                                               const float* __restrict__ duw,
                                               const float* __restrict__ scw,
                                               const float* __restrict__ w1,
                                               const float* __restrict__ w2,
                                               unsigned short* __restrict__ dpwh,
                                               unsigned short* __restrict__ duwh,
                                               unsigned short* __restrict__ scah,
                                               unsigned short* __restrict__ scbh,
                                               unsigned short* __restrict__ w1sh,
                                               unsigned short* __restrict__ w1bh,
                                               unsigned short* __restrict__ w2h) {
  int t = blockIdx.x * 256 + threadIdx.x;
  if (t < 65536) {
    int o = t >> 8, k = t & 255;
    float vb = w1[(size_t)o * 512 + 256 + k];
    w1sh[t] = f2bf(w1[(size_t)o * 512 + k] + vb);
    w1bh[t] = f2bf(vb);
    w2h[t] = f2bf(w2[t]);
  }
  if (t < 32768) { dpwh[t] = f2bf(dpw[t]); duwh[t] = f2bf(duw[t]); }
  if (t < 16384) {
    int o = t >> 7, c = t & 127;
    scah[t] = f2bf(scw[o * 256 + c]);
    scbh[t] = f2bf(scw[o * 256 + 128 + c]);
  }
}

// ---------------------------------------------------------------------------
// 1) per-(b,c) instance-norm stats over N
// ---------------------------------------------------------------------------
__global__ __launch_bounds__(256) void k_instat(const float* __restrict__ x,
                                                float* __restrict__ m_o,
                                                float* __restrict__ v_o,
                                                float* __restrict__ r_o) {
  const int row = blockIdx.x;  // b*C + c
  const float4* xr = reinterpret_cast<const float4*>(x + (size_t)row * N_);
  float s = 0.f, ss = 0.f;
  for (int i = threadIdx.x; i < N_ / 4; i += 256) {
    float4 v = xr[i];
    s += v.x + v.y + v.z + v.w;
    ss += v.x * v.x + v.y * v.y + v.z * v.z + v.w * v.w;
  }
  __shared__ float rs[256], rq[256];
  rs[threadIdx.x] = s; rq[threadIdx.x] = ss;
  __syncthreads();
  for (int st = 128; st > 0; st >>= 1) {
    if (threadIdx.x < st) { rs[threadIdx.x] += rs[threadIdx.x + st]; rq[threadIdx.x] += rq[threadIdx.x + st]; }
    __syncthreads();
  }
  if (threadIdx.x == 0) {
    float m = rs[0] / N_;
    float v = rq[0] / N_ - m * m;
    m_o[row] = m; v_o[row] = v; r_o[row] = rsqrtf(v + 1e-3f);
  }
}

// ---------------------------------------------------------------------------
// 2) fold IN+BN into per-(b,c) affine (BN mean of IN(x) is analytically 0)
// ---------------------------------------------------------------------------
__global__ void k_affine(const float* __restrict__ m_in, const float* __restrict__ v_in,
                         const float* __restrict__ r_in,
                         const float* __restrict__ dpg, const float* __restrict__ dpb,
                         const float* __restrict__ dug, const float* __restrict__ dub,
                         float* __restrict__ a_dp, float* __restrict__ d_dp,
                         float* __restrict__ a_du, float* __restrict__ d_du) {
  int c = threadIdx.x;  // 128 threads
  float V = 0.f;
  for (int b = 0; b < B_; b++) { float v = v_in[b * C_ + c]; V += v / (v + 1e-3f); }
  V *= (1.f / B_);
  float R = rsqrtf(V + 1e-5f);
  float gdp = dpg[c], bdp = dpb[c], gdu = dug[c], bdu = dub[c];
  for (int b = 0; b < B_; b++) {
    int i = b * C_ + c;
    float r = r_in[i], m = m_in[i];
    float sdp = r * R * gdp;
    a_dp[i] = sdp; d_dp[i] = -m * sdp + bdp;
    float sdu = r * R * gdu;
    a_du[i] = sdu; d_du[i] = -m * sdu + bdu;
  }
}

// ---------------------------------------------------------------------------
// 3) embed: out[k,n] = sum_c w[k,c]*relu(a*x+d) + bias (gload_lds + MFMA)
//    MODE 0: EB [b][k][n] ; MODE 1: EBT [b][n][k]
// ---------------------------------------------------------------------------
template <int MODE>
__global__ __launch_bounds__(256) void k_embed_g(const unsigned short* __restrict__ xh,
                                                 const unsigned short* __restrict__ wh,
                                                 const float* __restrict__ bias,
                                                 const float* __restrict__ aff_a,
                                                 const float* __restrict__ aff_d,
                                                 unsigned short* __restrict__ outp) {
  const int n0 = blockIdx.x * 128, k0 = blockIdx.y * 128, b = blockIdx.z;
  __shared__ __align__(16) unsigned short smem[2 * 128 * 128];
  unsigned short* tA = smem;              // [k][c] swizzled
  unsigned short* tB = smem + 128 * 128;  // [n][c] swizzled
  __shared__ float aff_as[128], aff_ds[128], bias_s[128];
  const int tid = threadIdx.x, lane = tid & 63, wid = tid >> 6;
  const int wr = wid >> 1, wc = wid & 1, l15 = lane & 15, l4 = lane >> 4;
  if (tid < 128) {
    aff_as[tid] = aff_a[b * C_ + tid];
    aff_ds[tid] = aff_d[b * C_ + tid];
    bias_s[tid] = bias[k0 + tid];
  }
#pragma unroll
  for (int i = 0; i < 8; i++) {
    int call = wid * 8 + i;
    int row = call * 4 + (lane >> 4);
    int gch = (lane & 15) ^ (row & 7);
    gload_lds16(wh + (size_t)(k0 + row) * C_ + gch * 8, tA + call * 512);
    gload_lds16(xh + (size_t)(b * N_ + n0 + row) * C_ + gch * 8, tB + call * 512);
  }
  __syncthreads();
  f32x4 acc[4][4] = {};
#pragma unroll
  for (int ks = 0; ks < 128; ks += 32) {
    const int ch = (ks >> 3) + l4;
    s16x8 af[4], bfv[4];
#pragma unroll
    for (int m = 0; m < 4; m++) {
      int row = wr * 64 + m * 16 + l15;
      af[m] = *reinterpret_cast<const s16x8*>(tA + row * 128 + ((ch ^ (row & 7)) << 3));
    }
#pragma unroll
    for (int n = 0; n < 4; n++) {
      int row = wc * 64 + n * 16 + l15;
      s16x8 raw = *reinterpret_cast<const s16x8*>(tB + row * 128 + ((ch ^ (row & 7)) << 3));
      s16x8 h;
#pragma unroll
      for (int j = 0; j < 8; j++) {
        int c = ks + 8 * l4 + j;
        h[j] = (short)f2bf(fmaxf(fmaf(aff_as[c], bf2f((unsigned short)raw[j]), aff_ds[c]), 0.f));
      }
      bfv[n] = h;
    }
#pragma unroll
    for (int m = 0; m < 4; m++)
#pragma unroll
      for (int n = 0; n < 4; n++)
        acc[m][n] = __builtin_amdgcn_mfma_f32_16x16x32_bf16(af[m], bfv[n], acc[m][n], 0, 0, 0);
  }
  __syncthreads();
  unsigned short (*e_s)[136] = reinterpret_cast<unsigned short(*)[136]>(smem);
#pragma unroll
  for (int m = 0; m < 4; m++)
#pragma unroll
    for (int n = 0; n < 4; n++) {
      int kl = wr * 64 + m * 16 + 4 * l4;
      int nl = wc * 64 + n * 16 + l15;
#pragma unroll
      for (int r = 0; r < 4; r++) {
        unsigned short v = f2bf(acc[m][n][r] + bias_s[kl + r]);
        if (MODE == 0) e_s[kl + r][nl] = v;
        else           e_s[nl][kl + r] = v;
      }
    }
  __syncthreads();
  if (MODE == 0) {
    for (int i = 0; i < 8; i++) {
      int q = tid + i * 256;
      int cg = q & 15, kk = q >> 4;
      u16x8 v = *reinterpret_cast<const u16x8*>(&e_s[kk][8 * cg]);
      *reinterpret_cast<u16x8*>(outp + (size_t)(b * K_ + k0 + kk) * N_ + n0 + 8 * cg) = v;
    }
  } else {
    for (int i = 0; i < 8; i++) {
      int q = tid + i * 256;
      int kg = q & 15, nn = q >> 4;
      u16x8 v = *reinterpret_cast<const u16x8*>(&e_s[nn][8 * kg]);
      *reinterpret_cast<u16x8*>(outp + (size_t)(b * N_ + n0 + nn) * K_ + k0 + 8 * kg) = v;
    }
  }
}

// ---------------------------------------------------------------------------
// 4) per-(b,k) row max + sum(exp) over N (bf16 input)
// ---------------------------------------------------------------------------
__global__ __launch_bounds__(256) void k_rowstat(const unsigned short* __restrict__ EB,
                                                 float* __restrict__ mx, float* __restrict__ rden) {
  const int row = blockIdx.x;
  float m = -1e30f, s = 0.f;
  for (int i = threadIdx.x; i < N_ / 8; i += 256) {
    u16x8 v = *reinterpret_cast<const u16x8*>(EB + (size_t)row * N_ + 8 * i);
    float f[8];
#pragma unroll
    for (int j = 0; j < 8; j++) f[j] = bf2f(v[j]);
    float lm = f[0];
#pragma unroll
    for (int j = 1; j < 8; j++) lm = fmaxf(lm, f[j]);
    if (lm > m) { s *= __expf(m - lm); m = lm; }
#pragma unroll
    for (int j = 0; j < 8; j++) s += __expf(f[j] - m);
  }
  __shared__ float rm[256], rsum[256];
  rm[threadIdx.x] = m; rsum[threadIdx.x] = s;
  __syncthreads();
  for (int st = 128; st > 0; st >>= 1) {
    if (threadIdx.x < st) {
      float m1 = rm[threadIdx.x], s1 = rsum[threadIdx.x];
      float m2 = rm[threadIdx.x + st], s2 = rsum[threadIdx.x + st];
      float M = fmaxf(m1, m2);
      rm[threadIdx.x] = M;
      rsum[threadIdx.x] = s1 * __expf(m1 - M) + s2 * __expf(m2 - M);
    }
    __syncthreads();
  }
  if (threadIdx.x == 0) { mx[row] = rm[0]; rden[row] = 1.f / rsum[0]; }
}

// ---------------------------------------------------------------------------
// 5) x_down partials: part[sp][b][c][k] = sum_{n in split} x[c,n]*exp(EB[k,n]-mx)
// ---------------------------------------------------------------------------
__global__ __launch_bounds__(256) void k_xdown_g(const unsigned short* __restrict__ xcn,
                                                 const unsigned short* __restrict__ EB,
                                                 const float* __restrict__ mx,
                                                 float* __restrict__ part) {
  const int k0 = blockIdx.x * 128, sp = blockIdx.y, b = blockIdx.z;
  const int nbase = sp * (N_ / NSP);
  __shared__ __align__(16) unsigned short smem[2 * 128 * 128];
  unsigned short* tA = smem;              // [c][n]
  unsigned short* tB = smem + 128 * 128;  // [k][n]
  __shared__ float mxs[128];
  const int tid = threadIdx.x, lane = tid & 63, wid = tid >> 6;
  const int wr = wid >> 1, wc = wid & 1, l15 = lane & 15, l4 = lane >> 4;
  if (tid < 128) mxs[tid] = mx[b * K_ + k0 + tid];
  f32x4 acc[4][4] = {};
  for (int nc = 0; nc < N_ / NSP; nc += 128) {
    const int n0 = nbase + nc;
#pragma unroll
    for (int i = 0; i < 8; i++) {
      int call = wid * 8 + i;
      int row = call * 4 + (lane >> 4);
      int gch = (lane & 15) ^ (row & 7);
      gload_lds16(xcn + (size_t)(b * C_ + row) * N_ + n0 + gch * 8, tA + call * 512);
      gload_lds16(EB + (size_t)(b * K_ + k0 + row) * N_ + n0 + gch * 8, tB + call * 512);
    }
    __syncthreads();
#pragma unroll
    for (int ks = 0; ks < 128; ks += 32) {
      const int ch = (ks >> 3) + l4;
      s16x8 af[4], bfv[4];
#pragma unroll
      for (int m = 0; m < 4; m++) {
        int row = wr * 64 + m * 16 + l15;
        af[m] = *reinterpret_cast<const s16x8*>(tA + row * 128 + ((ch ^ (row & 7)) << 3));
      }
#pragma unroll
      for (int n = 0; n < 4; n++) {
        int row = wc * 64 + n * 16 + l15;
        s16x8 raw = *reinterpret_cast<const s16x8*>(tB + row * 128 + ((ch ^ (row & 7)) << 3));
        float mv = mxs[row];
        s16x8 h;
#pragma unroll
        for (int j = 0; j < 8; j++)
          h[j] = (short)f2bf(__expf(bf2f((unsigned short)raw[j]) - mv));
        bfv[n] = h;
      }
#pragma unroll
      for (int m = 0; m < 4; m++)
#pragma unroll
        for (int n = 0; n < 4; n++)
          acc[m][n] = __builtin_amdgcn_mfma_f32_16x16x32_bf16(af[m], bfv[n], acc[m][n], 0, 0, 0);
    }
    __syncthreads();
  }
#pragma unroll
  for (int m = 0; m < 4; m++)
#pragma unroll
    for (int n = 0; n < 4; n++) {
      int c = wr * 64 + m * 16 + 4 * l4;
      int k = k0 + wc * 64 + n * 16 + l15;
#pragma unroll
      for (int r = 0; r < 4; r++)
        part[((size_t)(sp * B_ + b) * C_ + c + r) * K_ + k] = acc[m][n][r];
    }
}

// 6) reduce split partials, scale by 1/den -> xd fp32 [b][p][k] + xdh bf16
__global__ __launch_bounds__(256) void k_xdown_red(const float* __restrict__ part,
                                                   const float* __restrict__ rden,
                                                   float* __restrict__ xd,
                                                   unsigned short* __restrict__ xdh) {
  int e = blockIdx.x * 256 + threadIdx.x;  // B*C*K
  int k = e % K_;
  int b = e / (K_ * C_);
  float s = 0.f;
  for (int sp = 0; sp < NSP; sp++) s += part[(size_t)sp * (B_ * C_ * K_) + e];
  float v = s * rden[b * K_ + k];
  xd[e] = v;
  xdh[e] = f2bf(v);
}

// ---------------------------------------------------------------------------
// 7a) gram tiles: pd[b][p][q] = sum_k xd[b][p][k]*xd[b][q][k]
// ---------------------------------------------------------------------------
__global__ __launch_bounds__(256) void k_gram(const float* __restrict__ xd,
                                              float* __restrict__ pd) {
  const int p0 = blockIdx.x * 32, b = blockIdx.y;
  __shared__ float A[32][36];
  __shared__ float Bt[32][132];
  const int tid = threadIdx.x;
  const int tr = tid >> 5, tc = tid & 31;
  float acc[4][4] = {};
  for (int k0 = 0; k0 < K_; k0 += 32) {
    {
      int pp = tid >> 3, k4 = tid & 7;
      float4 v = *reinterpret_cast<const float4*>(xd + (size_t)(b * C_ + p0 + pp) * K_ + k0 + 4 * k4);
      A[4 * k4 + 0][pp] = v.x; A[4 * k4 + 1][pp] = v.y;
      A[4 * k4 + 2][pp] = v.z; A[4 * k4 + 3][pp] = v.w;
    }
    for (int i = 0; i < 4; i++) {
      int q = tid + i * 256;
      int qq = q >> 3, k4 = q & 7;
      float4 v = *reinterpret_cast<const float4*>(xd + (size_t)(b * C_ + qq) * K_ + k0 + 4 * k4);
      Bt[4 * k4 + 0][qq] = v.x; Bt[4 * k4 + 1][qq] = v.y;
      Bt[4 * k4 + 2][qq] = v.z; Bt[4 * k4 + 3][qq] = v.w;
    }
    __syncthreads();
    for (int kk = 0; kk < 32; ++kk) {
      float4 av = *reinterpret_cast<const float4*>(&A[kk][tr * 4]);
      float4 bv = *reinterpret_cast<const float4*>(&Bt[kk][tc * 4]);
      float a[4] = {av.x, av.y, av.z, av.w};
      float bb[4] = {bv.x, bv.y, bv.z, bv.w};
#pragma unroll
      for (int i = 0; i < 4; ++i)
#pragma unroll
        for (int j = 0; j < 4; ++j) acc[i][j] = fmaf(a[i], bb[j], acc[i][j]);
    }
    __syncthreads();
  }
#pragma unroll
  for (int i = 0; i < 4; ++i) {
    float4 r; r.x = acc[i][0]; r.y = acc[i][1]; r.z = acc[i][2]; r.w = acc[i][3];
    *reinterpret_cast<float4*>(pd + (size_t)(b * P_ + p0 + tr * 4 + i) * P_ + tc * 4) = r;
  }
}

// 7b) sq[b][p] = ||xd[b][p][:]||^2
__global__ __launch_bounds__(128) void k_sq(const float* __restrict__ xd,
                                            float* __restrict__ sq) {
  const int b = blockIdx.x, p = threadIdx.x;
  const float4* r = reinterpret_cast<const float4*>(xd + (size_t)(b * C_ + p) * K_);
  float s = 0.f;
  for (int i = 0; i < K_ / 4; i++) { float4 v = r[i]; s += v.x * v.x + v.y * v.y + v.z * v.z + v.w * v.w; }
  sq[b * P_ + p] = s;
}

// 7c) top-6 per point: one wave per point, 6 rounds of wave argmax
__global__ __launch_bounds__(256) void k_topk(const float* __restrict__ pd,
                                              const float* __restrict__ sq,
                                              int* __restrict__ idx) {
  const int wid = threadIdx.x >> 6, lane = threadIdx.x & 63;
  const int gp = blockIdx.x * 4 + wid;  // b*P + p
  const int b = gp >> 7;
  const float* row = pd + (size_t)gp * P_;
  float v0 = 2.f * row[lane] - sq[b * P_ + lane];
  float v1 = 2.f * row[lane + 64] - sq[b * P_ + lane + 64];
  int q0 = lane, q1 = lane + 64;
#pragma unroll
  for (int j = 0; j < NB_; j++) {
    float bv; int bq;
    if (v0 > v1 || (v0 == v1 && q0 < q1)) { bv = v0; bq = q0; } else { bv = v1; bq = q1; }
#pragma unroll
    for (int o = 32; o > 0; o >>= 1) {
      float ov = __shfl_xor(bv, o); int oq = __shfl_xor(bq, o);
      if (ov > bv || (ov == bv && oq < bq)) { bv = ov; bq = oq; }
    }
    if (lane == 0) idx[gp * NB_ + j] = bq;
    if (q0 == bq) v0 = -3.0e38f;
    if (q1 == bq) v1 = -3.0e38f;
  }
}

// ---------------------------------------------------------------------------
// 8) UV via MFMA: Ut/Vt[b][p][o] = sum_k W1{sum|b}[o][k] * xdh[b][p][k]
// ---------------------------------------------------------------------------
__global__ __launch_bounds__(256) void k_uv_mfma(const unsigned short* __restrict__ xdh,
                                                 const unsigned short* __restrict__ w1sh,
                                                 const unsigned short* __restrict__ w1bh,
                                                 float* __restrict__ Ut, float* __restrict__ Vt) {
  const int o0 = blockIdx.x * 128, which = blockIdx.y, b = blockIdx.z;
  __shared__ __align__(16) unsigned char smemraw[128 * 132 * 4];
  unsigned short* tA = (unsigned short*)smemraw;
  unsigned short* tB = tA + 128 * 128;
  const unsigned short* wsel = which ? w1bh : w1sh;
  const int tid = threadIdx.x, lane = tid & 63, wid = tid >> 6;
  const int wr = wid >> 1, wc = wid & 1, l15 = lane & 15, l4 = lane >> 4;
  f32x4 acc[4][4] = {};
  for (int kh = 0; kh < 256; kh += 128) {
#pragma unroll
    for (int i = 0; i < 8; i++) {
      int call = wid * 8 + i;
      int row = call * 4 + (lane >> 4);
      int gch = (lane & 15) ^ (row & 7);
      gload_lds16(wsel + (size_t)(o0 + row) * 256 + kh + gch * 8, tA + call * 512);
      gload_lds16(xdh + (size_t)(b * P_ + row) * 256 + kh + gch * 8, tB + call * 512);
    }
    __syncthreads();
#pragma unroll
    for (int ks = 0; ks < 128; ks += 32) {
      const int ch = (ks >> 3) + l4;
      s16x8 af[4], bfv[4];
#pragma unroll
      for (int m = 0; m < 4; m++) {
        int row = wr * 64 + m * 16 + l15;
        af[m] = *reinterpret_cast<const s16x8*>(tA + row * 128 + ((ch ^ (row & 7)) << 3));
      }
#pragma unroll
      for (int n = 0; n < 4; n++) {
        int row = wc * 64 + n * 16 + l15;
        bfv[n] = *reinterpret_cast<const s16x8*>(tB + row * 128 + ((ch ^ (row & 7)) << 3));
      }
#pragma unroll
      for (int m = 0; m < 4; m++)
#pragma unroll
        for (int n = 0; n < 4; n++)
          acc[m][n] = __builtin_amdgcn_mfma_f32_16x16x32_bf16(af[m], bfv[n], acc[m][n], 0, 0, 0);
    }
    __syncthreads();
  }
  // transpose epilogue in fp32 LDS -> Ut/Vt[b][p][o] linear rows
  float (*ef)[132] = (float(*)[132])smemraw;
#pragma unroll
  for (int m = 0; m < 4; m++)
#pragma unroll
    for (int n = 0; n < 4; n++) {
      int ol = wr * 64 + m * 16 + 4 * l4;
      int pl = wc * 64 + n * 16 + l15;
#pragma unroll
      for (int r = 0; r < 4; r++) ef[pl][ol + r] = acc[m][n][r];
    }
  __syncthreads();
  float* outp = which ? Vt : Ut;
  for (int i = 0; i < 16; i++) {
    int q = tid + i * 256;
    int pl = q >> 5, c4 = q & 31;
    float4 v = *reinterpret_cast<const float4*>(&ef[pl][c4 * 4]);
    *reinterpret_cast<float4*>(outp + (size_t)(b * P_ + pl) * 256 + o0 + c4 * 4) = v;
  }
}

// 9) g1h[b*768+pj][o] = Ut[b][p][o] + b1[o] - Vt[b][q][o]   (bf16, coalesced)
__global__ __launch_bounds__(256) void k_edge_t(const float* __restrict__ Ut,
                                                const float* __restrict__ Vt,
                                                const int* __restrict__ idx,
                                                const float* __restrict__ b1,
                                                unsigned short* __restrict__ g1h) {
  __shared__ float b1s[256];
  const int tid = threadIdx.x;
  b1s[tid] = b1[tid];
  __syncthreads();
  const int row0 = blockIdx.x * 16;
  for (int r = 0; r < 16; r++) {
    int row = row0 + r;  // b*768 + p*6 + j
    int b = row / 768, pj = row % 768, p = pj / 6;
    int q = idx[(b * P_ + p) * NB_ + (pj % 6)];
    float v = Ut[(size_t)(b * P_ + p) * 256 + tid] + b1s[tid]
            - Vt[(size_t)(b * P_ + q) * 256 + tid];
    g1h[(size_t)row * 256 + tid] = f2bf(v);
  }
}

// 10) BN stats over rows of gt [12288][256]: per-block partial sums
__global__ __launch_bounds__(256) void k_bnstat_t(const unsigned short* __restrict__ gt,
                                                  float* __restrict__ partS,
                                                  float* __restrict__ partQ) {
  const int tid = threadIdx.x;
  const size_t row0 = (size_t)blockIdx.x * 256;
  float s = 0.f, ss = 0.f;
  for (int r = 0; r < 256; r++) {
    float v = bf2f(gt[(row0 + r) * 256 + tid]);
    s += v; ss += v * v;
  }
  partS[blockIdx.x * 256 + tid] = s;
  partQ[blockIdx.x * 256 + tid] = ss;
}

// 10b) finalize BN scale/shift
__global__ __launch_bounds__(256) void k_bnfin(const float* __restrict__ partS,
                                               const float* __restrict__ partQ,
                                               const float* __restrict__ gamma,
                                               const float* __restrict__ beta,
                                               float* __restrict__ sc, float* __restrict__ sh) {
  int o = threadIdx.x;
  float s = 0.f, q = 0.f;
  for (int i = 0; i < 48; i++) { s += partS[i * 256 + o]; q += partQ[i * 256 + o]; }
  const float cnt = (float)(B_ * P_ * NB_);
  float m = s / cnt, var = q / cnt - m * m;
  float scale = gamma[o] * rsqrtf(var + 1e-5f);
  sc[o] = scale; sh[o] = -m * scale + beta[o];
}

// 11) conv2 via MFMA: g2h[n][o] = sum_c w2[o][c]*relu(bn1(g1h[n][c])) + b2
__global__ __launch_bounds__(256) void k_conv2_mfma(const unsigned short* __restrict__ g1h,
                                                    const unsigned short* __restrict__ w2h,
                                                    const float* __restrict__ b2,
                                                    const float* __restrict__ bn1sc,
                                                    const float* __restrict__ bn1sh,
                                                    unsigned short* __restrict__ g2h) {
  const int n0 = blockIdx.x * 128, o0 = blockIdx.y * 128, b = blockIdx.z;
  __shared__ __align__(16) unsigned short smem[2 * 128 * 128];
  unsigned short* tA = smem;
  unsigned short* tB = smem + 128 * 128;
  __shared__ float scs[256], shs[256], b2s[128];
  const int tid = threadIdx.x, lane = tid & 63, wid = tid >> 6;
  const int wr = wid >> 1, wc = wid & 1, l15 = lane & 15, l4 = lane >> 4;
  scs[tid] = bn1sc[tid]; shs[tid] = bn1sh[tid];
  if (tid < 128) b2s[tid] = b2[o0 + tid];
  f32x4 acc[4][4] = {};
  for (int kh = 0; kh < 256; kh += 128) {
#pragma unroll
    for (int i = 0; i < 8; i++) {
      int call = wid * 8 + i;
      int row = call * 4 + (lane >> 4);
      int gch = (lane & 15) ^ (row & 7);
      gload_lds16(w2h + (size_t)(o0 + row) * 256 + kh + gch * 8, tA + call * 512);
      gload_lds16(g1h + (size_t)(b * 768 + n0 + row) * 256 + kh + gch * 8, tB + call * 512);
    }
    __syncthreads();
#pragma unroll
    for (int ks = 0; ks < 128; ks += 32) {
      const int ch = (ks >> 3) + l4;
      s16x8 af[4], bfv[4];
#pragma unroll
      for (int m = 0; m < 4; m++) {
        int row = wr * 64 + m * 16 + l15;
        af[m] = *reinterpret_cast<const s16x8*>(tA + row * 128 + ((ch ^ (row & 7)) << 3));
      }
#pragma unroll
      for (int n = 0; n < 4; n++) {
        int row = wc * 64 + n * 16 + l15;
        s16x8 raw = *reinterpret_cast<const s16x8*>(tB + row * 128 + ((ch ^ (row & 7)) << 3));
        s16x8 h;
#pragma unroll
        for (int j = 0; j < 8; j++) {
          int c = kh + ks + 8 * l4 + j;
          h[j] = (short)f2bf(fmaxf(fmaf(scs[c], bf2f((unsigned short)raw[j]), shs[c]), 0.f));
        }
        bfv[n] = h;
      }
#pragma unroll
      for (int m = 0; m < 4; m++)
#pragma unroll
        for (int n = 0; n < 4; n++)
          acc[m][n] = __builtin_amdgcn_mfma_f32_16x16x32_bf16(af[m], bfv[n], acc[m][n], 0, 0, 0);
    }
    __syncthreads();
  }
  unsigned short (*e_s)[136] = reinterpret_cast<unsigned short(*)[136]>(smem);
#pragma unroll
  for (int m = 0; m < 4; m++)
#pragma unroll
    for (int n = 0; n < 4; n++) {
      int ol = wr * 64 + m * 16 + 4 * l4;
      int nl = wc * 64 + n * 16 + l15;
#pragma unroll
      for (int r = 0; r < 4; r++)
        e_s[nl][ol + r] = f2bf(acc[m][n][r] + b2s[ol + r]);
    }
  __syncthreads();
  for (int i = 0; i < 8; i++) {
    int q = tid + i * 256;
    int og = q & 15, nl = q >> 4;
    u16x8 v = *reinterpret_cast<const u16x8*>(&e_s[nl][8 * og]);
    *reinterpret_cast<u16x8*>(g2h + (size_t)(b * 768 + n0 + nl) * 256 + o0 + 8 * og) = v;
  }
}

// 13) gmaxh[b][k][p] = max_j relu(bn2(g2h[b*768+p*6+j][k]))  (bf16)
__global__ __launch_bounds__(256) void k_gmax_t(const unsigned short* __restrict__ g2h,
                                                const float* __restrict__ bn2sc,
                                                const float* __restrict__ bn2sh,
                                                unsigned short* __restrict__ gmaxh) {
  const int o0 = blockIdx.x * 128, b = blockIdx.y;
  const int ol = threadIdx.x & 127, ph = threadIdx.x >> 7;
  const int o = o0 + ol;
  const float sc = bn2sc[o], sh = bn2sh[o];
  for (int p8 = ph * 64; p8 < ph * 64 + 64; p8 += 8) {
    u16x8 pack;
#pragma unroll
    for (int pi = 0; pi < 8; pi++) {
      int p = p8 + pi;
      float m = 0.f;
#pragma unroll
      for (int j = 0; j < NB_; j++) {
        float v = bf2f(g2h[(size_t)(b * 768 + p * 6 + j) * 256 + o]);
        m = fmaxf(m, fmaf(sc, v, sh));
      }
      pack[pi] = f2bf(m);
    }
    *reinterpret_cast<u16x8*>(gmaxh + (size_t)(b * 256 + o) * P_ + p8) = pack;
  }
}

// 14) M2h[b][o2][k] = sum_c scwB[o2][c] * gmaxh[b][k][c]  (MFMA)
__global__ __launch_bounds__(256) void k_m2_mfma(const unsigned short* __restrict__ gmaxh,
                                                 const unsigned short* __restrict__ scbh,
                                                 unsigned short* __restrict__ M2h) {
  const int k0 = blockIdx.x * 128, b = blockIdx.y;
  __shared__ __align__(16) unsigned short smem[2 * 128 * 128];
  unsigned short* tA = smem;
  unsigned short* tB = smem + 128 * 128;
  const int tid = threadIdx.x, lane = tid & 63, wid = tid >> 6;
  const int wr = wid >> 1, wc = wid & 1, l15 = lane & 15, l4 = lane >> 4;
#pragma unroll
  for (int i = 0; i < 8; i++) {
    int call = wid * 8 + i;
    int row = call * 4 + (lane >> 4);
    int gch = (lane & 15) ^ (row & 7);
    gload_lds16(scbh + (size_t)row * P_ + gch * 8, tA + call * 512);
    gload_lds16(gmaxh + (size_t)(b * 256 + k0 + row) * P_ + gch * 8, tB + call * 512);
  }
  __syncthreads();
  f32x4 acc[4][4] = {};
#pragma unroll
  for (int ks = 0; ks < 128; ks += 32) {
    const int ch = (ks >> 3) + l4;
    s16x8 af[4], bfv[4];
#pragma unroll
    for (int m = 0; m < 4; m++) {
      int row = wr * 64 + m * 16 + l15;
      af[m] = *reinterpret_cast<const s16x8*>(tA + row * 128 + ((ch ^ (row & 7)) << 3));
    }
#pragma unroll
    for (int n = 0; n < 4; n++) {
      int row = wc * 64 + n * 16 + l15;
      bfv[n] = *reinterpret_cast<const s16x8*>(tB + row * 128 + ((ch ^ (row & 7)) << 3));
    }
#pragma unroll
    for (int m = 0; m < 4; m++)
#pragma unroll
      for (int n = 0; n < 4; n++)
        acc[m][n] = __builtin_amdgcn_mfma_f32_16x16x32_bf16(af[m], bfv[n], acc[m][n], 0, 0, 0);
  }
  __syncthreads();
  unsigned short (*e_s)[136] = reinterpret_cast<unsigned short(*)[136]>(smem);
#pragma unroll
  for (int m = 0; m < 4; m++)
#pragma unroll
    for (int n = 0; n < 4; n++) {
      int ol = wr * 64 + m * 16 + 4 * l4;
      int kl = wc * 64 + n * 16 + l15;
#pragma unroll
      for (int r = 0; r < 4; r++)
        e_s[ol + r][kl] = f2bf(acc[m][n][r]);
    }
  __syncthreads();
  for (int i = 0; i < 8; i++) {
    int q = tid + i * 256;
    int kg = q & 15, oo = q >> 4;
    u16x8 v = *reinterpret_cast<const u16x8*>(&e_s[oo][8 * kg]);
    *reinterpret_cast<u16x8*>(M2h + (size_t)(b * C_ + oo) * K_ + k0 + 8 * kg) = v;
  }
}

// ---------------------------------------------------------------------------
// 15) per-(b,n) softmax-over-k stats from EBT[b][n][k] bf16
// ---------------------------------------------------------------------------
__global__ __launch_bounds__(256) void k_colstat(const unsigned short* __restrict__ EBT,
                                                 float* __restrict__ mx2, float* __restrict__ rs2) {
  const int wid = threadIdx.x >> 6, lane = threadIdx.x & 63;
  const int bn = blockIdx.x * 4 + wid;  // b*N + n
  u16x4 v = *reinterpret_cast<const u16x4*>(EBT + (size_t)bn * K_ + 4 * lane);
  float f0 = bf2f(v[0]), f1 = bf2f(v[1]), f2 = bf2f(v[2]), f3 = bf2f(v[3]);
  float m = fmaxf(fmaxf(f0, f1), fmaxf(f2, f3));
  for (int o = 32; o > 0; o >>= 1) m = fmaxf(m, __shfl_xor(m, o));
  float s = __expf(f0 - m) + __expf(f1 - m) + __expf(f2 - m) + __expf(f3 - m);
  for (int o = 32; o > 0; o >>= 1) s += __shfl_xor(s, o);
  if (lane == 0) { mx2[bn] = m; rs2[bn] = 1.f / s; }
}

// ---------------------------------------------------------------------------
// 16) out[o,n] = scwA@x + M2@softmax_k(EBT) + scb  (gload_lds staging)
// ---------------------------------------------------------------------------
__global__ __launch_bounds__(256) void k_final_g(const unsigned short* __restrict__ EBT,
                                                 const unsigned short* __restrict__ xh,
                                                 const unsigned short* __restrict__ M2h,
                                                 const unsigned short* __restrict__ scah,
                                                 const float* __restrict__ scb,
                                                 const float* __restrict__ mx2,
                                                 const float* __restrict__ rs2,
                                                 float* __restrict__ out) {
  const int n0 = blockIdx.x * 128, b = blockIdx.y;
  __shared__ __align__(16) unsigned short smem[2 * 128 * 128];
  unsigned short* tA = smem;
  unsigned short* tB = smem + 128 * 128;
  __shared__ float mx2s[128], rs2s[128], scb_s[128];
  const int tid = threadIdx.x, lane = tid & 63, wid = tid >> 6;
  const int wr = wid >> 1, wc = wid & 1, l15 = lane & 15, l4 = lane >> 4;
  if (tid < 128) {
    mx2s[tid] = mx2[b * N_ + n0 + tid];
    rs2s[tid] = rs2[b * N_ + n0 + tid];
    scb_s[tid] = scb[tid];
  }
  f32x4 acc[4][4] = {};
  // ---- phase A: contraction over c (scwA @ x) ----
#pragma unroll
  for (int i = 0; i < 8; i++) {
    int call = wid * 8 + i;
    int row = call * 4 + (lane >> 4);
    int gch = (lane & 15) ^ (row & 7);
    gload_lds16(scah + (size_t)row * C_ + gch * 8, tA + call * 512);
    gload_lds16(xh + (size_t)(b * N_ + n0 + row) * C_ + gch * 8, tB + call * 512);
  }
  __syncthreads();
#pragma unroll
  for (int ks = 0; ks < 128; ks += 32) {
    const int ch = (ks >> 3) + l4;
    s16x8 af[4], bfv[4];
#pragma unroll
    for (int m = 0; m < 4; m++) {
      int row = wr * 64 + m * 16 + l15;
      af[m] = *reinterpret_cast<const s16x8*>(tA + row * 128 + ((ch ^ (row & 7)) << 3));
    }
#pragma unroll
    for (int n = 0; n < 4; n++) {
      int row = wc * 64 + n * 16 + l15;
      bfv[n] = *reinterpret_cast<const s16x8*>(tB + row * 128 + ((ch ^ (row & 7)) << 3));
    }
#pragma unroll
    for (int m = 0; m < 4; m++)
#pragma unroll
      for (int n = 0; n < 4; n++)
        acc[m][n] = __builtin_amdgcn_mfma_f32_16x16x32_bf16(af[m], bfv[n], acc[m][n], 0, 0, 0);
  }
  __syncthreads();
  // ---- phase B: contraction over k (M2 @ softmax), two 128-halves ----
  for (int kh = 0; kh < K_; kh += 128) {
#pragma unroll
    for (int i = 0; i < 8; i++) {
      int call = wid * 8 + i;
      int row = call * 4 + (lane >> 4);
      int gch = (lane & 15) ^ (row & 7);
      gload_lds16(M2h + (size_t)(b * C_ + row) * K_ + kh + gch * 8, tA + call * 512);
      gload_lds16(EBT + (size_t)(b * N_ + n0 + row) * K_ + kh + gch * 8, tB + call * 512);
    }
    __syncthreads();
#pragma unroll
    for (int ks = 0; ks < 128; ks += 32) {
      const int ch = (ks >> 3) + l4;
      s16x8 af[4], bfv[4];
#pragma unroll
      for (int m = 0; m < 4; m++) {
        int row = wr * 64 + m * 16 + l15;
        af[m] = *reinterpret_cast<const s16x8*>(tA + row * 128 + ((ch ^ (row & 7)) << 3));
      }
#pragma unroll
      for (int n = 0; n < 4; n++) {
        int row = wc * 64 + n * 16 + l15;
        s16x8 raw = *reinterpret_cast<const s16x8*>(tB + row * 128 + ((ch ^ (row & 7)) << 3));
        float mv = mx2s[row], rv = rs2s[row];
        s16x8 h;
#pragma unroll
        for (int j = 0; j < 8; j++)
          h[j] = (short)f2bf(__expf(bf2f((unsigned short)raw[j]) - mv) * rv);
        bfv[n] = h;
      }
#pragma unroll
      for (int m = 0; m < 4; m++)
#pragma unroll
        for (int n = 0; n < 4; n++)
          acc[m][n] = __builtin_amdgcn_mfma_f32_16x16x32_bf16(af[m], bfv[n], acc[m][n], 0, 0, 0);
    }
    __syncthreads();
  }
#pragma unroll
  for (int m = 0; m < 4; m++)
#pragma unroll
    for (int n = 0; n < 4; n++) {
      int o = wr * 64 + m * 16 + 4 * l4;
      int nn = n0 + wc * 64 + n * 16 + l15;
#pragma unroll
      for (int r = 0; r < 4; r++)
        out[(size_t)(b * C_ + o + r) * N_ + nn] = acc[m][n][r] + scb_s[o + r];
    }
}

// ---------------------------------------------------------------------------
extern "C" void kernel_launch(void* const* d_in, const int* in_sizes, int n_in,
                              void* d_out, int out_size, void* d_ws, size_t ws_size,
                              hipStream_t stream) {
  (void)in_sizes; (void)n_in; (void)out_size; (void)ws_size;
  const float* x      = (const float*)d_in[0];
  const float* dpg    = (const float*)d_in[1];
  const float* dpb    = (const float*)d_in[2];
  const float* dpw    = (const float*)d_in[3];
  const float* dpbias = (const float*)d_in[4];
  const float* dug    = (const float*)d_in[5];
  const float* dub    = (const float*)d_in[6];
  const float* duw    = (const float*)d_in[7];
  const float* dubias = (const float*)d_in[8];
  const float* w1     = (const float*)d_in[9];
  const float* b1     = (const float*)d_in[10];
  const float* g1g    = (const float*)d_in[11];
  const float* g1b    = (const float*)d_in[12];
  const float* w2     = (const float*)d_in[13];
  const float* b2     = (const float*)d_in[14];
  const float* g2g    = (const float*)d_in[15];
  const float* g2b    = (const float*)d_in[16];
  const float* scw    = (const float*)d_in[17];
  const float* scb    = (const float*)d_in[18];
  float* out = (float*)d_out;
  float* ws  = (float*)d_ws;

  // workspace layout (float-slot units unless noted)
  unsigned short* EB  = (unsigned short*)ws;               // B*K*N bf16
  unsigned short* xh  = (unsigned short*)(ws + 16777216);  // B*N*C bf16
  unsigned short* xcn = (unsigned short*)(ws + 25165824);  // B*C*N bf16
  float* base  = ws + 33554432;
  float* m_in  = base;               // 2048
  float* v_in  = m_in + 2048;
  float* r_in  = v_in + 2048;
  float* a_dp  = r_in + 2048;
  float* d_dp  = a_dp + 2048;
  float* a_du  = d_dp + 2048;
  float* d_du  = a_du + 2048;
  float* mx    = d_du + 2048;        // 4096
  float* rden  = mx + 4096;          // 4096
  float* mx2   = rden + 4096;        // 131072
  float* rs2   = mx2 + 131072;       // 131072
  float* xd    = rs2 + 131072;       // 524288 fp32 [b][p][k]
  float* Ut    = xd + 524288;        // 524288
  float* Vt    = Ut + 524288;        // 524288
  int*   idxb  = (int*)(Vt + 524288);  // 12288
  float* bn1sc = (float*)(idxb + 12288);
  float* bn1sh = bn1sc + 256;
  float* bn2sc = bn1sh + 256;
  float* bn2sh = bn2sc + 256;
  float* sq    = bn2sh + 256;        // 2048
  float* pd    = sq + 2048;          // 262144
  float* partS = pd + 262144;        // 12288
  float* partQ = partS + 12288;      // 12288
  unsigned short* xdh  = (unsigned short*)(partQ + 12288);  // 524288 shorts
  unsigned short* dpwh = xdh + 524288;     // 32768
  unsigned short* duwh = dpwh + 32768;     // 32768
  unsigned short* scah = duwh + 32768;     // 16384
  unsigned short* scbh = scah + 16384;     // 16384
  unsigned short* w1sh = scbh + 16384;     // 65536
  unsigned short* w1bh = w1sh + 65536;     // 65536
  unsigned short* w2h  = w1bh + 65536;     // 65536
  unsigned short* M2h  = w2h + 65536;      // 524288 shorts
  float* part = (float*)(M2h + 524288);    // NSP*B*C*K = 8,388,608 fp32
  // post-xdown aliases inside the dead `part` region:
  unsigned short* g1h   = (unsigned short*)part;  // 3,145,728 shorts
  unsigned short* g2h   = g1h + 3145728;          // 3,145,728 shorts
  unsigned short* gmaxh = g2h + 3145728;          // 524,288 shorts

  k_prep<<<dim3(128, 16), 256, 0, stream>>>(x, xh, xcn);
  k_wconv<<<dim3(256), 256, 0, stream>>>(dpw, duw, scw, w1, w2,
                                         dpwh, duwh, scah, scbh, w1sh, w1bh, w2h);
  k_instat<<<dim3(B_ * C_), 256, 0, stream>>>(x, m_in, v_in, r_in);
  k_affine<<<1, 128, 0, stream>>>(m_in, v_in, r_in, dpg, dpb, dug, dub, a_dp, d_dp, a_du, d_du);
  k_embed_g<0><<<dim3(64, 2, 16), 256, 0, stream>>>(xh, dpwh, dpbias, a_dp, d_dp, EB);
  k_rowstat<<<dim3(B_ * K_), 256, 0, stream>>>(EB, mx, rden);
  k_xdown_g<<<dim3(2, NSP, 16), 256, 0, stream>>>(xcn, EB, mx, part);
  k_xdown_red<<<dim3(2048), 256, 0, stream>>>(part, rden, xd, xdh);
  k_gram<<<dim3(4, 16), 256, 0, stream>>>(xd, pd);
  k_sq<<<dim3(16), 128, 0, stream>>>(xd, sq);
  k_topk<<<dim3(512), 256, 0, stream>>>(pd, sq, idxb);
  k_uv_mfma<<<dim3(2, 2, 16), 256, 0, stream>>>(xdh, w1sh, w1bh, Ut, Vt);
  k_edge_t<<<dim3(768), 256, 0, stream>>>(Ut, Vt, idxb, b1, g1h);
  k_bnstat_t<<<dim3(48), 256, 0, stream>>>(g1h, partS, partQ);
  k_bnfin<<<dim3(1), 256, 0, stream>>>(partS, partQ, g1g, g1b, bn1sc, bn1sh);
  k_conv2_mfma<<<dim3(6, 2, 16), 256, 0, stream>>>(g1h, w2h, b2, bn1sc, bn1sh, g2h);
  k_bnstat_t<<<dim3(48), 256, 0, stream>>>(g2h, partS, partQ);
  k_bnfin<<<dim3(1), 256, 0, stream>>>(partS, partQ, g2g, g2b, bn2sc, bn2sh);
  k_gmax_t<<<dim3(2, 16), 256, 0, stream>>>(g2h, bn2sc, bn2sh, gmaxh);
  k_m2_mfma<<<dim3(2, 16), 256, 0, stream>>>(gmaxh, scbh, M2h);
  k_embed_g<1><<<dim3(64, 2, 16), 256, 0, stream>>>(xh, duwh, dubias, a_du, d_du, EB);
  k_colstat<<<dim3(B_ * N_ / 4), 256, 0, stream>>>(EB, mx2, rs2);
  k_final_g<<<dim3(64, 16), 256, 0, stream>>>(EB, xh, M2h, scah, scb, mx2, rs2, out);
}

// Round 6
// 271.971 us; speedup vs baseline: 3.8530x; 1.1364x over previous
//
#include <hip/hip_runtime.h>

typedef __attribute__((ext_vector_type(4))) float f32x4;
typedef __attribute__((ext_vector_type(8))) short s16x8;
typedef __attribute__((ext_vector_type(8))) unsigned short u16x8;
typedef __attribute__((ext_vector_type(4))) unsigned short u16x4;

namespace {
constexpr int B_ = 16, C_ = 128, N_ = 8192, K_ = 256, P_ = 128, NB_ = 6;
constexpr int NSP = 16;  // xdown n-splits
}

__device__ __forceinline__ float bf2f(unsigned short h) {
  return __uint_as_float(((unsigned int)h) << 16);
}
__device__ __forceinline__ unsigned short f2bf(float f) {
  unsigned int u = __float_as_uint(f);
  return (unsigned short)((u + 0x7fffu + ((u >> 16) & 1u)) >> 16);
}
// async global->LDS, 16B per lane, lane l writes lds_base + l*16
__device__ __forceinline__ void gload_lds16(const void* gsrc, void* ldsdst) {
  __builtin_amdgcn_global_load_lds(
      (const __attribute__((address_space(1))) void*)gsrc,
      (__attribute__((address_space(3))) void*)ldsdst, 16, 0, 0);
}

// ---------------------------------------------------------------------------
// 0) prep: xh[b][n][c] bf16 + xcn[b][c][n] bf16 + per-(chunk,b,c) IN partials
// ---------------------------------------------------------------------------
__global__ __launch_bounds__(256) void k_prep(const float* __restrict__ x,
                                              unsigned short* __restrict__ xh,
                                              unsigned short* __restrict__ xcn,
                                              float* __restrict__ pstS,
                                              float* __restrict__ pstQ) {
  const int chunk = blockIdx.x, b = blockIdx.y;
  const int n0 = chunk * 64;
  __shared__ float ts[64][132];
  __shared__ float rs_[2][128], rq_[2][128];
  const int tid = threadIdx.x;
  for (int i = 0; i < 8; i++) {
    int q = tid + i * 256;
    int n4 = q & 15, c = q >> 4;
    float4 v = *reinterpret_cast<const float4*>(x + (size_t)(b * C_ + c) * N_ + n0 + 4 * n4);
    ts[4 * n4 + 0][c] = v.x; ts[4 * n4 + 1][c] = v.y;
    ts[4 * n4 + 2][c] = v.z; ts[4 * n4 + 3][c] = v.w;
    u16x4 p; p[0] = f2bf(v.x); p[1] = f2bf(v.y); p[2] = f2bf(v.z); p[3] = f2bf(v.w);
    *reinterpret_cast<u16x4*>(xcn + (size_t)(b * C_ + c) * N_ + n0 + 4 * n4) = p;
  }
  __syncthreads();
  for (int i = 0; i < 4; i++) {
    int q = tid + i * 256;
    int cg = q & 15, nn = q >> 4;
    u16x8 o;
#pragma unroll
    for (int j = 0; j < 8; j++) o[j] = f2bf(ts[nn][8 * cg + j]);
    *reinterpret_cast<u16x8*>(xh + (size_t)(b * N_ + n0 + nn) * C_ + 8 * cg) = o;
  }
  // instance-norm partial stats: per c, sum over the 64 n of this chunk
  {
    int c = tid & 127, h = tid >> 7;
    float s = 0.f, ss = 0.f;
    for (int nn = h * 32; nn < h * 32 + 32; nn++) { float v = ts[nn][c]; s += v; ss += v * v; }
    rs_[h][c] = s; rq_[h][c] = ss;
  }
  __syncthreads();
  if (tid < 128) {
    pstS[(chunk * 16 + b) * 128 + tid] = rs_[0][tid] + rs_[1][tid];
    pstQ[(chunk * 16 + b) * 128 + tid] = rq_[0][tid] + rq_[1][tid];
  }
}

// 0c) finalize instance-norm stats per (b,c)
__global__ __launch_bounds__(256) void k_instat_fin(const float* __restrict__ pstS,
                                                    const float* __restrict__ pstQ,
                                                    float* __restrict__ m_o,
                                                    float* __restrict__ v_o,
                                                    float* __restrict__ r_o) {
  int e = blockIdx.x * 256 + threadIdx.x;  // b*128+c (2048)
  int b = e >> 7, c = e & 127;
  float s = 0.f, q = 0.f;
  for (int ch = 0; ch < 128; ch++) {
    s += pstS[(ch * 16 + b) * 128 + c];
    q += pstQ[(ch * 16 + b) * 128 + c];
  }
  float m = s / N_;
  float v = q / N_ - m * m;
  m_o[e] = m; v_o[e] = v; r_o[e] = rsqrtf(v + 1e-3f);
}

// 0b) convert all weights to bf16 once
__global__ __launch_bounds__(256) void k_wconv(const float* __restrict__ dpw,
                                               const float* __restrict__ duw,
                                               const float* __restrict__ scw,
                                               const float* __restrict__ w1,
                                               const float* __restrict__ w2,
                                               unsigned short* __restrict__ dpwh,
                                               unsigned short* __restrict__ duwh,
                                               unsigned short* __restrict__ scah,
                                               unsigned short* __restrict__ scbh,
                                               unsigned short* __restrict__ w1sh,
                                               unsigned short* __restrict__ w1bh,
                                               unsigned short* __restrict__ w2h) {
  int t = blockIdx.x * 256 + threadIdx.x;
  if (t < 65536) {
    int o = t >> 8, k = t & 255;
    float vb = w1[(size_t)o * 512 + 256 + k];
    w1sh[t] = f2bf(w1[(size_t)o * 512 + k] + vb);
    w1bh[t] = f2bf(vb);
    w2h[t] = f2bf(w2[t]);
  }
  if (t < 32768) { dpwh[t] = f2bf(dpw[t]); duwh[t] = f2bf(duw[t]); }
  if (t < 16384) {
    int o = t >> 7, c = t & 127;
    scah[t] = f2bf(scw[o * 256 + c]);
    scbh[t] = f2bf(scw[o * 256 + 128 + c]);
  }
}

// ---------------------------------------------------------------------------
// 2) fold IN+BN into per-(b,c) affine (BN mean of IN(x) is analytically 0)
// ---------------------------------------------------------------------------
__global__ void k_affine(const float* __restrict__ m_in, const float* __restrict__ v_in,
                         const float* __restrict__ r_in,
                         const float* __restrict__ dpg, const float* __restrict__ dpb,
                         const float* __restrict__ dug, const float* __restrict__ dub,
                         float* __restrict__ a_dp, float* __restrict__ d_dp,
                         float* __restrict__ a_du, float* __restrict__ d_du) {
  int c = threadIdx.x;  // 128 threads
  float V = 0.f;
  for (int b = 0; b < B_; b++) { float v = v_in[b * C_ + c]; V += v / (v + 1e-3f); }
  V *= (1.f / B_);
  float R = rsqrtf(V + 1e-5f);
  float gdp = dpg[c], bdp = dpb[c], gdu = dug[c], bdu = dub[c];
  for (int b = 0; b < B_; b++) {
    int i = b * C_ + c;
    float r = r_in[i], m = m_in[i];
    float sdp = r * R * gdp;
    a_dp[i] = sdp; d_dp[i] = -m * sdp + bdp;
    float sdu = r * R * gdu;
    a_du[i] = sdu; d_du[i] = -m * sdu + bdu;
  }
}

// ---------------------------------------------------------------------------
// 3) embed: P = exp(W@relu(a*x+d) + bias) written as bf16, plus tile-partial
//    sums of P for the softmax denominator (no max subtraction: |embed|≲10).
//    MODE 0: P [b][k][n], psum[(nblk*16+b)*256 + k]   (sum over tile's n)
//    MODE 1: PT [b][n][k], psum[(kblk*16+b)*8192 + n] (sum over tile's k)
// ---------------------------------------------------------------------------
template <int MODE>
__global__ __launch_bounds__(256) void k_embed_p(const unsigned short* __restrict__ xh,
                                                 const unsigned short* __restrict__ wh,
                                                 const float* __restrict__ bias,
                                                 const float* __restrict__ aff_a,
                                                 const float* __restrict__ aff_d,
                                                 unsigned short* __restrict__ outp,
                                                 float* __restrict__ psum) {
  const int n0 = blockIdx.x * 128, k0 = blockIdx.y * 128, b = blockIdx.z;
  __shared__ __align__(16) unsigned short smem[2 * 128 * 128];
  unsigned short* tA = smem;              // [k][c] swizzled
  unsigned short* tB = smem + 128 * 128;  // [n][c] swizzled
  __shared__ float aff_as[128], aff_ds[128], bias_s[128];
  const int tid = threadIdx.x, lane = tid & 63, wid = tid >> 6;
  const int wr = wid >> 1, wc = wid & 1, l15 = lane & 15, l4 = lane >> 4;
  if (tid < 128) {
    aff_as[tid] = aff_a[b * C_ + tid];
    aff_ds[tid] = aff_d[b * C_ + tid];
    bias_s[tid] = bias[k0 + tid];
  }
#pragma unroll
  for (int i = 0; i < 8; i++) {
    int call = wid * 8 + i;
    int row = call * 4 + (lane >> 4);
    int gch = (lane & 15) ^ (row & 7);
    gload_lds16(wh + (size_t)(k0 + row) * C_ + gch * 8, tA + call * 512);
    gload_lds16(xh + (size_t)(b * N_ + n0 + row) * C_ + gch * 8, tB + call * 512);
  }
  __syncthreads();
  f32x4 acc[4][4] = {};
#pragma unroll
  for (int ks = 0; ks < 128; ks += 32) {
    const int ch = (ks >> 3) + l4;
    s16x8 af[4], bfv[4];
#pragma unroll
    for (int m = 0; m < 4; m++) {
      int row = wr * 64 + m * 16 + l15;
      af[m] = *reinterpret_cast<const s16x8*>(tA + row * 128 + ((ch ^ (row & 7)) << 3));
    }
#pragma unroll
    for (int n = 0; n < 4; n++) {
      int row = wc * 64 + n * 16 + l15;
      s16x8 raw = *reinterpret_cast<const s16x8*>(tB + row * 128 + ((ch ^ (row & 7)) << 3));
      s16x8 h;
#pragma unroll
      for (int j = 0; j < 8; j++) {
        int c = ks + 8 * l4 + j;
        h[j] = (short)f2bf(fmaxf(fmaf(aff_as[c], bf2f((unsigned short)raw[j]), aff_ds[c]), 0.f));
      }
      bfv[n] = h;
    }
#pragma unroll
    for (int m = 0; m < 4; m++)
#pragma unroll
      for (int n = 0; n < 4; n++)
        acc[m][n] = __builtin_amdgcn_mfma_f32_16x16x32_bf16(af[m], bfv[n], acc[m][n], 0, 0, 0);
  }
  __syncthreads();
  // epilogue: e_s tile of P = exp(acc+bias)  (MODE0: [k][n], MODE1: [n][k])
  unsigned short (*e_s)[136] = reinterpret_cast<unsigned short(*)[136]>(smem);
#pragma unroll
  for (int m = 0; m < 4; m++)
#pragma unroll
    for (int n = 0; n < 4; n++) {
      int kl = wr * 64 + m * 16 + 4 * l4;
      int nl = wc * 64 + n * 16 + l15;
#pragma unroll
      for (int r = 0; r < 4; r++) {
        unsigned short v = f2bf(__expf(acc[m][n][r] + bias_s[kl + r]));
        if (MODE == 0) e_s[kl + r][nl] = v;
        else           e_s[nl][kl + r] = v;
      }
    }
  __syncthreads();
  // tile-partial denominator: sum each e_s row's 128 bf16 values
  {
    int row = tid >> 1, half = tid & 1;
    float s = 0.f;
    for (int j = 0; j < 64; j++) s += bf2f(e_s[row][half * 64 + j]);
    s += __shfl_xor(s, 1);
    if (half == 0) {
      if (MODE == 0) psum[((size_t)blockIdx.x * 16 + b) * 256 + k0 + row] = s;
      else           psum[((size_t)blockIdx.y * 16 + b) * 8192 + n0 + row] = s;
    }
  }
  if (MODE == 0) {
    for (int i = 0; i < 8; i++) {
      int q = tid + i * 256;
      int cg = q & 15, kk = q >> 4;
      u16x8 v = *reinterpret_cast<const u16x8*>(&e_s[kk][8 * cg]);
      *reinterpret_cast<u16x8*>(outp + (size_t)(b * K_ + k0 + kk) * N_ + n0 + 8 * cg) = v;
    }
  } else {
    for (int i = 0; i < 8; i++) {
      int q = tid + i * 256;
      int kg = q & 15, nn = q >> 4;
      u16x8 v = *reinterpret_cast<const u16x8*>(&e_s[nn][8 * kg]);
      *reinterpret_cast<u16x8*>(outp + (size_t)(b * N_ + n0 + nn) * K_ + k0 + 8 * kg) = v;
    }
  }
}

// 4a) rden[b][k] = 1 / sum over 64 n-tiles of row partials
__global__ __launch_bounds__(256) void k_rowfin(const float* __restrict__ pS,
                                                float* __restrict__ rden) {
  int e = blockIdx.x * 256 + threadIdx.x;  // b*256+k (4096)
  int b = e >> 8, k = e & 255;
  float s = 0.f;
  for (int nb = 0; nb < 64; nb++) s += pS[((size_t)nb * 16 + b) * 256 + k];
  rden[e] = 1.f / s;
}

// 4b) rs2[b][n] = 1 / (pC[0][b][n] + pC[1][b][n])
__global__ __launch_bounds__(256) void k_colfin(const float* __restrict__ pC,
                                                float* __restrict__ rs2) {
  int e = blockIdx.x * 256 + threadIdx.x;  // b*8192+n (131072)
  rs2[e] = 1.f / (pC[e] + pC[131072 + e]);
}

// ---------------------------------------------------------------------------
// 5) x_down partials: part[sp][b][c][k] = sum_{n in split} x[c,n]*P[k,n]
//    (raw bf16 operands both sides — no transform)
// ---------------------------------------------------------------------------
__global__ __launch_bounds__(256) void k_xdown_g(const unsigned short* __restrict__ xcn,
                                                 const unsigned short* __restrict__ Pb,
                                                 float* __restrict__ part) {
  const int k0 = blockIdx.x * 128, sp = blockIdx.y, b = blockIdx.z;
  const int nbase = sp * (N_ / NSP);
  __shared__ __align__(16) unsigned short smem[2 * 128 * 128];
  unsigned short* tA = smem;              // [c][n]
  unsigned short* tB = smem + 128 * 128;  // [k][n]
  const int tid = threadIdx.x, lane = tid & 63, wid = tid >> 6;
  const int wr = wid >> 1, wc = wid & 1, l15 = lane & 15, l4 = lane >> 4;
  f32x4 acc[4][4] = {};
  for (int nc = 0; nc < N_ / NSP; nc += 128) {
    const int n0 = nbase + nc;
#pragma unroll
    for (int i = 0; i < 8; i++) {
      int call = wid * 8 + i;
      int row = call * 4 + (lane >> 4);
      int gch = (lane & 15) ^ (row & 7);
      gload_lds16(xcn + (size_t)(b * C_ + row) * N_ + n0 + gch * 8, tA + call * 512);
      gload_lds16(Pb + (size_t)(b * K_ + k0 + row) * N_ + n0 + gch * 8, tB + call * 512);
    }
    __syncthreads();
#pragma unroll
    for (int ks = 0; ks < 128; ks += 32) {
      const int ch = (ks >> 3) + l4;
      s16x8 af[4], bfv[4];
#pragma unroll
      for (int m = 0; m < 4; m++) {
        int row = wr * 64 + m * 16 + l15;
        af[m] = *reinterpret_cast<const s16x8*>(tA + row * 128 + ((ch ^ (row & 7)) << 3));
      }
#pragma unroll
      for (int n = 0; n < 4; n++) {
        int row = wc * 64 + n * 16 + l15;
        bfv[n] = *reinterpret_cast<const s16x8*>(tB + row * 128 + ((ch ^ (row & 7)) << 3));
      }
#pragma unroll
      for (int m = 0; m < 4; m++)
#pragma unroll
        for (int n = 0; n < 4; n++)
          acc[m][n] = __builtin_amdgcn_mfma_f32_16x16x32_bf16(af[m], bfv[n], acc[m][n], 0, 0, 0);
    }
    __syncthreads();
  }
#pragma unroll
  for (int m = 0; m < 4; m++)
#pragma unroll
    for (int n = 0; n < 4; n++) {
      int c = wr * 64 + m * 16 + 4 * l4;
      int k = k0 + wc * 64 + n * 16 + l15;
#pragma unroll
      for (int r = 0; r < 4; r++)
        part[((size_t)(sp * B_ + b) * C_ + c + r) * K_ + k] = acc[m][n][r];
    }
}

// 6) reduce split partials, scale by 1/den -> xd fp32 [b][p][k] + xdh bf16
__global__ __launch_bounds__(256) void k_xdown_red(const float* __restrict__ part,
                                                   const float* __restrict__ rden,
                                                   float* __restrict__ xd,
                                                   unsigned short* __restrict__ xdh) {
  int e = blockIdx.x * 256 + threadIdx.x;  // B*C*K
  int k = e % K_;
  int b = e / (K_ * C_);
  float s = 0.f;
  for (int sp = 0; sp < NSP; sp++) s += part[(size_t)sp * (B_ * C_ * K_) + e];
  float v = s * rden[b * K_ + k];
  xd[e] = v;
  xdh[e] = f2bf(v);
}

// ---------------------------------------------------------------------------
// 7a) gram tiles: pd[b][p][q] = sum_k xd[b][p][k]*xd[b][q][k]
// ---------------------------------------------------------------------------
__global__ __launch_bounds__(256) void k_gram(const float* __restrict__ xd,
                                              float* __restrict__ pd) {
  const int p0 = blockIdx.x * 32, b = blockIdx.y;
  __shared__ float A[32][36];
  __shared__ float Bt[32][132];
  const int tid = threadIdx.x;
  const int tr = tid >> 5, tc = tid & 31;
  float acc[4][4] = {};
  for (int k0 = 0; k0 < K_; k0 += 32) {
    {
      int pp = tid >> 3, k4 = tid & 7;
      float4 v = *reinterpret_cast<const float4*>(xd + (size_t)(b * C_ + p0 + pp) * K_ + k0 + 4 * k4);
      A[4 * k4 + 0][pp] = v.x; A[4 * k4 + 1][pp] = v.y;
      A[4 * k4 + 2][pp] = v.z; A[4 * k4 + 3][pp] = v.w;
    }
    for (int i = 0; i < 4; i++) {
      int q = tid + i * 256;
      int qq = q >> 3, k4 = q & 7;
      float4 v = *reinterpret_cast<const float4*>(xd + (size_t)(b * C_ + qq) * K_ + k0 + 4 * k4);
      Bt[4 * k4 + 0][qq] = v.x; Bt[4 * k4 + 1][qq] = v.y;
      Bt[4 * k4 + 2][qq] = v.z; Bt[4 * k4 + 3][qq] = v.w;
    }
    __syncthreads();
    for (int kk = 0; kk < 32; ++kk) {
      float4 av = *reinterpret_cast<const float4*>(&A[kk][tr * 4]);
      float4 bv = *reinterpret_cast<const float4*>(&Bt[kk][tc * 4]);
      float a[4] = {av.x, av.y, av.z, av.w};
      float bb[4] = {bv.x, bv.y, bv.z, bv.w};
#pragma unroll
      for (int i = 0; i < 4; ++i)
#pragma unroll
        for (int j = 0; j < 4; ++j) acc[i][j] = fmaf(a[i], bb[j], acc[i][j]);
    }
    __syncthreads();
  }
#pragma unroll
  for (int i = 0; i < 4; ++i) {
    float4 r; r.x = acc[i][0]; r.y = acc[i][1]; r.z = acc[i][2]; r.w = acc[i][3];
    *reinterpret_cast<float4*>(pd + (size_t)(b * P_ + p0 + tr * 4 + i) * P_ + tc * 4) = r;
  }
}

// 7b) sq[b][p] = ||xd[b][p][:]||^2
__global__ __launch_bounds__(128) void k_sq(const float* __restrict__ xd,
                                            float* __restrict__ sq) {
  const int b = blockIdx.x, p = threadIdx.x;
  const float4* r = reinterpret_cast<const float4*>(xd + (size_t)(b * C_ + p) * K_);
  float s = 0.f;
  for (int i = 0; i < K_ / 4; i++) { float4 v = r[i]; s += v.x * v.x + v.y * v.y + v.z * v.z + v.w * v.w; }
  sq[b * P_ + p] = s;
}

// 7c) top-6 per point: one wave per point, 6 rounds of wave argmax
__global__ __launch_bounds__(256) void k_topk(const float* __restrict__ pd,
                                              const float* __restrict__ sq,
                                              int* __restrict__ idx) {
  const int wid = threadIdx.x >> 6, lane = threadIdx.x & 63;
  const int gp = blockIdx.x * 4 + wid;  // b*P + p
  const int b = gp >> 7;
  const float* row = pd + (size_t)gp * P_;
  float v0 = 2.f * row[lane] - sq[b * P_ + lane];
  float v1 = 2.f * row[lane + 64] - sq[b * P_ + lane + 64];
  int q0 = lane, q1 = lane + 64;
#pragma unroll
  for (int j = 0; j < NB_; j++) {
    float bv; int bq;
    if (v0 > v1 || (v0 == v1 && q0 < q1)) { bv = v0; bq = q0; } else { bv = v1; bq = q1; }
#pragma unroll
    for (int o = 32; o > 0; o >>= 1) {
      float ov = __shfl_xor(bv, o); int oq = __shfl_xor(bq, o);
      if (ov > bv || (ov == bv && oq < bq)) { bv = ov; bq = oq; }
    }
    if (lane == 0) idx[gp * NB_ + j] = bq;
    if (q0 == bq) v0 = -3.0e38f;
    if (q1 == bq) v1 = -3.0e38f;
  }
}

// ---------------------------------------------------------------------------
// 8) UV via MFMA: Ut/Vt[b][p][o] = sum_k W1{sum|b}[o][k] * xdh[b][p][k]
// ---------------------------------------------------------------------------
__global__ __launch_bounds__(256) void k_uv_mfma(const unsigned short* __restrict__ xdh,
                                                 const unsigned short* __restrict__ w1sh,
                                                 const unsigned short* __restrict__ w1bh,
                                                 float* __restrict__ Ut, float* __restrict__ Vt) {
  const int o0 = blockIdx.x * 128, which = blockIdx.y, b = blockIdx.z;
  __shared__ __align__(16) unsigned char smemraw[128 * 132 * 4];
  unsigned short* tA = (unsigned short*)smemraw;
  unsigned short* tB = tA + 128 * 128;
  const unsigned short* wsel = which ? w1bh : w1sh;
  const int tid = threadIdx.x, lane = tid & 63, wid = tid >> 6;
  const int wr = wid >> 1, wc = wid & 1, l15 = lane & 15, l4 = lane >> 4;
  f32x4 acc[4][4] = {};
  for (int kh = 0; kh < 256; kh += 128) {
#pragma unroll
    for (int i = 0; i < 8; i++) {
      int call = wid * 8 + i;
      int row = call * 4 + (lane >> 4);
      int gch = (lane & 15) ^ (row & 7);
      gload_lds16(wsel + (size_t)(o0 + row) * 256 + kh + gch * 8, tA + call * 512);
      gload_lds16(xdh + (size_t)(b * P_ + row) * 256 + kh + gch * 8, tB + call * 512);
    }
    __syncthreads();
#pragma unroll
    for (int ks = 0; ks < 128; ks += 32) {
      const int ch = (ks >> 3) + l4;
      s16x8 af[4], bfv[4];
#pragma unroll
      for (int m = 0; m < 4; m++) {
        int row = wr * 64 + m * 16 + l15;
        af[m] = *reinterpret_cast<const s16x8*>(tA + row * 128 + ((ch ^ (row & 7)) << 3));
      }
#pragma unroll
      for (int n = 0; n < 4; n++) {
        int row = wc * 64 + n * 16 + l15;
        bfv[n] = *reinterpret_cast<const s16x8*>(tB + row * 128 + ((ch ^ (row & 7)) << 3));
      }
#pragma unroll
      for (int m = 0; m < 4; m++)
#pragma unroll
        for (int n = 0; n < 4; n++)
          acc[m][n] = __builtin_amdgcn_mfma_f32_16x16x32_bf16(af[m], bfv[n], acc[m][n], 0, 0, 0);
    }
    __syncthreads();
  }
  // transpose epilogue in fp32 LDS -> Ut/Vt[b][p][o] linear rows
  float (*ef)[132] = (float(*)[132])smemraw;
#pragma unroll
  for (int m = 0; m < 4; m++)
#pragma unroll
    for (int n = 0; n < 4; n++) {
      int ol = wr * 64 + m * 16 + 4 * l4;
      int pl = wc * 64 + n * 16 + l15;
#pragma unroll
      for (int r = 0; r < 4; r++) ef[pl][ol + r] = acc[m][n][r];
    }
  __syncthreads();
  float* outp = which ? Vt : Ut;
  for (int i = 0; i < 16; i++) {
    int q = tid + i * 256;
    int pl = q >> 5, c4 = q & 31;
    float4 v = *reinterpret_cast<const float4*>(&ef[pl][c4 * 4]);
    *reinterpret_cast<float4*>(outp + (size_t)(b * P_ + pl) * 256 + o0 + c4 * 4) = v;
  }
}

// 9) g1h[b*768+pj][o] = Ut[b][p][o] + b1[o] - Vt[b][q][o]   (bf16, coalesced)
__global__ __launch_bounds__(256) void k_edge_t(const float* __restrict__ Ut,
                                                const float* __restrict__ Vt,
                                                const int* __restrict__ idx,
                                                const float* __restrict__ b1,
                                                unsigned short* __restrict__ g1h) {
  __shared__ float b1s[256];
  const int tid = threadIdx.x;
  b1s[tid] = b1[tid];
  __syncthreads();
  const int row0 = blockIdx.x * 16;
  for (int r = 0; r < 16; r++) {
    int row = row0 + r;  // b*768 + p*6 + j
    int b = row / 768, pj = row % 768, p = pj / 6;
    int q = idx[(b * P_ + p) * NB_ + (pj % 6)];
    float v = Ut[(size_t)(b * P_ + p) * 256 + tid] + b1s[tid]
            - Vt[(size_t)(b * P_ + q) * 256 + tid];
    g1h[(size_t)row * 256 + tid] = f2bf(v);
  }
}

// 10) BN stats over rows of gt [12288][256]: per-block partial sums
__global__ __launch_bounds__(256) void k_bnstat_t(const unsigned short* __restrict__ gt,
                                                  float* __restrict__ partS,
                                                  float* __restrict__ partQ) {
  const int tid = threadIdx.x;
  const size_t row0 = (size_t)blockIdx.x * 256;
  float s = 0.f, ss = 0.f;
  for (int r = 0; r < 256; r++) {
    float v = bf2f(gt[(row0 + r) * 256 + tid]);
    s += v; ss += v * v;
  }
  partS[blockIdx.x * 256 + tid] = s;
  partQ[blockIdx.x * 256 + tid] = ss;
}

// 10b) finalize BN scale/shift
__global__ __launch_bounds__(256) void k_bnfin(const float* __restrict__ partS,
                                               const float* __restrict__ partQ,
                                               const float* __restrict__ gamma,
                                               const float* __restrict__ beta,
                                               float* __restrict__ sc, float* __restrict__ sh) {
  int o = threadIdx.x;
  float s = 0.f, q = 0.f;
  for (int i = 0; i < 48; i++) { s += partS[i * 256 + o]; q += partQ[i * 256 + o]; }
  const float cnt = (float)(B_ * P_ * NB_);
  float m = s / cnt, var = q / cnt - m * m;
  float scale = gamma[o] * rsqrtf(var + 1e-5f);
  sc[o] = scale; sh[o] = -m * scale + beta[o];
}

// 11) conv2 via MFMA: g2h[n][o] = sum_c w2[o][c]*relu(bn1(g1h[n][c])) + b2
__global__ __launch_bounds__(256) void k_conv2_mfma(const unsigned short* __restrict__ g1h,
                                                    const unsigned short* __restrict__ w2h,
                                                    const float* __restrict__ b2,
                                                    const float* __restrict__ bn1sc,
                                                    const float* __restrict__ bn1sh,
                                                    unsigned short* __restrict__ g2h) {
  const int n0 = blockIdx.x * 128, o0 = blockIdx.y * 128, b = blockIdx.z;
  __shared__ __align__(16) unsigned short smem[2 * 128 * 128];
  unsigned short* tA = smem;
  unsigned short* tB = smem + 128 * 128;
  __shared__ float scs[256], shs[256], b2s[128];
  const int tid = threadIdx.x, lane = tid & 63, wid = tid >> 6;
  const int wr = wid >> 1, wc = wid & 1, l15 = lane & 15, l4 = lane >> 4;
  scs[tid] = bn1sc[tid]; shs[tid] = bn1sh[tid];
  if (tid < 128) b2s[tid] = b2[o0 + tid];
  f32x4 acc[4][4] = {};
  for (int kh = 0; kh < 256; kh += 128) {
#pragma unroll
    for (int i = 0; i < 8; i++) {
      int call = wid * 8 + i;
      int row = call * 4 + (lane >> 4);
      int gch = (lane & 15) ^ (row & 7);
      gload_lds16(w2h + (size_t)(o0 + row) * 256 + kh + gch * 8, tA + call * 512);
      gload_lds16(g1h + (size_t)(b * 768 + n0 + row) * 256 + kh + gch * 8, tB + call * 512);
    }
    __syncthreads();
#pragma unroll
    for (int ks = 0; ks < 128; ks += 32) {
      const int ch = (ks >> 3) + l4;
      s16x8 af[4], bfv[4];
#pragma unroll
      for (int m = 0; m < 4; m++) {
        int row = wr * 64 + m * 16 + l15;
        af[m] = *reinterpret_cast<const s16x8*>(tA + row * 128 + ((ch ^ (row & 7)) << 3));
      }
#pragma unroll
      for (int n = 0; n < 4; n++) {
        int row = wc * 64 + n * 16 + l15;
        s16x8 raw = *reinterpret_cast<const s16x8*>(tB + row * 128 + ((ch ^ (row & 7)) << 3));
        s16x8 h;
#pragma unroll
        for (int j = 0; j < 8; j++) {
          int c = kh + ks + 8 * l4 + j;
          h[j] = (short)f2bf(fmaxf(fmaf(scs[c], bf2f((unsigned short)raw[j]), shs[c]), 0.f));
        }
        bfv[n] = h;
      }
#pragma unroll
      for (int m = 0; m < 4; m++)
#pragma unroll
        for (int n = 0; n < 4; n++)
          acc[m][n] = __builtin_amdgcn_mfma_f32_16x16x32_bf16(af[m], bfv[n], acc[m][n], 0, 0, 0);
    }
    __syncthreads();
  }
  unsigned short (*e_s)[136] = reinterpret_cast<unsigned short(*)[136]>(smem);
#pragma unroll
  for (int m = 0; m < 4; m++)
#pragma unroll
    for (int n = 0; n < 4; n++) {
      int ol = wr * 64 + m * 16 + 4 * l4;
      int nl = wc * 64 + n * 16 + l15;
#pragma unroll
      for (int r = 0; r < 4; r++)
        e_s[nl][ol + r] = f2bf(acc[m][n][r] + b2s[ol + r]);
    }
  __syncthreads();
  for (int i = 0; i < 8; i++) {
    int q = tid + i * 256;
    int og = q & 15, nl = q >> 4;
    u16x8 v = *reinterpret_cast<const u16x8*>(&e_s[nl][8 * og]);
    *reinterpret_cast<u16x8*>(g2h + (size_t)(b * 768 + n0 + nl) * 256 + o0 + 8 * og) = v;
  }
}

// 13) gmaxh[b][k][p] = max_j relu(bn2(g2h[b*768+p*6+j][k]))  (bf16)
__global__ __launch_bounds__(256) void k_gmax_t(const unsigned short* __restrict__ g2h,
                                                const float* __restrict__ bn2sc,
                                                const float* __restrict__ bn2sh,
                                                unsigned short* __restrict__ gmaxh) {
  const int o0 = blockIdx.x * 128, b = blockIdx.y;
  const int ol = threadIdx.x & 127, ph = threadIdx.x >> 7;
  const int o = o0 + ol;
  const float sc = bn2sc[o], sh = bn2sh[o];
  for (int p8 = ph * 64; p8 < ph * 64 + 64; p8 += 8) {
    u16x8 pack;
#pragma unroll
    for (int pi = 0; pi < 8; pi++) {
      int p = p8 + pi;
      float m = 0.f;
#pragma unroll
      for (int j = 0; j < NB_; j++) {
        float v = bf2f(g2h[(size_t)(b * 768 + p * 6 + j) * 256 + o]);
        m = fmaxf(m, fmaf(sc, v, sh));
      }
      pack[pi] = f2bf(m);
    }
    *reinterpret_cast<u16x8*>(gmaxh + (size_t)(b * 256 + o) * P_ + p8) = pack;
  }
}

// 14) M2h[b][o2][k] = sum_c scwB[o2][c] * gmaxh[b][k][c]  (MFMA)
__global__ __launch_bounds__(256) void k_m2_mfma(const unsigned short* __restrict__ gmaxh,
                                                 const unsigned short* __restrict__ scbh,
                                                 unsigned short* __restrict__ M2h) {
  const int k0 = blockIdx.x * 128, b = blockIdx.y;
  __shared__ __align__(16) unsigned short smem[2 * 128 * 128];
  unsigned short* tA = smem;
  unsigned short* tB = smem + 128 * 128;
  const int tid = threadIdx.x, lane = tid & 63, wid = tid >> 6;
  const int wr = wid >> 1, wc = wid & 1, l15 = lane & 15, l4 = lane >> 4;
#pragma unroll
  for (int i = 0; i < 8; i++) {
    int call = wid * 8 + i;
    int row = call * 4 + (lane >> 4);
    int gch = (lane & 15) ^ (row & 7);
    gload_lds16(scbh + (size_t)row * P_ + gch * 8, tA + call * 512);
    gload_lds16(gmaxh + (size_t)(b * 256 + k0 + row) * P_ + gch * 8, tB + call * 512);
  }
  __syncthreads();
  f32x4 acc[4][4] = {};
#pragma unroll
  for (int ks = 0; ks < 128; ks += 32) {
    const int ch = (ks >> 3) + l4;
    s16x8 af[4], bfv[4];
#pragma unroll
    for (int m = 0; m < 4; m++) {
      int row = wr * 64 + m * 16 + l15;
      af[m] = *reinterpret_cast<const s16x8*>(tA + row * 128 + ((ch ^ (row & 7)) << 3));
    }
#pragma unroll
    for (int n = 0; n < 4; n++) {
      int row = wc * 64 + n * 16 + l15;
      bfv[n] = *reinterpret_cast<const s16x8*>(tB + row * 128 + ((ch ^ (row & 7)) << 3));
    }
#pragma unroll
    for (int m = 0; m < 4; m++)
#pragma unroll
      for (int n = 0; n < 4; n++)
        acc[m][n] = __builtin_amdgcn_mfma_f32_16x16x32_bf16(af[m], bfv[n], acc[m][n], 0, 0, 0);
  }
  __syncthreads();
  unsigned short (*e_s)[136] = reinterpret_cast<unsigned short(*)[136]>(smem);
#pragma unroll
  for (int m = 0; m < 4; m++)
#pragma unroll
    for (int n = 0; n < 4; n++) {
      int ol = wr * 64 + m * 16 + 4 * l4;
      int kl = wc * 64 + n * 16 + l15;
#pragma unroll
      for (int r = 0; r < 4; r++)
        e_s[ol + r][kl] = f2bf(acc[m][n][r]);
    }
  __syncthreads();
  for (int i = 0; i < 8; i++) {
    int q = tid + i * 256;
    int kg = q & 15, oo = q >> 4;
    u16x8 v = *reinterpret_cast<const u16x8*>(&e_s[oo][8 * kg]);
    *reinterpret_cast<u16x8*>(M2h + (size_t)(b * C_ + oo) * K_ + k0 + 8 * kg) = v;
  }
}

// ---------------------------------------------------------------------------
// 16) out[o,n] = scwA@x + (M2 @ PT)*rs2[n] + scb  — raw operands, no transform
// ---------------------------------------------------------------------------
__global__ __launch_bounds__(256) void k_final_g(const unsigned short* __restrict__ PT,
                                                 const unsigned short* __restrict__ xh,
                                                 const unsigned short* __restrict__ M2h,
                                                 const unsigned short* __restrict__ scah,
                                                 const float* __restrict__ scb,
                                                 const float* __restrict__ rs2,
                                                 float* __restrict__ out) {
  const int n0 = blockIdx.x * 128, b = blockIdx.y;
  __shared__ __align__(16) unsigned short smem[2 * 128 * 128];
  unsigned short* tA = smem;
  unsigned short* tB = smem + 128 * 128;
  __shared__ float rs2s[128], scb_s[128];
  const int tid = threadIdx.x, lane = tid & 63, wid = tid >> 6;
  const int wr = wid >> 1, wc = wid & 1, l15 = lane & 15, l4 = lane >> 4;
  if (tid < 128) {
    rs2s[tid] = rs2[b * N_ + n0 + tid];
    scb_s[tid] = scb[tid];
  }
  f32x4 acc[4][4] = {};
  // ---- phase B first: contraction over k (M2 @ P), two 128-halves, raw ----
  for (int kh = 0; kh < K_; kh += 128) {
#pragma unroll
    for (int i = 0; i < 8; i++) {
      int call = wid * 8 + i;
      int row = call * 4 + (lane >> 4);
      int gch = (lane & 15) ^ (row & 7);
      gload_lds16(M2h + (size_t)(b * C_ + row) * K_ + kh + gch * 8, tA + call * 512);
      gload_lds16(PT + (size_t)(b * N_ + n0 + row) * K_ + kh + gch * 8, tB + call * 512);
    }
    __syncthreads();
#pragma unroll
    for (int ks = 0; ks < 128; ks += 32) {
      const int ch = (ks >> 3) + l4;
      s16x8 af[4], bfv[4];
#pragma unroll
      for (int m = 0; m < 4; m++) {
        int row = wr * 64 + m * 16 + l15;
        af[m] = *reinterpret_cast<const s16x8*>(tA + row * 128 + ((ch ^ (row & 7)) << 3));
      }
#pragma unroll
      for (int n = 0; n < 4; n++) {
        int row = wc * 64 + n * 16 + l15;
        bfv[n] = *reinterpret_cast<const s16x8*>(tB + row * 128 + ((ch ^ (row & 7)) << 3));
      }
#pragma unroll
      for (int m = 0; m < 4; m++)
#pragma unroll
        for (int n = 0; n < 4; n++)
          acc[m][n] = __builtin_amdgcn_mfma_f32_16x16x32_bf16(af[m], bfv[n], acc[m][n], 0, 0, 0);
    }
    __syncthreads();
  }
  // scale phase-B accumulator by per-column softmax denominator
  __syncthreads();  // rs2s visible (loaded at kernel start)
#pragma unroll
  for (int n = 0; n < 4; n++) {
    float rv = rs2s[wc * 64 + n * 16 + l15];
#pragma unroll
    for (int m = 0; m < 4; m++) {
      acc[m][n][0] *= rv; acc[m][n][1] *= rv; acc[m][n][2] *= rv; acc[m][n][3] *= rv;
    }
  }
  // ---- phase A: contraction over c (scwA @ x), raw ----
#pragma unroll
  for (int i = 0; i < 8; i++) {
    int call = wid * 8 + i;
    int row = call * 4 + (lane >> 4);
    int gch = (lane & 15) ^ (row & 7);
    gload_lds16(scah + (size_t)row * C_ + gch * 8, tA + call * 512);
    gload_lds16(xh + (size_t)(b * N_ + n0 + row) * C_ + gch * 8, tB + call * 512);
  }
  __syncthreads();
#pragma unroll
  for (int ks = 0; ks < 128; ks += 32) {
    const int ch = (ks >> 3) + l4;
    s16x8 af[4], bfv[4];
#pragma unroll
    for (int m = 0; m < 4; m++) {
      int row = wr * 64 + m * 16 + l15;
      af[m] = *reinterpret_cast<const s16x8*>(tA + row * 128 + ((ch ^ (row & 7)) << 3));
    }
#pragma unroll
    for (int n = 0; n < 4; n++) {
      int row = wc * 64 + n * 16 + l15;
      bfv[n] = *reinterpret_cast<const s16x8*>(tB + row * 128 + ((ch ^ (row & 7)) << 3));
    }
#pragma unroll
    for (int m = 0; m < 4; m++)
#pragma unroll
      for (int n = 0; n < 4; n++)
        acc[m][n] = __builtin_amdgcn_mfma_f32_16x16x32_bf16(af[m], bfv[n], acc[m][n], 0, 0, 0);
  }
#pragma unroll
  for (int m = 0; m < 4; m++)
#pragma unroll
    for (int n = 0; n < 4; n++) {
      int o = wr * 64 + m * 16 + 4 * l4;
      int nn = n0 + wc * 64 + n * 16 + l15;
#pragma unroll
      for (int r = 0; r < 4; r++)
        out[(size_t)(b * C_ + o + r) * N_ + nn] = acc[m][n][r] + scb_s[o + r];
    }
}

// ---------------------------------------------------------------------------
extern "C" void kernel_launch(void* const* d_in, const int* in_sizes, int n_in,
                              void* d_out, int out_size, void* d_ws, size_t ws_size,
                              hipStream_t stream) {
  (void)in_sizes; (void)n_in; (void)out_size; (void)ws_size;
  const float* x      = (const float*)d_in[0];
  const float* dpg    = (const float*)d_in[1];
  const float* dpb    = (const float*)d_in[2];
  const float* dpw    = (const float*)d_in[3];
  const float* dpbias = (const float*)d_in[4];
  const float* dug    = (const float*)d_in[5];
  const float* dub    = (const float*)d_in[6];
  const float* duw    = (const float*)d_in[7];
  const float* dubias = (const float*)d_in[8];
  const float* w1     = (const float*)d_in[9];
  const float* b1     = (const float*)d_in[10];
  const float* g1g    = (const float*)d_in[11];
  const float* g1b    = (const float*)d_in[12];
  const float* w2     = (const float*)d_in[13];
  const float* b2     = (const float*)d_in[14];
  const float* g2g    = (const float*)d_in[15];
  const float* g2b    = (const float*)d_in[16];
  const float* scw    = (const float*)d_in[17];
  const float* scb    = (const float*)d_in[18];
  float* out = (float*)d_out;
  float* ws  = (float*)d_ws;

  // workspace layout (float-slot units unless noted)
  unsigned short* EB  = (unsigned short*)ws;               // B*K*N bf16 (P, later PT)
  unsigned short* xh  = (unsigned short*)(ws + 16777216);  // B*N*C bf16
  unsigned short* xcn = (unsigned short*)(ws + 25165824);  // B*C*N bf16
  float* base  = ws + 33554432;
  float* m_in  = base;               // 2048
  float* v_in  = m_in + 2048;
  float* r_in  = v_in + 2048;
  float* a_dp  = r_in + 2048;
  float* d_dp  = a_dp + 2048;
  float* a_du  = d_dp + 2048;
  float* d_du  = a_du + 2048;
  float* rden  = d_du + 2048;        // 4096
  float* rs2   = rden + 4096;        // 131072
  float* xd    = rs2 + 131072;       // 524288 fp32 [b][p][k]
  float* Ut    = xd + 524288;        // 524288
  float* Vt    = Ut + 524288;        // 524288
  int*   idxb  = (int*)(Vt + 524288);  // 12288
  float* bn1sc = (float*)(idxb + 12288);
  float* bn1sh = bn1sc + 256;
  float* bn2sc = bn1sh + 256;
  float* bn2sh = bn2sc + 256;
  float* sq    = bn2sh + 256;        // 2048
  float* pd    = sq + 2048;          // 262144
  float* partS = pd + 262144;        // 12288
  float* partQ = partS + 12288;      // 12288
  float* pstS  = partQ + 12288;      // 262144 (128 chunks ×16b×128c)
  float* pstQ  = pstS + 262144;      // 262144
  float* pS    = pstQ + 262144;      // 262144 (64 ntiles ×16b×256k)
  float* pC    = pS + 262144;        // 262144 (2 ktiles ×16b×8192n)
  unsigned short* xdh  = (unsigned short*)(pC + 262144);    // 524288 shorts
  unsigned short* dpwh = xdh + 524288;     // 32768
  unsigned short* duwh = dpwh + 32768;     // 32768
  unsigned short* scah = duwh + 32768;     // 16384
  unsigned short* scbh = scah + 16384;     // 16384
  unsigned short* w1sh = scbh + 16384;     // 65536
  unsigned short* w1bh = w1sh + 65536;     // 65536
  unsigned short* w2h  = w1bh + 65536;     // 65536
  unsigned short* M2h  = w2h + 65536;      // 524288 shorts
  float* part = (float*)(M2h + 524288);    // NSP*B*C*K = 8,388,608 fp32
  // post-xdown aliases inside the dead `part` region:
  unsigned short* g1h   = (unsigned short*)part;  // 3,145,728 shorts
  unsigned short* g2h   = g1h + 3145728;          // 3,145,728 shorts
  unsigned short* gmaxh = g2h + 3145728;          // 524,288 shorts

  k_prep<<<dim3(128, 16), 256, 0, stream>>>(x, xh, xcn, pstS, pstQ);
  k_wconv<<<dim3(256), 256, 0, stream>>>(dpw, duw, scw, w1, w2,
                                         dpwh, duwh, scah, scbh, w1sh, w1bh, w2h);
  k_instat_fin<<<dim3(8), 256, 0, stream>>>(pstS, pstQ, m_in, v_in, r_in);
  k_affine<<<1, 128, 0, stream>>>(m_in, v_in, r_in, dpg, dpb, dug, dub, a_dp, d_dp, a_du, d_du);
  k_embed_p<0><<<dim3(64, 2, 16), 256, 0, stream>>>(xh, dpwh, dpbias, a_dp, d_dp, EB, pS);
  k_rowfin<<<dim3(16), 256, 0, stream>>>(pS, rden);
  k_xdown_g<<<dim3(2, NSP, 16), 256, 0, stream>>>(xcn, EB, part);
  k_xdown_red<<<dim3(2048), 256, 0, stream>>>(part, rden, xd, xdh);
  k_gram<<<dim3(4, 16), 256, 0, stream>>>(xd, pd);
  k_sq<<<dim3(16), 128, 0, stream>>>(xd, sq);
  k_topk<<<dim3(512), 256, 0, stream>>>(pd, sq, idxb);
  k_uv_mfma<<<dim3(2, 2, 16), 256, 0, stream>>>(xdh, w1sh, w1bh, Ut, Vt);
  k_edge_t<<<dim3(768), 256, 0, stream>>>(Ut, Vt, idxb, b1, g1h);
  k_bnstat_t<<<dim3(48), 256, 0, stream>>>(g1h, partS, partQ);
  k_bnfin<<<dim3(1), 256, 0, stream>>>(partS, partQ, g1g, g1b, bn1sc, bn1sh);
  k_conv2_mfma<<<dim3(6, 2, 16), 256, 0, stream>>>(g1h, w2h, b2, bn1sc, bn1sh, g2h);
  k_bnstat_t<<<dim3(48), 256, 0, stream>>>(g2h, partS, partQ);
  k_bnfin<<<dim3(1), 256, 0, stream>>>(partS, partQ, g2g, g2b, bn2sc, bn2sh);
  k_gmax_t<<<dim3(2, 16), 256, 0, stream>>>(g2h, bn2sc, bn2sh, gmaxh);
  k_m2_mfma<<<dim3(2, 16), 256, 0, stream>>>(gmaxh, scbh, M2h);
  k_embed_p<1><<<dim3(64, 2, 16), 256, 0, stream>>>(xh, duwh, dubias, a_du, d_du, EB, pC);
  k_colfin<<<dim3(512), 256, 0, stream>>>(pC, rs2);
  k_final_g<<<dim3(64, 16), 256, 0, stream>>>(EB, xh, M2h, scah, scb, rs2, out);
}